// Round 5
// baseline (260.451 us; speedup 1.0000x reference)
//
#include <hip/hip_runtime.h>

#define N_NODES 100000
#define IN_CH 128
#define HIDDEN 128
#define OUT_CH 64
#define N_POS 600000
#define N_NEG 600000

typedef unsigned int uint32;
typedef unsigned short ushort16;
typedef __attribute__((ext_vector_type(8))) short bf16x8;
typedef __attribute__((ext_vector_type(4))) float f32x4;

// ---- bf16 helpers ----
__device__ inline float bf_lo(uint32 u) {
    union { uint32 i; float f; } v;
    v.i = u << 16;
    return v.f;
}
__device__ inline float bf_hi(uint32 u) {
    union { uint32 i; float f; } v;
    v.i = u & 0xffff0000u;
    return v.f;
}
__device__ inline ushort16 f2bf(float f) {
    union { uint32 i; float f; } v;
    v.f = f;
    uint32 r = v.i + 0x7fffu + ((v.i >> 16) & 1u);  // round-to-nearest-even
    return (ushort16)(r >> 16);
}
__device__ inline uint32 pack2bf(float a, float b) {
    return (uint32)f2bf(a) | ((uint32)f2bf(b) << 16);
}

#define NB_HIST ((N_POS + 255) / 256)   // 2344 -- 1 edge/thread (measured best, r0 vs r1/r2)
#define NB_FILL ((N_POS + 255) / 256)   // 2344
#define NB_GEMM1 ((N_NODES + 63) / 64)  // 1563
// Interleaved launch: groups of 5 blocks = 3 fill + 2 gemm (ratio ~ 2344:1563).
// Keeps fill (latency-bound) and gemm (MFMA-bound) co-resident on every CU for
// the whole kernel instead of fill-first/gemm-later dispatch order.
#define NB_MIX_GROUPS ((NB_FILL + 2) / 3)                 // 782
#define NB_MIX (NB_MIX_GROUPS * 5)                        // 3910 (3 idle-tail blocks)

// ===== fused: hist_count (+rank persist) + weight transpose/convert =====
// The atomicAdd's return value IS the edge's rank among same-dst edges.
// Persisting it (coalesced 4B store) lets csr-fill compute its slot with
// pure loads: p = rowstart[d] + rank[e]. No atomic, no cursor in fill.
// (verified -13us on csr_gemm1, r4)
__global__ void hist_wt(const int* __restrict__ dst, int* __restrict__ hist,
                        int* __restrict__ rank,
                        const float* __restrict__ W1, const float* __restrict__ W2,
                        ushort16* __restrict__ W1t, ushort16* __restrict__ W2t) {
    if (blockIdx.x < NB_HIST) {
        int i = blockIdx.x * 256 + threadIdx.x;
        if (i < N_POS) rank[i] = atomicAdd(&hist[dst[i]], 1);
    } else {
        int i = (blockIdx.x - NB_HIST) * 256 + threadIdx.x;
        if (i < 128 * 128) {
            int n = i >> 7, k = i & 127;
            W1t[i] = f2bf(W1[k * 128 + n]);
        } else {
            int j = i - 128 * 128;
            if (j < 64 * 128) {
                int n = j >> 7, k = j & 127;
                W2t[j] = f2bf(W2[k * 64 + n]);
            }
        }
    }
}

__global__ void scan_reduce(const int* __restrict__ hist, int* __restrict__ partials, int n) {
    __shared__ int sdata[256];
    int b = blockIdx.x, t = threadIdx.x;
    int base = b * 1024;
    int s = 0;
    for (int i = t; i < 1024; i += 256) {
        int idx = base + i;
        s += (idx < n) ? hist[idx] : 0;
    }
    sdata[t] = s;
    __syncthreads();
    for (int off = 128; off > 0; off >>= 1) {
        if (t < off) sdata[t] += sdata[t + off];
        __syncthreads();
    }
    if (t == 0) partials[b] = sdata[0];
}

// scan_final computes its own partials-prefix (first wave). NB_SCAN = 98 <= 128.
__global__ void scan_final(const int* __restrict__ hist, const int* __restrict__ partials,
                           int* __restrict__ rowstart, float* __restrict__ dinv, int n) {
    __shared__ int tsum[256];
    __shared__ int base_sh;
    int t = threadIdx.x, b = blockIdx.x;
    if (t < 64) {
        int s0 = (t < b) ? partials[t] : 0;
        int i2 = t + 64;
        int s1 = (i2 < b && i2 < 98) ? partials[i2] : 0;
        int s = s0 + s1;
#pragma unroll
        for (int off = 32; off > 0; off >>= 1) s += __shfl_down(s, off, 64);
        if (t == 0) base_sh = s;
    }
    int base = b * 1024 + t * 4;
    int v[4];
    int s = 0;
#pragma unroll
    for (int j = 0; j < 4; j++) {
        int i = base + j;
        v[j] = (i < n) ? hist[i] : 0;
        s += v[j];
    }
    tsum[t] = s;
    __syncthreads();
    for (int off = 1; off < 256; off <<= 1) {
        int a = (t >= off) ? tsum[t - off] : 0;
        __syncthreads();
        tsum[t] += a;
        __syncthreads();
    }
    int offset = base_sh + (tsum[t] - s);
#pragma unroll
    for (int j = 0; j < 4; j++) {
        int i = base + j;
        if (i < n) {
            rowstart[i] = offset;
            dinv[i] = rsqrtf((float)v[j] + 1.0f);
            offset += v[j];
        }
    }
    if (b == 0 && t == 0) rowstart[n] = N_POS;
}

// ===== shared GEMM tile body: H_bf16[node0..node0+64, M] = X @ W =====
// K-split double staging: LDS holds only a K/2 slice of X-tile and W at a
// time (27.6KB for M=128 vs 52KB full) so co-scheduled scatter blocks keep
// ~5 blocks/CU occupancy. W staged through LDS (coalesced once, broadcast
// reads) — round-11 direct-global W was a 1.7x regression (heavy reuse case).
template <int M, bool XBF>
__device__ __forceinline__ void gemm_tile(const void* __restrict__ Xv,
                                          const ushort16* __restrict__ Wt,
                                          ushort16* __restrict__ H, int n, int tileIdx) {
    constexpr int K = 128;
    constexpr int TN = 64;
    constexpr int KH = 64;  // K half
    constexpr int XS = 72;  // padded half-row stride (shorts): 144B -> 2-way bank alias (free)
    __shared__ short Xs[TN * XS];
    __shared__ short Ws[M * XS];
    int tid = threadIdx.x;
    int node0 = tileIdx * TN;

    constexpr int CT = M / 16;
    int w = tid >> 6;
    int lane = tid & 63;
    int l15 = lane & 15;
    int quad = lane >> 4;
    f32x4 acc[CT] = {};

#pragma unroll
    for (int h = 0; h < 2; ++h) {
        if (h) __syncthreads();  // all waves done reading previous half
        // stage W half: M rows x 64 shorts (128B contiguous per row)
        for (int q = tid; q < M * 8; q += 256) {
            int row = q >> 3, c = q & 7;
            uint4 v = *(const uint4*)((const short*)Wt + row * K + h * KH + c * 8);
            *(uint4*)(Ws + row * XS + c * 8) = v;
        }
        // stage X half
        if (!XBF) {
            const float* X = (const float*)Xv;
            int row = tid >> 2, part = tid & 3;  // 4 threads/row, 16 floats each
            int gn = node0 + row;
#pragma unroll
            for (int c = 0; c < 4; ++c) {
                int kl = part * 16 + c * 4;  // local k within half
                float4 v = (gn < n) ? *(const float4*)(X + (size_t)gn * K + h * KH + kl)
                                    : float4{0, 0, 0, 0};
                uint2 p = {pack2bf(v.x, v.y), pack2bf(v.z, v.w)};
                *(uint2*)(Xs + row * XS + kl) = p;
            }
        } else {
            const short* X = (const short*)Xv;
            for (int q = tid; q < TN * 8; q += 256) {
                int row = q >> 3, c = q & 7;
                int gn = node0 + row;
                uint4 v = (gn < n) ? *(const uint4*)(X + (size_t)gn * K + h * KH + c * 8)
                                   : uint4{0, 0, 0, 0};
                *(uint4*)(Xs + row * XS + c * 8) = v;
            }
        }
        __syncthreads();

        const short* xrow = Xs + (w * 16 + l15) * XS + quad * 8;
#pragma unroll
        for (int kk = 0; kk < 2; ++kk) {
            bf16x8 a = *(const bf16x8*)(xrow + kk * 32);
#pragma unroll
            for (int ct = 0; ct < CT; ++ct) {
                bf16x8 b = *(const bf16x8*)(Ws + (ct * 16 + l15) * XS + quad * 8 + kk * 32);
                acc[ct] = __builtin_amdgcn_mfma_f32_16x16x32_bf16(a, b, acc[ct], 0, 0, 0);
            }
        }
    }

#pragma unroll
    for (int ct = 0; ct < CT; ++ct) {
#pragma unroll
        for (int r = 0; r < 4; ++r) {
            int gn = node0 + w * 16 + quad * 4 + r;
            if (gn < n) H[(size_t)gn * M + ct * 16 + l15] = f2bf(acc[ct][r]);
        }
    }
}

// ===== fused: csr_fill (atomic-free) + layer-1 GEMM, role-INTERLEAVED =====
// Groups of 5 blocks: r<3 -> fill block g*3+r, else gemm tile g*2+(r-3).
// Every CU holds both latency-bound fill waves and MFMA waves concurrently.
__global__ __launch_bounds__(256) void csr_gemm1(
    const int* __restrict__ src, const int* __restrict__ dst, const float* __restrict__ dinv,
    const int* __restrict__ rowstart, const int* __restrict__ rank,
    int2* __restrict__ adjw, const float* __restrict__ x,
    const ushort16* __restrict__ W1t, ushort16* __restrict__ H, int n) {
    int bid = blockIdx.x;
    int g = bid / 5, r = bid % 5;
    if (r < 3) {
        int fb = g * 3 + r;
        if (fb >= NB_FILL) return;
        int e = fb * 256 + threadIdx.x;
        if (e < N_POS) {
            int s = src[e], d = dst[e];
            int p = rowstart[d] + rank[e];
            adjw[p] = int2{s, __float_as_int(dinv[s] * dinv[d])};
        }
    } else {
        int gb = g * 2 + (r - 3);
        if (gb >= NB_GEMM1) return;
        gemm_tile<HIDDEN, false>(x, W1t, H, n, gb);
    }
}

// ===== layer-1 aggregation body for one node (F=128, +bias+relu), 16 lanes =====
__device__ __forceinline__ uint4 agg_node128(int node, int l, const int* __restrict__ rowstart,
                                             const int2* __restrict__ adjw,
                                             const float* __restrict__ dinv,
                                             const ushort16* __restrict__ H,
                                             const float* __restrict__ bias) {
    float dn = dinv[node];
    int rs = rowstart[node], re = rowstart[node + 1];
    int deg = re - rs;
    int pc = (deg > 0) ? rs : (rs > 0 ? rs - 1 : 0);  // safe clamp index
    uint4 h[8];
    float wv[8];
#pragma unroll
    for (int j = 0; j < 8; ++j) {
        int p = (rs + j < re) ? rs + j : pc;
        int2 e = adjw[p];
        h[j] = *(const uint4*)(H + (size_t)e.x * 128 + l * 8);
        wv[j] = (j < deg) ? __int_as_float(e.y) : 0.0f;
    }
    float s0[8] = {}, s1[8] = {};
#pragma unroll
    for (int j = 0; j < 8; j += 2) {
        s0[0] += bf_lo(h[j].x) * wv[j]; s0[1] += bf_hi(h[j].x) * wv[j];
        s0[2] += bf_lo(h[j].y) * wv[j]; s0[3] += bf_hi(h[j].y) * wv[j];
        s0[4] += bf_lo(h[j].z) * wv[j]; s0[5] += bf_hi(h[j].z) * wv[j];
        s0[6] += bf_lo(h[j].w) * wv[j]; s0[7] += bf_hi(h[j].w) * wv[j];
        s1[0] += bf_lo(h[j + 1].x) * wv[j + 1]; s1[1] += bf_hi(h[j + 1].x) * wv[j + 1];
        s1[2] += bf_lo(h[j + 1].y) * wv[j + 1]; s1[3] += bf_hi(h[j + 1].y) * wv[j + 1];
        s1[4] += bf_lo(h[j + 1].z) * wv[j + 1]; s1[5] += bf_hi(h[j + 1].z) * wv[j + 1];
        s1[6] += bf_lo(h[j + 1].w) * wv[j + 1]; s1[7] += bf_hi(h[j + 1].w) * wv[j + 1];
    }
    for (int p = rs + 8; p < re; ++p) {
        int2 e = adjw[p];
        float w = __int_as_float(e.y);
        uint4 hh = *(const uint4*)(H + (size_t)e.x * 128 + l * 8);
        s0[0] += bf_lo(hh.x) * w; s0[1] += bf_hi(hh.x) * w;
        s0[2] += bf_lo(hh.y) * w; s0[3] += bf_hi(hh.y) * w;
        s0[4] += bf_lo(hh.z) * w; s0[5] += bf_hi(hh.z) * w;
        s0[6] += bf_lo(hh.w) * w; s0[7] += bf_hi(hh.w) * w;
    }
    uint4 hv = *(const uint4*)(H + (size_t)node * 128 + l * 8);
    float4 bv0 = *(const float4*)(bias + l * 8);
    float4 bv1 = *(const float4*)(bias + l * 8 + 4);
    float d2 = dn * dn;
    float hs[8] = {bf_lo(hv.x), bf_hi(hv.x), bf_lo(hv.y), bf_hi(hv.y),
                   bf_lo(hv.z), bf_hi(hv.z), bf_lo(hv.w), bf_hi(hv.w)};
    float bb[8] = {bv0.x, bv0.y, bv0.z, bv0.w, bv1.x, bv1.y, bv1.z, bv1.w};
    float v[8];
#pragma unroll
    for (int j = 0; j < 8; ++j) {
        v[j] = fmaxf(s0[j] + s1[j] + hs[j] * d2 + bb[j], 0.0f);  // relu (layer 1)
    }
    return uint4{pack2bf(v[0], v[1]), pack2bf(v[2], v[3]), pack2bf(v[4], v[5]),
                 pack2bf(v[6], v[7])};
}

// ===== fused: layer-1 agg (+bias+relu) -> LDS -> layer-2 GEMM =====
// 64 nodes/block, 256 threads. Z never touches global memory. (verified -6us, r1)
// W2 is NOT LDS-staged: each fragment read once per block, W2t (16KB) is
// L1-resident -> direct global reads. LDS = Zs only (17.4KB) -> 8 blocks/CU;
// launch_bounds(256,8) caps VGPR<=64 to make 32 waves/CU reachable.
#define ZS 136  // padded row stride (shorts); 272B, 16B-aligned
__global__ __launch_bounds__(256, 8) void agg1_gemm2(
    const int* __restrict__ rowstart, const int2* __restrict__ adjw,
    const float* __restrict__ dinv, const ushort16* __restrict__ H,
    const float* __restrict__ b1, const ushort16* __restrict__ W2t,
    ushort16* __restrict__ h2, int n) {
    __shared__ __align__(16) short Zs[64 * ZS];
    int tid = threadIdx.x;
    int node0 = blockIdx.x * 64;

    // layer-1 aggregation for 64 nodes: 16 groups x 16 lanes, 4 nodes each
    int g = tid >> 4, l = tid & 15;
#pragma unroll 1
    for (int it = 0; it < 4; ++it) {
        int row = g * 4 + it;
        int node = node0 + row;
        uint4 z = (node < n) ? agg_node128(node, l, rowstart, adjw, dinv, H, b1)
                             : uint4{0, 0, 0, 0};
        *(uint4*)(Zs + row * ZS + l * 8) = z;
    }
    __syncthreads();

    // GEMM: h2[64 x 64] = Zs @ W2 (16 MFMAs per wave); B read direct from L1/L2
    int w = tid >> 6, lane = tid & 63, l15 = lane & 15, quad = lane >> 4;
    f32x4 acc[4] = {};
    const short* zrow = Zs + (w * 16 + l15) * ZS + quad * 8;
    const short* wbase = (const short*)W2t + l15 * 128 + quad * 8;
#pragma unroll
    for (int kk = 0; kk < 4; ++kk) {
        bf16x8 a = *(const bf16x8*)(zrow + kk * 32);
#pragma unroll
        for (int ct = 0; ct < 4; ++ct) {
            bf16x8 b = *(const bf16x8*)(wbase + ct * 16 * 128 + kk * 32);
            acc[ct] = __builtin_amdgcn_mfma_f32_16x16x32_bf16(a, b, acc[ct], 0, 0, 0);
        }
    }
#pragma unroll
    for (int ct = 0; ct < 4; ++ct) {
#pragma unroll
        for (int r = 0; r < 4; ++r) {
            int gn = node0 + w * 16 + quad * 4 + r;
            if (gn < n) h2[(size_t)gn * OUT_CH + ct * 16 + l15] = f2bf(acc[ct][r]);
        }
    }
}

// ========= pull aggregation + self-loop + bias (+relu), bf16 H/Z =========
// FOUR nodes per wave (16 lanes each). Predicated straight-line 8-edge block.
template <int F, bool RELU>
__global__ void agg_pull(const int* __restrict__ rowstart, const int2* __restrict__ adjw,
                         const float* __restrict__ dinv, const ushort16* __restrict__ H,
                         const float* __restrict__ bias, ushort16* __restrict__ Z, int n) {
    int g = threadIdx.x >> 4;  // 16-lane group
    int l = threadIdx.x & 15;
    int node = blockIdx.x * (blockDim.x >> 4) + g;
    if (node >= n) return;
    float dn = dinv[node];
    int rs = rowstart[node], re = rowstart[node + 1];
    int deg = re - rs;
    int pc = (deg > 0) ? rs : (rs > 0 ? rs - 1 : 0);  // safe clamp index
    if (F == 128) {
        uint4 h[8];
        float wv[8];
#pragma unroll
        for (int j = 0; j < 8; ++j) {
            int p = (rs + j < re) ? rs + j : pc;
            int2 e = adjw[p];
            h[j] = *(const uint4*)(H + (size_t)e.x * F + l * 8);
            wv[j] = (j < deg) ? __int_as_float(e.y) : 0.0f;
        }
        float s0[8] = {}, s1[8] = {};
#pragma unroll
        for (int j = 0; j < 8; j += 2) {
            s0[0] += bf_lo(h[j].x) * wv[j]; s0[1] += bf_hi(h[j].x) * wv[j];
            s0[2] += bf_lo(h[j].y) * wv[j]; s0[3] += bf_hi(h[j].y) * wv[j];
            s0[4] += bf_lo(h[j].z) * wv[j]; s0[5] += bf_hi(h[j].z) * wv[j];
            s0[6] += bf_lo(h[j].w) * wv[j]; s0[7] += bf_hi(h[j].w) * wv[j];
            s1[0] += bf_lo(h[j + 1].x) * wv[j + 1]; s1[1] += bf_hi(h[j + 1].x) * wv[j + 1];
            s1[2] += bf_lo(h[j + 1].y) * wv[j + 1]; s1[3] += bf_hi(h[j + 1].y) * wv[j + 1];
            s1[4] += bf_lo(h[j + 1].z) * wv[j + 1]; s1[5] += bf_hi(h[j + 1].z) * wv[j + 1];
            s1[6] += bf_lo(h[j + 1].w) * wv[j + 1]; s1[7] += bf_hi(h[j + 1].w) * wv[j + 1];
        }
        for (int p = rs + 8; p < re; ++p) {
            int2 e = adjw[p];
            float w = __int_as_float(e.y);
            uint4 hh = *(const uint4*)(H + (size_t)e.x * F + l * 8);
            s0[0] += bf_lo(hh.x) * w; s0[1] += bf_hi(hh.x) * w;
            s0[2] += bf_lo(hh.y) * w; s0[3] += bf_hi(hh.y) * w;
            s0[4] += bf_lo(hh.z) * w; s0[5] += bf_hi(hh.z) * w;
            s0[6] += bf_lo(hh.w) * w; s0[7] += bf_hi(hh.w) * w;
        }
        uint4 hv = *(const uint4*)(H + (size_t)node * F + l * 8);
        float4 bv0 = *(const float4*)(bias + l * 8);
        float4 bv1 = *(const float4*)(bias + l * 8 + 4);
        float d2 = dn * dn;
        float hs[8] = {bf_lo(hv.x), bf_hi(hv.x), bf_lo(hv.y), bf_hi(hv.y),
                       bf_lo(hv.z), bf_hi(hv.z), bf_lo(hv.w), bf_hi(hv.w)};
        float bb[8] = {bv0.x, bv0.y, bv0.z, bv0.w, bv1.x, bv1.y, bv1.z, bv1.w};
        float v[8];
#pragma unroll
        for (int j = 0; j < 8; ++j) {
            v[j] = s0[j] + s1[j] + hs[j] * d2 + bb[j];
            if (RELU) v[j] = fmaxf(v[j], 0.0f);
        }
        *(uint4*)(Z + (size_t)node * F + l * 8) =
            uint4{pack2bf(v[0], v[1]), pack2bf(v[2], v[3]), pack2bf(v[4], v[5]),
                  pack2bf(v[6], v[7])};
    } else {  // F == 64
        uint2 h[8];
        float wv[8];
#pragma unroll
        for (int j = 0; j < 8; ++j) {
            int p = (rs + j < re) ? rs + j : pc;
            int2 e = adjw[p];
            h[j] = *(const uint2*)(H + (size_t)e.x * F + l * 4);
            wv[j] = (j < deg) ? __int_as_float(e.y) : 0.0f;
        }
        float s0[4] = {}, s1[4] = {};
#pragma unroll
        for (int j = 0; j < 8; j += 2) {
            s0[0] += bf_lo(h[j].x) * wv[j]; s0[1] += bf_hi(h[j].x) * wv[j];
            s0[2] += bf_lo(h[j].y) * wv[j]; s0[3] += bf_hi(h[j].y) * wv[j];
            s1[0] += bf_lo(h[j + 1].x) * wv[j + 1]; s1[1] += bf_hi(h[j + 1].x) * wv[j + 1];
            s1[2] += bf_lo(h[j + 1].y) * wv[j + 1]; s1[3] += bf_hi(h[j + 1].y) * wv[j + 1];
        }
        for (int p = rs + 8; p < re; ++p) {
            int2 e = adjw[p];
            float w = __int_as_float(e.y);
            uint2 hh = *(const uint2*)(H + (size_t)e.x * F + l * 4);
            s0[0] += bf_lo(hh.x) * w; s0[1] += bf_hi(hh.x) * w;
            s0[2] += bf_lo(hh.y) * w; s0[3] += bf_hi(hh.y) * w;
        }
        uint2 hv = *(const uint2*)(H + (size_t)node * F + l * 4);
        float4 bv = *(const float4*)(bias + l * 4);
        float d2 = dn * dn;
        float hs[4] = {bf_lo(hv.x), bf_hi(hv.x), bf_lo(hv.y), bf_hi(hv.y)};
        float bb[4] = {bv.x, bv.y, bv.z, bv.w};
        float v[4];
#pragma unroll
        for (int j = 0; j < 4; ++j) {
            v[j] = s0[j] + s1[j] + hs[j] * d2 + bb[j];
            if (RELU) v[j] = fmaxf(v[j], 0.0f);
        }
        *(uint2*)(Z + (size_t)node * F + l * 4) = uint2{pack2bf(v[0], v[1]), pack2bf(v[2], v[3])};
    }
}

// ===== decode via MFMA: 32 edges per wave (two 16-edge groups) =====
__global__ void decode_mfma(const int* __restrict__ pos, const int* __restrict__ neg,
                            const short* __restrict__ Z, float* __restrict__ out) {
    int wid = threadIdx.x >> 6;
    int lane = threadIdx.x & 63;
    int l15 = lane & 15;
    int quad = lane >> 4;
    int e0 = (blockIdx.x * 4 + wid) * 32;
    if (e0 >= N_POS + N_NEG) return;
    const int* bp = (e0 < N_POS) ? pos : (neg - N_POS);
    int eA = e0 + l15;
    int eB = e0 + 16 + l15;
    int aA = bp[eA], bA = bp[600000 + eA];
    int aB = bp[eB], bB = bp[600000 + eB];

    const short* zaA = Z + (size_t)aA * OUT_CH + quad * 8;
    const short* zbA = Z + (size_t)bA * OUT_CH + quad * 8;
    const short* zaB = Z + (size_t)aB * OUT_CH + quad * 8;
    const short* zbB = Z + (size_t)bB * OUT_CH + quad * 8;
    bf16x8 a0A = *(const bf16x8*)(zaA);
    bf16x8 a1A = *(const bf16x8*)(zaA + 32);
    bf16x8 b0A = *(const bf16x8*)(zbA);
    bf16x8 b1A = *(const bf16x8*)(zbA + 32);
    bf16x8 a0B = *(const bf16x8*)(zaB);
    bf16x8 a1B = *(const bf16x8*)(zaB + 32);
    bf16x8 b0B = *(const bf16x8*)(zbB);
    bf16x8 b1B = *(const bf16x8*)(zbB + 32);

    f32x4 accA = {}, accB = {};
    accA = __builtin_amdgcn_mfma_f32_16x16x32_bf16(a0A, b0A, accA, 0, 0, 0);
    accB = __builtin_amdgcn_mfma_f32_16x16x32_bf16(a0B, b0B, accB, 0, 0, 0);
    accA = __builtin_amdgcn_mfma_f32_16x16x32_bf16(a1A, b1A, accA, 0, 0, 0);
    accB = __builtin_amdgcn_mfma_f32_16x16x32_bf16(a1B, b1B, accB, 0, 0, 0);

    if (quad == (l15 >> 2)) {
        out[eA] = accA[l15 & 3];
        out[eB] = accB[l15 & 3];
    }
}

extern "C" void kernel_launch(void* const* d_in, const int* in_sizes, int n_in,
                              void* d_out, int out_size, void* d_ws, size_t ws_size,
                              hipStream_t stream) {
    const float* x = (const float*)d_in[0];
    const int* pos = (const int*)d_in[1];  // row0 = src, row1 = dst
    const int* neg = (const int*)d_in[2];
    const float* W1 = (const float*)d_in[3];
    const float* b1 = (const float*)d_in[4];
    const float* W2 = (const float*)d_in[5];
    const float* b2 = (const float*)d_in[6];
    float* out = (float*)d_out;

    // workspace layout (bf16 intermediates)
    ushort16* A = (ushort16*)d_ws;                      // H [N,128]; later z2 [N,64]
    ushort16* B = A + (size_t)N_NODES * 128;            // h2 [N,64]
    float* dinv = (float*)(B + (size_t)N_NODES * 128);  // [N]
    int* hist = (int*)(dinv + N_NODES);                 // [N]
    int* rowstart = hist + N_NODES;                     // [N+1]
    int2* adjw = (int2*)(rowstart + N_NODES + 1);       // [N_POS] (adj, wgt) pairs
    int* partials = (int*)(adjw + N_POS);               // [128]
    ushort16* W1t = (ushort16*)(partials + 128);        // [128*128]
    ushort16* W2t = W1t + 128 * 128;                    // [64*128]
    // rank[N_POS] overlays B: rank is dead before agg1_gemm2 writes h2 into B
    // (csr_gemm1 completes first; same stream).
    int* rank = (int*)B;

    const int* pos_src = pos;
    const int* pos_dst = pos + N_POS;

    constexpr int NB_SCAN = (N_NODES + 1023) / 1024;  // 98

    // ---- CSR build + dinv + weight convert ----
    hipMemsetAsync(hist, 0, N_NODES * sizeof(int), stream);
    hist_wt<<<NB_HIST + 96, 256, 0, stream>>>(pos_dst, hist, rank, W1, W2, W1t, W2t);
    scan_reduce<<<NB_SCAN, 256, 0, stream>>>(hist, partials, N_NODES);
    scan_final<<<NB_SCAN, 256, 0, stream>>>(hist, partials, rowstart, dinv, N_NODES);

    // ---- csr_fill (atomic-free) + layer-1 GEMM, role-interleaved ----
    csr_gemm1<<<NB_MIX, 256, 0, stream>>>(pos_src, pos_dst, dinv, rowstart, rank,
                                          adjw, x, W1t, A, N_NODES);

    // ---- fused layer-1 aggregation + layer-2 GEMM: reads H(=A), writes h2(=B) ----
    agg1_gemm2<<<(N_NODES + 63) / 64, 256, 0, stream>>>(rowstart, adjw, dinv, A, b1, W2t, B,
                                                        N_NODES);

    // ---- layer-2 aggregation: reads h2(=B), writes z2(=A) ----
    agg_pull<OUT_CH, false><<<(N_NODES + 15) / 16, 256, 0, stream>>>(rowstart, adjw, dinv, B, b2,
                                                                     A, N_NODES);

    // ---- decode (32 edges/wave, 128/block) ----
    decode_mfma<<<(N_POS + N_NEG) / 128, 256, 0, stream>>>(pos, neg, (const short*)A, out);
}

// Round 6
// 258.035 us; speedup vs baseline: 1.0094x; 1.0094x over previous
//
#include <hip/hip_runtime.h>

#define N_NODES 100000
#define IN_CH 128
#define HIDDEN 128
#define OUT_CH 64
#define N_POS 600000
#define N_NEG 600000

typedef unsigned int uint32;
typedef unsigned short ushort16;
typedef __attribute__((ext_vector_type(8))) short bf16x8;
typedef __attribute__((ext_vector_type(4))) float f32x4;

// ---- bf16 helpers ----
__device__ inline float bf_lo(uint32 u) {
    union { uint32 i; float f; } v;
    v.i = u << 16;
    return v.f;
}
__device__ inline float bf_hi(uint32 u) {
    union { uint32 i; float f; } v;
    v.i = u & 0xffff0000u;
    return v.f;
}
__device__ inline ushort16 f2bf(float f) {
    union { uint32 i; float f; } v;
    v.f = f;
    uint32 r = v.i + 0x7fffu + ((v.i >> 16) & 1u);  // round-to-nearest-even
    return (ushort16)(r >> 16);
}
__device__ inline uint32 pack2bf(float a, float b) {
    return (uint32)f2bf(a) | ((uint32)f2bf(b) << 16);
}

#define NB_HIST ((N_POS + 255) / 256)   // 2344 -- 1 edge/thread (measured best, r0 vs r1/r2)
#define NB_FILL ((N_POS + 255) / 256)   // 2344 -- sequential layout (interleave was neutral, r5)
#define NB_GEMM1 ((N_NODES + 63) / 64)  // 1563

// ===== fused: hist_count (+rank persist) + weight transpose/convert =====
// The atomicAdd's return value IS the edge's rank among same-dst edges.
// Persisting it (coalesced 4B store) lets csr-fill compute its slot with
// pure loads: p = rowstart[d] + rank[e]. No atomic, no cursor in fill.
// (verified -13us on csr_gemm1, r4)
__global__ void hist_wt(const int* __restrict__ dst, int* __restrict__ hist,
                        int* __restrict__ rank,
                        const float* __restrict__ W1, const float* __restrict__ W2,
                        ushort16* __restrict__ W1t, ushort16* __restrict__ W2t) {
    if (blockIdx.x < NB_HIST) {
        int i = blockIdx.x * 256 + threadIdx.x;
        if (i < N_POS) rank[i] = atomicAdd(&hist[dst[i]], 1);
    } else {
        int i = (blockIdx.x - NB_HIST) * 256 + threadIdx.x;
        if (i < 128 * 128) {
            int n = i >> 7, k = i & 127;
            W1t[i] = f2bf(W1[k * 128 + n]);
        } else {
            int j = i - 128 * 128;
            if (j < 64 * 128) {
                int n = j >> 7, k = j & 127;
                W2t[j] = f2bf(W2[k * 64 + n]);
            }
        }
    }
}

__global__ void scan_reduce(const int* __restrict__ hist, int* __restrict__ partials, int n) {
    __shared__ int sdata[256];
    int b = blockIdx.x, t = threadIdx.x;
    int base = b * 1024;
    int s = 0;
    for (int i = t; i < 1024; i += 256) {
        int idx = base + i;
        s += (idx < n) ? hist[idx] : 0;
    }
    sdata[t] = s;
    __syncthreads();
    for (int off = 128; off > 0; off >>= 1) {
        if (t < off) sdata[t] += sdata[t + off];
        __syncthreads();
    }
    if (t == 0) partials[b] = sdata[0];
}

// scan_final computes its own partials-prefix (first wave). NB_SCAN = 98 <= 128.
__global__ void scan_final(const int* __restrict__ hist, const int* __restrict__ partials,
                           int* __restrict__ rowstart, float* __restrict__ dinv, int n) {
    __shared__ int tsum[256];
    __shared__ int base_sh;
    int t = threadIdx.x, b = blockIdx.x;
    if (t < 64) {
        int s0 = (t < b) ? partials[t] : 0;
        int i2 = t + 64;
        int s1 = (i2 < b && i2 < 98) ? partials[i2] : 0;
        int s = s0 + s1;
#pragma unroll
        for (int off = 32; off > 0; off >>= 1) s += __shfl_down(s, off, 64);
        if (t == 0) base_sh = s;
    }
    int base = b * 1024 + t * 4;
    int v[4];
    int s = 0;
#pragma unroll
    for (int j = 0; j < 4; j++) {
        int i = base + j;
        v[j] = (i < n) ? hist[i] : 0;
        s += v[j];
    }
    tsum[t] = s;
    __syncthreads();
    for (int off = 1; off < 256; off <<= 1) {
        int a = (t >= off) ? tsum[t - off] : 0;
        __syncthreads();
        tsum[t] += a;
        __syncthreads();
    }
    int offset = base_sh + (tsum[t] - s);
#pragma unroll
    for (int j = 0; j < 4; j++) {
        int i = base + j;
        if (i < n) {
            rowstart[i] = offset;
            dinv[i] = rsqrtf((float)v[j] + 1.0f);
            offset += v[j];
        }
    }
    if (b == 0 && t == 0) rowstart[n] = N_POS;
}

// ===== shared GEMM tile body: H_bf16[node0..node0+64, M] = X @ W =====
// K-split double staging: LDS holds only a K/2 slice of X-tile and W at a
// time (27.6KB for M=128 vs 52KB full) so co-scheduled scatter blocks keep
// ~5 blocks/CU occupancy. W staged through LDS (coalesced once, broadcast
// reads) — heavy-reuse case; direct-global W was a 1.7x regression here.
template <int M, bool XBF>
__device__ __forceinline__ void gemm_tile(const void* __restrict__ Xv,
                                          const ushort16* __restrict__ Wt,
                                          ushort16* __restrict__ H, int n, int tileIdx) {
    constexpr int K = 128;
    constexpr int TN = 64;
    constexpr int KH = 64;  // K half
    constexpr int XS = 72;  // padded half-row stride (shorts): 144B -> 2-way bank alias (free)
    __shared__ short Xs[TN * XS];
    __shared__ short Ws[M * XS];
    int tid = threadIdx.x;
    int node0 = tileIdx * TN;

    constexpr int CT = M / 16;
    int w = tid >> 6;
    int lane = tid & 63;
    int l15 = lane & 15;
    int quad = lane >> 4;
    f32x4 acc[CT] = {};

#pragma unroll
    for (int h = 0; h < 2; ++h) {
        if (h) __syncthreads();  // all waves done reading previous half
        // stage W half: M rows x 64 shorts (128B contiguous per row)
        for (int q = tid; q < M * 8; q += 256) {
            int row = q >> 3, c = q & 7;
            uint4 v = *(const uint4*)((const short*)Wt + row * K + h * KH + c * 8);
            *(uint4*)(Ws + row * XS + c * 8) = v;
        }
        // stage X half
        if (!XBF) {
            const float* X = (const float*)Xv;
            int row = tid >> 2, part = tid & 3;  // 4 threads/row, 16 floats each
            int gn = node0 + row;
#pragma unroll
            for (int c = 0; c < 4; ++c) {
                int kl = part * 16 + c * 4;  // local k within half
                float4 v = (gn < n) ? *(const float4*)(X + (size_t)gn * K + h * KH + kl)
                                    : float4{0, 0, 0, 0};
                uint2 p = {pack2bf(v.x, v.y), pack2bf(v.z, v.w)};
                *(uint2*)(Xs + row * XS + kl) = p;
            }
        } else {
            const short* X = (const short*)Xv;
            for (int q = tid; q < TN * 8; q += 256) {
                int row = q >> 3, c = q & 7;
                int gn = node0 + row;
                uint4 v = (gn < n) ? *(const uint4*)(X + (size_t)gn * K + h * KH + c * 8)
                                   : uint4{0, 0, 0, 0};
                *(uint4*)(Xs + row * XS + c * 8) = v;
            }
        }
        __syncthreads();

        const short* xrow = Xs + (w * 16 + l15) * XS + quad * 8;
#pragma unroll
        for (int kk = 0; kk < 2; ++kk) {
            bf16x8 a = *(const bf16x8*)(xrow + kk * 32);
#pragma unroll
            for (int ct = 0; ct < CT; ++ct) {
                bf16x8 b = *(const bf16x8*)(Ws + (ct * 16 + l15) * XS + quad * 8 + kk * 32);
                acc[ct] = __builtin_amdgcn_mfma_f32_16x16x32_bf16(a, b, acc[ct], 0, 0, 0);
            }
        }
    }

#pragma unroll
    for (int ct = 0; ct < CT; ++ct) {
#pragma unroll
        for (int r = 0; r < 4; ++r) {
            int gn = node0 + w * 16 + quad * 4 + r;
            if (gn < n) H[(size_t)gn * M + ct * 16 + l15] = f2bf(acc[ct][r]);
        }
    }
}

// ===== fused: csr_fill (atomic-free, pure loads) + layer-1 GEMM (MFMA-bound) =====
// Fill slot = rowstart[d] + rank[e] (rank persisted by hist). Sequential block
// layout (r5 interleave was neutral). Measured 41us (r4).
__global__ __launch_bounds__(256) void csr_gemm1(
    const int* __restrict__ src, const int* __restrict__ dst, const float* __restrict__ dinv,
    const int* __restrict__ rowstart, const int* __restrict__ rank,
    int2* __restrict__ adjw, const float* __restrict__ x,
    const ushort16* __restrict__ W1t, ushort16* __restrict__ H, int n) {
    if (blockIdx.x < NB_FILL) {
        int e = blockIdx.x * 256 + threadIdx.x;
        if (e < N_POS) {
            int s = src[e], d = dst[e];
            int p = rowstart[d] + rank[e];
            adjw[p] = int2{s, __float_as_int(dinv[s] * dinv[d])};
        }
    } else {
        gemm_tile<HIDDEN, false>(x, W1t, H, n, blockIdx.x - NB_FILL);
    }
}

// ===== layer-1 aggregation body for one node (F=128, +bias+relu), 16 lanes =====
__device__ __forceinline__ uint4 agg_node128(int node, int l, const int* __restrict__ rowstart,
                                             const int2* __restrict__ adjw,
                                             const float* __restrict__ dinv,
                                             const ushort16* __restrict__ H,
                                             const float* __restrict__ bias) {
    float dn = dinv[node];
    int rs = rowstart[node], re = rowstart[node + 1];
    int deg = re - rs;
    int pc = (deg > 0) ? rs : (rs > 0 ? rs - 1 : 0);  // safe clamp index
    uint4 h[8];
    float wv[8];
#pragma unroll
    for (int j = 0; j < 8; ++j) {
        int p = (rs + j < re) ? rs + j : pc;
        int2 e = adjw[p];
        h[j] = *(const uint4*)(H + (size_t)e.x * 128 + l * 8);
        wv[j] = (j < deg) ? __int_as_float(e.y) : 0.0f;
    }
    float s0[8] = {}, s1[8] = {};
#pragma unroll
    for (int j = 0; j < 8; j += 2) {
        s0[0] += bf_lo(h[j].x) * wv[j]; s0[1] += bf_hi(h[j].x) * wv[j];
        s0[2] += bf_lo(h[j].y) * wv[j]; s0[3] += bf_hi(h[j].y) * wv[j];
        s0[4] += bf_lo(h[j].z) * wv[j]; s0[5] += bf_hi(h[j].z) * wv[j];
        s0[6] += bf_lo(h[j].w) * wv[j]; s0[7] += bf_hi(h[j].w) * wv[j];
        s1[0] += bf_lo(h[j + 1].x) * wv[j + 1]; s1[1] += bf_hi(h[j + 1].x) * wv[j + 1];
        s1[2] += bf_lo(h[j + 1].y) * wv[j + 1]; s1[3] += bf_hi(h[j + 1].y) * wv[j + 1];
        s1[4] += bf_lo(h[j + 1].z) * wv[j + 1]; s1[5] += bf_hi(h[j + 1].z) * wv[j + 1];
        s1[6] += bf_lo(h[j + 1].w) * wv[j + 1]; s1[7] += bf_hi(h[j + 1].w) * wv[j + 1];
    }
    for (int p = rs + 8; p < re; ++p) {
        int2 e = adjw[p];
        float w = __int_as_float(e.y);
        uint4 hh = *(const uint4*)(H + (size_t)e.x * 128 + l * 8);
        s0[0] += bf_lo(hh.x) * w; s0[1] += bf_hi(hh.x) * w;
        s0[2] += bf_lo(hh.y) * w; s0[3] += bf_hi(hh.y) * w;
        s0[4] += bf_lo(hh.z) * w; s0[5] += bf_hi(hh.z) * w;
        s0[6] += bf_lo(hh.w) * w; s0[7] += bf_hi(hh.w) * w;
    }
    uint4 hv = *(const uint4*)(H + (size_t)node * 128 + l * 8);
    float4 bv0 = *(const float4*)(bias + l * 8);
    float4 bv1 = *(const float4*)(bias + l * 8 + 4);
    float d2 = dn * dn;
    float hs[8] = {bf_lo(hv.x), bf_hi(hv.x), bf_lo(hv.y), bf_hi(hv.y),
                   bf_lo(hv.z), bf_hi(hv.z), bf_lo(hv.w), bf_hi(hv.w)};
    float bb[8] = {bv0.x, bv0.y, bv0.z, bv0.w, bv1.x, bv1.y, bv1.z, bv1.w};
    float v[8];
#pragma unroll
    for (int j = 0; j < 8; ++j) {
        v[j] = fmaxf(s0[j] + s1[j] + hs[j] * d2 + bb[j], 0.0f);  // relu (layer 1)
    }
    return uint4{pack2bf(v[0], v[1]), pack2bf(v[2], v[3]), pack2bf(v[4], v[5]),
                 pack2bf(v[6], v[7])};
}

// ===== fused: layer-1 agg (+bias+relu) -> LDS -> layer-2 GEMM =====
// 64 nodes/block, 256 threads. Z never touches global memory. (verified -6us, r1)
// W2 NOT LDS-staged (16KB, L1-resident, read-once -> direct global). LDS = Zs
// only (17.4KB). launch_bounds(256,4): VGPR ~52 keeps the 8-deep gather batch
// in registers (r5's (256,8) cap -> VGPR 32 serialized the gathers, +4.5us);
// LDS now allows up to 8 blocks/CU anyway -> occupancy ~46% with full ILP.
#define ZS 136  // padded row stride (shorts); 272B, 16B-aligned
__global__ __launch_bounds__(256, 4) void agg1_gemm2(
    const int* __restrict__ rowstart, const int2* __restrict__ adjw,
    const float* __restrict__ dinv, const ushort16* __restrict__ H,
    const float* __restrict__ b1, const ushort16* __restrict__ W2t,
    ushort16* __restrict__ h2, int n) {
    __shared__ __align__(16) short Zs[64 * ZS];
    int tid = threadIdx.x;
    int node0 = blockIdx.x * 64;

    // layer-1 aggregation for 64 nodes: 16 groups x 16 lanes, 4 nodes each
    int g = tid >> 4, l = tid & 15;
#pragma unroll 1
    for (int it = 0; it < 4; ++it) {
        int row = g * 4 + it;
        int node = node0 + row;
        uint4 z = (node < n) ? agg_node128(node, l, rowstart, adjw, dinv, H, b1)
                             : uint4{0, 0, 0, 0};
        *(uint4*)(Zs + row * ZS + l * 8) = z;
    }
    __syncthreads();

    // GEMM: h2[64 x 64] = Zs @ W2 (16 MFMAs per wave); B read direct from L1/L2
    int w = tid >> 6, lane = tid & 63, l15 = lane & 15, quad = lane >> 4;
    f32x4 acc[4] = {};
    const short* zrow = Zs + (w * 16 + l15) * ZS + quad * 8;
    const short* wbase = (const short*)W2t + l15 * 128 + quad * 8;
#pragma unroll
    for (int kk = 0; kk < 4; ++kk) {
        bf16x8 a = *(const bf16x8*)(zrow + kk * 32);
#pragma unroll
        for (int ct = 0; ct < 4; ++ct) {
            bf16x8 b = *(const bf16x8*)(wbase + ct * 16 * 128 + kk * 32);
            acc[ct] = __builtin_amdgcn_mfma_f32_16x16x32_bf16(a, b, acc[ct], 0, 0, 0);
        }
    }
#pragma unroll
    for (int ct = 0; ct < 4; ++ct) {
#pragma unroll
        for (int r = 0; r < 4; ++r) {
            int gn = node0 + w * 16 + quad * 4 + r;
            if (gn < n) h2[(size_t)gn * OUT_CH + ct * 16 + l15] = f2bf(acc[ct][r]);
        }
    }
}

// ========= pull aggregation + self-loop + bias (+relu), bf16 H/Z =========
// FOUR nodes per wave (16 lanes each). Predicated straight-line 8-edge block.
template <int F, bool RELU>
__global__ void agg_pull(const int* __restrict__ rowstart, const int2* __restrict__ adjw,
                         const float* __restrict__ dinv, const ushort16* __restrict__ H,
                         const float* __restrict__ bias, ushort16* __restrict__ Z, int n) {
    int g = threadIdx.x >> 4;  // 16-lane group
    int l = threadIdx.x & 15;
    int node = blockIdx.x * (blockDim.x >> 4) + g;
    if (node >= n) return;
    float dn = dinv[node];
    int rs = rowstart[node], re = rowstart[node + 1];
    int deg = re - rs;
    int pc = (deg > 0) ? rs : (rs > 0 ? rs - 1 : 0);  // safe clamp index
    if (F == 128) {
        uint4 h[8];
        float wv[8];
#pragma unroll
        for (int j = 0; j < 8; ++j) {
            int p = (rs + j < re) ? rs + j : pc;
            int2 e = adjw[p];
            h[j] = *(const uint4*)(H + (size_t)e.x * F + l * 8);
            wv[j] = (j < deg) ? __int_as_float(e.y) : 0.0f;
        }
        float s0[8] = {}, s1[8] = {};
#pragma unroll
        for (int j = 0; j < 8; j += 2) {
            s0[0] += bf_lo(h[j].x) * wv[j]; s0[1] += bf_hi(h[j].x) * wv[j];
            s0[2] += bf_lo(h[j].y) * wv[j]; s0[3] += bf_hi(h[j].y) * wv[j];
            s0[4] += bf_lo(h[j].z) * wv[j]; s0[5] += bf_hi(h[j].z) * wv[j];
            s0[6] += bf_lo(h[j].w) * wv[j]; s0[7] += bf_hi(h[j].w) * wv[j];
            s1[0] += bf_lo(h[j + 1].x) * wv[j + 1]; s1[1] += bf_hi(h[j + 1].x) * wv[j + 1];
            s1[2] += bf_lo(h[j + 1].y) * wv[j + 1]; s1[3] += bf_hi(h[j + 1].y) * wv[j + 1];
            s1[4] += bf_lo(h[j + 1].z) * wv[j + 1]; s1[5] += bf_hi(h[j + 1].z) * wv[j + 1];
            s1[6] += bf_lo(h[j + 1].w) * wv[j + 1]; s1[7] += bf_hi(h[j + 1].w) * wv[j + 1];
        }
        for (int p = rs + 8; p < re; ++p) {
            int2 e = adjw[p];
            float w = __int_as_float(e.y);
            uint4 hh = *(const uint4*)(H + (size_t)e.x * F + l * 8);
            s0[0] += bf_lo(hh.x) * w; s0[1] += bf_hi(hh.x) * w;
            s0[2] += bf_lo(hh.y) * w; s0[3] += bf_hi(hh.y) * w;
            s0[4] += bf_lo(hh.z) * w; s0[5] += bf_hi(hh.z) * w;
            s0[6] += bf_lo(hh.w) * w; s0[7] += bf_hi(hh.w) * w;
        }
        uint4 hv = *(const uint4*)(H + (size_t)node * F + l * 8);
        float4 bv0 = *(const float4*)(bias + l * 8);
        float4 bv1 = *(const float4*)(bias + l * 8 + 4);
        float d2 = dn * dn;
        float hs[8] = {bf_lo(hv.x), bf_hi(hv.x), bf_lo(hv.y), bf_hi(hv.y),
                       bf_lo(hv.z), bf_hi(hv.z), bf_lo(hv.w), bf_hi(hv.w)};
        float bb[8] = {bv0.x, bv0.y, bv0.z, bv0.w, bv1.x, bv1.y, bv1.z, bv1.w};
        float v[8];
#pragma unroll
        for (int j = 0; j < 8; ++j) {
            v[j] = s0[j] + s1[j] + hs[j] * d2 + bb[j];
            if (RELU) v[j] = fmaxf(v[j], 0.0f);
        }
        *(uint4*)(Z + (size_t)node * F + l * 8) =
            uint4{pack2bf(v[0], v[1]), pack2bf(v[2], v[3]), pack2bf(v[4], v[5]),
                  pack2bf(v[6], v[7])};
    } else {  // F == 64
        uint2 h[8];
        float wv[8];
#pragma unroll
        for (int j = 0; j < 8; ++j) {
            int p = (rs + j < re) ? rs + j : pc;
            int2 e = adjw[p];
            h[j] = *(const uint2*)(H + (size_t)e.x * F + l * 4);
            wv[j] = (j < deg) ? __int_as_float(e.y) : 0.0f;
        }
        float s0[4] = {}, s1[4] = {};
#pragma unroll
        for (int j = 0; j < 8; j += 2) {
            s0[0] += bf_lo(h[j].x) * wv[j]; s0[1] += bf_hi(h[j].x) * wv[j];
            s0[2] += bf_lo(h[j].y) * wv[j]; s0[3] += bf_hi(h[j].y) * wv[j];
            s1[0] += bf_lo(h[j + 1].x) * wv[j + 1]; s1[1] += bf_hi(h[j + 1].x) * wv[j + 1];
            s1[2] += bf_lo(h[j + 1].y) * wv[j + 1]; s1[3] += bf_hi(h[j + 1].y) * wv[j + 1];
        }
        for (int p = rs + 8; p < re; ++p) {
            int2 e = adjw[p];
            float w = __int_as_float(e.y);
            uint2 hh = *(const uint2*)(H + (size_t)e.x * F + l * 4);
            s0[0] += bf_lo(hh.x) * w; s0[1] += bf_hi(hh.x) * w;
            s0[2] += bf_lo(hh.y) * w; s0[3] += bf_hi(hh.y) * w;
        }
        uint2 hv = *(const uint2*)(H + (size_t)node * F + l * 4);
        float4 bv = *(const float4*)(bias + l * 4);
        float d2 = dn * dn;
        float hs[4] = {bf_lo(hv.x), bf_hi(hv.x), bf_lo(hv.y), bf_hi(hv.y)};
        float bb[4] = {bv.x, bv.y, bv.z, bv.w};
        float v[4];
#pragma unroll
        for (int j = 0; j < 4; ++j) {
            v[j] = s0[j] + s1[j] + hs[j] * d2 + bb[j];
            if (RELU) v[j] = fmaxf(v[j], 0.0f);
        }
        *(uint2*)(Z + (size_t)node * F + l * 4) = uint2{pack2bf(v[0], v[1]), pack2bf(v[2], v[3])};
    }
}

// ===== decode via MFMA: 32 edges per wave (two 16-edge groups) =====
__global__ void decode_mfma(const int* __restrict__ pos, const int* __restrict__ neg,
                            const short* __restrict__ Z, float* __restrict__ out) {
    int wid = threadIdx.x >> 6;
    int lane = threadIdx.x & 63;
    int l15 = lane & 15;
    int quad = lane >> 4;
    int e0 = (blockIdx.x * 4 + wid) * 32;
    if (e0 >= N_POS + N_NEG) return;
    const int* bp = (e0 < N_POS) ? pos : (neg - N_POS);
    int eA = e0 + l15;
    int eB = e0 + 16 + l15;
    int aA = bp[eA], bA = bp[600000 + eA];
    int aB = bp[eB], bB = bp[600000 + eB];

    const short* zaA = Z + (size_t)aA * OUT_CH + quad * 8;
    const short* zbA = Z + (size_t)bA * OUT_CH + quad * 8;
    const short* zaB = Z + (size_t)aB * OUT_CH + quad * 8;
    const short* zbB = Z + (size_t)bB * OUT_CH + quad * 8;
    bf16x8 a0A = *(const bf16x8*)(zaA);
    bf16x8 a1A = *(const bf16x8*)(zaA + 32);
    bf16x8 b0A = *(const bf16x8*)(zbA);
    bf16x8 b1A = *(const bf16x8*)(zbA + 32);
    bf16x8 a0B = *(const bf16x8*)(zaB);
    bf16x8 a1B = *(const bf16x8*)(zaB + 32);
    bf16x8 b0B = *(const bf16x8*)(zbB);
    bf16x8 b1B = *(const bf16x8*)(zbB + 32);

    f32x4 accA = {}, accB = {};
    accA = __builtin_amdgcn_mfma_f32_16x16x32_bf16(a0A, b0A, accA, 0, 0, 0);
    accB = __builtin_amdgcn_mfma_f32_16x16x32_bf16(a0B, b0B, accB, 0, 0, 0);
    accA = __builtin_amdgcn_mfma_f32_16x16x32_bf16(a1A, b1A, accA, 0, 0, 0);
    accB = __builtin_amdgcn_mfma_f32_16x16x32_bf16(a1B, b1B, accB, 0, 0, 0);

    if (quad == (l15 >> 2)) {
        out[eA] = accA[l15 & 3];
        out[eB] = accB[l15 & 3];
    }
}

extern "C" void kernel_launch(void* const* d_in, const int* in_sizes, int n_in,
                              void* d_out, int out_size, void* d_ws, size_t ws_size,
                              hipStream_t stream) {
    const float* x = (const float*)d_in[0];
    const int* pos = (const int*)d_in[1];  // row0 = src, row1 = dst
    const int* neg = (const int*)d_in[2];
    const float* W1 = (const float*)d_in[3];
    const float* b1 = (const float*)d_in[4];
    const float* W2 = (const float*)d_in[5];
    const float* b2 = (const float*)d_in[6];
    float* out = (float*)d_out;

    // workspace layout (bf16 intermediates)
    ushort16* A = (ushort16*)d_ws;                      // H [N,128]; later z2 [N,64]
    ushort16* B = A + (size_t)N_NODES * 128;            // h2 [N,64]
    float* dinv = (float*)(B + (size_t)N_NODES * 128);  // [N]
    int* hist = (int*)(dinv + N_NODES);                 // [N]
    int* rowstart = hist + N_NODES;                     // [N+1]
    int2* adjw = (int2*)(rowstart + N_NODES + 1);       // [N_POS] (adj, wgt) pairs
    int* partials = (int*)(adjw + N_POS);               // [128]
    ushort16* W1t = (ushort16*)(partials + 128);        // [128*128]
    ushort16* W2t = W1t + 128 * 128;                    // [64*128]
    // rank[N_POS] overlays B: rank is dead before agg1_gemm2 writes h2 into B
    // (csr_gemm1 completes first; same stream).
    int* rank = (int*)B;

    const int* pos_src = pos;
    const int* pos_dst = pos + N_POS;

    constexpr int NB_SCAN = (N_NODES + 1023) / 1024;  // 98

    // ---- CSR build + dinv + weight convert ----
    hipMemsetAsync(hist, 0, N_NODES * sizeof(int), stream);
    hist_wt<<<NB_HIST + 96, 256, 0, stream>>>(pos_dst, hist, rank, W1, W2, W1t, W2t);
    scan_reduce<<<NB_SCAN, 256, 0, stream>>>(hist, partials, N_NODES);
    scan_final<<<NB_SCAN, 256, 0, stream>>>(hist, partials, rowstart, dinv, N_NODES);

    // ---- csr_fill (atomic-free) + layer-1 GEMM fused (one launch) ----
    csr_gemm1<<<NB_FILL + NB_GEMM1, 256, 0, stream>>>(pos_src, pos_dst, dinv, rowstart, rank,
                                                      adjw, x, W1t, A, N_NODES);

    // ---- fused layer-1 aggregation + layer-2 GEMM: reads H(=A), writes h2(=B) ----
    agg1_gemm2<<<(N_NODES + 63) / 64, 256, 0, stream>>>(rowstart, adjw, dinv, A, b1, W2t, B,
                                                        N_NODES);

    // ---- layer-2 aggregation: reads h2(=B), writes z2(=A) ----
    agg_pull<OUT_CH, false><<<(N_NODES + 15) / 16, 256, 0, stream>>>(rowstart, adjw, dinv, B, b2,
                                                                     A, N_NODES);

    // ---- decode (32 edges/wave, 128/block) ----
    decode_mfma<<<(N_POS + N_NEG) / 128, 256, 0, stream>>>(pos, neg, (const short*)A, out);
}

// Round 7
// 257.865 us; speedup vs baseline: 1.0100x; 1.0007x over previous
//
#include <hip/hip_runtime.h>

#define N_NODES 100000
#define IN_CH 128
#define HIDDEN 128
#define OUT_CH 64
#define N_POS 600000
#define N_NEG 600000

typedef unsigned int uint32;
typedef unsigned short ushort16;
typedef __attribute__((ext_vector_type(8))) short bf16x8;
typedef __attribute__((ext_vector_type(4))) float f32x4;

// ---- bf16 helpers ----
__device__ inline float bf_lo(uint32 u) {
    union { uint32 i; float f; } v;
    v.i = u << 16;
    return v.f;
}
__device__ inline float bf_hi(uint32 u) {
    union { uint32 i; float f; } v;
    v.i = u & 0xffff0000u;
    return v.f;
}
__device__ inline ushort16 f2bf(float f) {
    union { uint32 i; float f; } v;
    v.f = f;
    uint32 r = v.i + 0x7fffu + ((v.i >> 16) & 1u);  // round-to-nearest-even
    return (ushort16)(r >> 16);
}
__device__ inline uint32 pack2bf(float a, float b) {
    return (uint32)f2bf(a) | ((uint32)f2bf(b) << 16);
}

#define NB_HIST ((N_POS + 255) / 256)   // 2344 -- 1 edge/thread (measured best, r0 vs r1/r2)
#define NB_FILL ((N_POS + 255) / 256)   // 2344 -- sequential layout (interleave was neutral, r5)
#define NB_GEMM1 ((N_NODES + 63) / 64)  // 1563

// ===== fused: hist_count (+rank persist) + weight transpose/convert =====
// atomicAdd's return value IS the edge's rank among same-dst edges; persisting
// it lets csr-fill compute its slot with pure loads. (verified -13us, r4)
__global__ void hist_wt(const int* __restrict__ dst, int* __restrict__ hist,
                        int* __restrict__ rank,
                        const float* __restrict__ W1, const float* __restrict__ W2,
                        ushort16* __restrict__ W1t, ushort16* __restrict__ W2t) {
    if (blockIdx.x < NB_HIST) {
        int i = blockIdx.x * 256 + threadIdx.x;
        if (i < N_POS) rank[i] = atomicAdd(&hist[dst[i]], 1);
    } else {
        int i = (blockIdx.x - NB_HIST) * 256 + threadIdx.x;
        if (i < 128 * 128) {
            int n = i >> 7, k = i & 127;
            W1t[i] = f2bf(W1[k * 128 + n]);
        } else {
            int j = i - 128 * 128;
            if (j < 64 * 128) {
                int n = j >> 7, k = j & 127;
                W2t[j] = f2bf(W2[k * 64 + n]);
            }
        }
    }
}

__global__ void scan_reduce(const int* __restrict__ hist, int* __restrict__ partials, int n) {
    __shared__ int sdata[256];
    int b = blockIdx.x, t = threadIdx.x;
    int base = b * 1024;
    int s = 0;
    for (int i = t; i < 1024; i += 256) {
        int idx = base + i;
        s += (idx < n) ? hist[idx] : 0;
    }
    sdata[t] = s;
    __syncthreads();
    for (int off = 128; off > 0; off >>= 1) {
        if (t < off) sdata[t] += sdata[t + off];
        __syncthreads();
    }
    if (t == 0) partials[b] = sdata[0];
}

// scan_final computes its own partials-prefix (first wave). NB_SCAN = 98 <= 128.
__global__ void scan_final(const int* __restrict__ hist, const int* __restrict__ partials,
                           int* __restrict__ rowstart, float* __restrict__ dinv, int n) {
    __shared__ int tsum[256];
    __shared__ int base_sh;
    int t = threadIdx.x, b = blockIdx.x;
    if (t < 64) {
        int s0 = (t < b) ? partials[t] : 0;
        int i2 = t + 64;
        int s1 = (i2 < b && i2 < 98) ? partials[i2] : 0;
        int s = s0 + s1;
#pragma unroll
        for (int off = 32; off > 0; off >>= 1) s += __shfl_down(s, off, 64);
        if (t == 0) base_sh = s;
    }
    int base = b * 1024 + t * 4;
    int v[4];
    int s = 0;
#pragma unroll
    for (int j = 0; j < 4; j++) {
        int i = base + j;
        v[j] = (i < n) ? hist[i] : 0;
        s += v[j];
    }
    tsum[t] = s;
    __syncthreads();
    for (int off = 1; off < 256; off <<= 1) {
        int a = (t >= off) ? tsum[t - off] : 0;
        __syncthreads();
        tsum[t] += a;
        __syncthreads();
    }
    int offset = base_sh + (tsum[t] - s);
#pragma unroll
    for (int j = 0; j < 4; j++) {
        int i = base + j;
        if (i < n) {
            rowstart[i] = offset;
            dinv[i] = rsqrtf((float)v[j] + 1.0f);
            offset += v[j];
        }
    }
    if (b == 0 && t == 0) rowstart[n] = N_POS;
}

// ===== shared GEMM tile body: H_bf16[node0..node0+64, M] = X @ W =====
template <int M, bool XBF>
__device__ __forceinline__ void gemm_tile(const void* __restrict__ Xv,
                                          const ushort16* __restrict__ Wt,
                                          ushort16* __restrict__ H, int n, int tileIdx) {
    constexpr int K = 128;
    constexpr int TN = 64;
    constexpr int KH = 64;  // K half
    constexpr int XS = 72;  // padded half-row stride (shorts): 144B -> 2-way bank alias (free)
    __shared__ short Xs[TN * XS];
    __shared__ short Ws[M * XS];
    int tid = threadIdx.x;
    int node0 = tileIdx * TN;

    constexpr int CT = M / 16;
    int w = tid >> 6;
    int lane = tid & 63;
    int l15 = lane & 15;
    int quad = lane >> 4;
    f32x4 acc[CT] = {};

#pragma unroll
    for (int h = 0; h < 2; ++h) {
        if (h) __syncthreads();
        for (int q = tid; q < M * 8; q += 256) {
            int row = q >> 3, c = q & 7;
            uint4 v = *(const uint4*)((const short*)Wt + row * K + h * KH + c * 8);
            *(uint4*)(Ws + row * XS + c * 8) = v;
        }
        if (!XBF) {
            const float* X = (const float*)Xv;
            int row = tid >> 2, part = tid & 3;
            int gn = node0 + row;
#pragma unroll
            for (int c = 0; c < 4; ++c) {
                int kl = part * 16 + c * 4;
                float4 v = (gn < n) ? *(const float4*)(X + (size_t)gn * K + h * KH + kl)
                                    : float4{0, 0, 0, 0};
                uint2 p = {pack2bf(v.x, v.y), pack2bf(v.z, v.w)};
                *(uint2*)(Xs + row * XS + kl) = p;
            }
        } else {
            const short* X = (const short*)Xv;
            for (int q = tid; q < TN * 8; q += 256) {
                int row = q >> 3, c = q & 7;
                int gn = node0 + row;
                uint4 v = (gn < n) ? *(const uint4*)(X + (size_t)gn * K + h * KH + c * 8)
                                   : uint4{0, 0, 0, 0};
                *(uint4*)(Xs + row * XS + c * 8) = v;
            }
        }
        __syncthreads();

        const short* xrow = Xs + (w * 16 + l15) * XS + quad * 8;
#pragma unroll
        for (int kk = 0; kk < 2; ++kk) {
            bf16x8 a = *(const bf16x8*)(xrow + kk * 32);
#pragma unroll
            for (int ct = 0; ct < CT; ++ct) {
                bf16x8 b = *(const bf16x8*)(Ws + (ct * 16 + l15) * XS + quad * 8 + kk * 32);
                acc[ct] = __builtin_amdgcn_mfma_f32_16x16x32_bf16(a, b, acc[ct], 0, 0, 0);
            }
        }
    }

#pragma unroll
    for (int ct = 0; ct < CT; ++ct) {
#pragma unroll
        for (int r = 0; r < 4; ++r) {
            int gn = node0 + w * 16 + quad * 4 + r;
            if (gn < n) H[(size_t)gn * M + ct * 16 + l15] = f2bf(acc[ct][r]);
        }
    }
}

// ===== fused: csr_fill (atomic-free, pure loads) + layer-1 GEMM =====
__global__ __launch_bounds__(256) void csr_gemm1(
    const int* __restrict__ src, const int* __restrict__ dst, const float* __restrict__ dinv,
    const int* __restrict__ rowstart, const int* __restrict__ rank,
    int2* __restrict__ adjw, const float* __restrict__ x,
    const ushort16* __restrict__ W1t, ushort16* __restrict__ H, int n) {
    if (blockIdx.x < NB_FILL) {
        int e = blockIdx.x * 256 + threadIdx.x;
        if (e < N_POS) {
            int s = src[e], d = dst[e];
            int p = rowstart[d] + rank[e];
            adjw[p] = int2{s, __float_as_int(dinv[s] * dinv[d])};
        }
    } else {
        gemm_tile<HIDDEN, false>(x, W1t, H, n, blockIdx.x - NB_FILL);
    }
}

// ===== PAIR layer-1 aggregation: two nodes' 8-edge batches in flight =====
// Halves serial memory round-trips per 16-lane group (gather-latency-bound:
// r4 counters 27% occ / 31% VALU / 29% HBM). ~100-115 VGPR, fits (256,4) cap.
__device__ __forceinline__ void agg_pair128(
    int nodeA, int nodeB, int l, const int* __restrict__ rowstart,
    const int2* __restrict__ adjw, const float* __restrict__ dinv,
    const ushort16* __restrict__ H, const float* __restrict__ bias,
    uint4* outA, uint4* outB) {
    float dnA = dinv[nodeA], dnB = dinv[nodeB];
    int rsA = rowstart[nodeA], reA = rowstart[nodeA + 1];
    int rsB = rowstart[nodeB], reB = rowstart[nodeB + 1];
    int degA = reA - rsA, degB = reB - rsB;
    int pcA = (degA > 0) ? rsA : (rsA > 0 ? rsA - 1 : 0);
    int pcB = (degB > 0) ? rsB : (rsB > 0 ? rsB - 1 : 0);
    uint4 hA[8], hB[8];
    float wA[8], wB[8];
#pragma unroll
    for (int j = 0; j < 8; ++j) {
        int2 ea = adjw[(rsA + j < reA) ? rsA + j : pcA];
        int2 eb = adjw[(rsB + j < reB) ? rsB + j : pcB];
        hA[j] = *(const uint4*)(H + (size_t)ea.x * 128 + l * 8);
        hB[j] = *(const uint4*)(H + (size_t)eb.x * 128 + l * 8);
        wA[j] = (j < degA) ? __int_as_float(ea.y) : 0.0f;
        wB[j] = (j < degB) ? __int_as_float(eb.y) : 0.0f;
    }
    float sA[8] = {}, sB[8] = {};
#pragma unroll
    for (int j = 0; j < 8; ++j) {
        sA[0] += bf_lo(hA[j].x) * wA[j]; sA[1] += bf_hi(hA[j].x) * wA[j];
        sA[2] += bf_lo(hA[j].y) * wA[j]; sA[3] += bf_hi(hA[j].y) * wA[j];
        sA[4] += bf_lo(hA[j].z) * wA[j]; sA[5] += bf_hi(hA[j].z) * wA[j];
        sA[6] += bf_lo(hA[j].w) * wA[j]; sA[7] += bf_hi(hA[j].w) * wA[j];
        sB[0] += bf_lo(hB[j].x) * wB[j]; sB[1] += bf_hi(hB[j].x) * wB[j];
        sB[2] += bf_lo(hB[j].y) * wB[j]; sB[3] += bf_hi(hB[j].y) * wB[j];
        sB[4] += bf_lo(hB[j].z) * wB[j]; sB[5] += bf_hi(hB[j].z) * wB[j];
        sB[6] += bf_lo(hB[j].w) * wB[j]; sB[7] += bf_hi(hB[j].w) * wB[j];
    }
    for (int p = rsA + 8; p < reA; ++p) {
        int2 e = adjw[p];
        float w = __int_as_float(e.y);
        uint4 hh = *(const uint4*)(H + (size_t)e.x * 128 + l * 8);
        sA[0] += bf_lo(hh.x) * w; sA[1] += bf_hi(hh.x) * w;
        sA[2] += bf_lo(hh.y) * w; sA[3] += bf_hi(hh.y) * w;
        sA[4] += bf_lo(hh.z) * w; sA[5] += bf_hi(hh.z) * w;
        sA[6] += bf_lo(hh.w) * w; sA[7] += bf_hi(hh.w) * w;
    }
    for (int p = rsB + 8; p < reB; ++p) {
        int2 e = adjw[p];
        float w = __int_as_float(e.y);
        uint4 hh = *(const uint4*)(H + (size_t)e.x * 128 + l * 8);
        sB[0] += bf_lo(hh.x) * w; sB[1] += bf_hi(hh.x) * w;
        sB[2] += bf_lo(hh.y) * w; sB[3] += bf_hi(hh.y) * w;
        sB[4] += bf_lo(hh.z) * w; sB[5] += bf_hi(hh.z) * w;
        sB[6] += bf_lo(hh.w) * w; sB[7] += bf_hi(hh.w) * w;
    }
    uint4 hvA = *(const uint4*)(H + (size_t)nodeA * 128 + l * 8);
    uint4 hvB = *(const uint4*)(H + (size_t)nodeB * 128 + l * 8);
    float4 bv0 = *(const float4*)(bias + l * 8);
    float4 bv1 = *(const float4*)(bias + l * 8 + 4);
    float bb[8] = {bv0.x, bv0.y, bv0.z, bv0.w, bv1.x, bv1.y, bv1.z, bv1.w};
    float d2A = dnA * dnA, d2B = dnB * dnB;
    float hsA[8] = {bf_lo(hvA.x), bf_hi(hvA.x), bf_lo(hvA.y), bf_hi(hvA.y),
                    bf_lo(hvA.z), bf_hi(hvA.z), bf_lo(hvA.w), bf_hi(hvA.w)};
    float hsB[8] = {bf_lo(hvB.x), bf_hi(hvB.x), bf_lo(hvB.y), bf_hi(hvB.y),
                    bf_lo(hvB.z), bf_hi(hvB.z), bf_lo(hvB.w), bf_hi(hvB.w)};
    float vA[8], vB[8];
#pragma unroll
    for (int j = 0; j < 8; ++j) {
        vA[j] = fmaxf(sA[j] + hsA[j] * d2A + bb[j], 0.0f);  // relu (layer 1)
        vB[j] = fmaxf(sB[j] + hsB[j] * d2B + bb[j], 0.0f);
    }
    *outA = uint4{pack2bf(vA[0], vA[1]), pack2bf(vA[2], vA[3]),
                  pack2bf(vA[4], vA[5]), pack2bf(vA[6], vA[7])};
    *outB = uint4{pack2bf(vB[0], vB[1]), pack2bf(vB[2], vB[3]),
                  pack2bf(vB[4], vB[5]), pack2bf(vB[6], vB[7])};
}

// ===== fused: layer-1 agg (pair-ILP) -> LDS -> layer-2 GEMM =====
// r4 structure restored (Ws LDS staging: 41.1us anchor; direct-global W2 was
// +4us, r5/r6). Agg loop now processes the group's 4 nodes as 2 pairs.
#define ZS 136  // padded row stride (shorts); 272B, 16B-aligned
__global__ __launch_bounds__(256, 4) void agg1_gemm2(
    const int* __restrict__ rowstart, const int2* __restrict__ adjw,
    const float* __restrict__ dinv, const ushort16* __restrict__ H,
    const float* __restrict__ b1, const ushort16* __restrict__ W2t,
    ushort16* __restrict__ h2, int n) {
    __shared__ __align__(16) short Zs[64 * ZS];
    __shared__ __align__(16) short Ws[64 * ZS];
    int tid = threadIdx.x;
    int node0 = blockIdx.x * 64;

    // stage W2t [64 out][128 k] -> Ws (independent of agg; overlaps its latency)
    for (int q = tid; q < 64 * 16; q += 256) {
        int row = q >> 4, c = q & 15;
        uint4 v = *(const uint4*)((const short*)W2t + row * 128 + c * 8);
        *(uint4*)(Ws + row * ZS + c * 8) = v;
    }

    // layer-1 aggregation for 64 nodes: 16 groups x 16 lanes, 2 node-pairs each
    int g = tid >> 4, l = tid & 15;
#pragma unroll 1
    for (int it = 0; it < 2; ++it) {
        int rowA = g * 4 + it * 2;
        int nodeA = node0 + rowA, nodeB = nodeA + 1;
        int cA = (nodeA < n) ? nodeA : (n - 1);
        int cB = (nodeB < n) ? nodeB : (n - 1);
        uint4 zA, zB;
        agg_pair128(cA, cB, l, rowstart, adjw, dinv, H, b1, &zA, &zB);
        if (nodeA >= n) zA = uint4{0, 0, 0, 0};
        if (nodeB >= n) zB = uint4{0, 0, 0, 0};
        *(uint4*)(Zs + rowA * ZS + l * 8) = zA;
        *(uint4*)(Zs + (rowA + 1) * ZS + l * 8) = zB;
    }
    __syncthreads();

    // GEMM: h2[64 x 64] = Zs @ W2 (16 MFMAs per wave)
    int w = tid >> 6, lane = tid & 63, l15 = lane & 15, quad = lane >> 4;
    f32x4 acc[4] = {};
    const short* zrow = Zs + (w * 16 + l15) * ZS + quad * 8;
#pragma unroll
    for (int kk = 0; kk < 4; ++kk) {
        bf16x8 a = *(const bf16x8*)(zrow + kk * 32);
#pragma unroll
        for (int ct = 0; ct < 4; ++ct) {
            bf16x8 b = *(const bf16x8*)(Ws + (ct * 16 + l15) * ZS + quad * 8 + kk * 32);
            acc[ct] = __builtin_amdgcn_mfma_f32_16x16x32_bf16(a, b, acc[ct], 0, 0, 0);
        }
    }
#pragma unroll
    for (int ct = 0; ct < 4; ++ct) {
#pragma unroll
        for (int r = 0; r < 4; ++r) {
            int gn = node0 + w * 16 + quad * 4 + r;
            if (gn < n) h2[(size_t)gn * OUT_CH + ct * 16 + l15] = f2bf(acc[ct][r]);
        }
    }
}

// ========= pull aggregation + self-loop + bias (+relu), bf16 H/Z =========
// FOUR nodes per wave (16 lanes each). Predicated straight-line 8-edge block.
template <int F, bool RELU>
__global__ void agg_pull(const int* __restrict__ rowstart, const int2* __restrict__ adjw,
                         const float* __restrict__ dinv, const ushort16* __restrict__ H,
                         const float* __restrict__ bias, ushort16* __restrict__ Z, int n) {
    int g = threadIdx.x >> 4;  // 16-lane group
    int l = threadIdx.x & 15;
    int node = blockIdx.x * (blockDim.x >> 4) + g;
    if (node >= n) return;
    float dn = dinv[node];
    int rs = rowstart[node], re = rowstart[node + 1];
    int deg = re - rs;
    int pc = (deg > 0) ? rs : (rs > 0 ? rs - 1 : 0);  // safe clamp index
    if (F == 128) {
        uint4 h[8];
        float wv[8];
#pragma unroll
        for (int j = 0; j < 8; ++j) {
            int p = (rs + j < re) ? rs + j : pc;
            int2 e = adjw[p];
            h[j] = *(const uint4*)(H + (size_t)e.x * F + l * 8);
            wv[j] = (j < deg) ? __int_as_float(e.y) : 0.0f;
        }
        float s0[8] = {}, s1[8] = {};
#pragma unroll
        for (int j = 0; j < 8; j += 2) {
            s0[0] += bf_lo(h[j].x) * wv[j]; s0[1] += bf_hi(h[j].x) * wv[j];
            s0[2] += bf_lo(h[j].y) * wv[j]; s0[3] += bf_hi(h[j].y) * wv[j];
            s0[4] += bf_lo(h[j].z) * wv[j]; s0[5] += bf_hi(h[j].z) * wv[j];
            s0[6] += bf_lo(h[j].w) * wv[j]; s0[7] += bf_hi(h[j].w) * wv[j];
            s1[0] += bf_lo(h[j + 1].x) * wv[j + 1]; s1[1] += bf_hi(h[j + 1].x) * wv[j + 1];
            s1[2] += bf_lo(h[j + 1].y) * wv[j + 1]; s1[3] += bf_hi(h[j + 1].y) * wv[j + 1];
            s1[4] += bf_lo(h[j + 1].z) * wv[j + 1]; s1[5] += bf_hi(h[j + 1].z) * wv[j + 1];
            s1[6] += bf_lo(h[j + 1].w) * wv[j + 1]; s1[7] += bf_hi(h[j + 1].w) * wv[j + 1];
        }
        for (int p = rs + 8; p < re; ++p) {
            int2 e = adjw[p];
            float w = __int_as_float(e.y);
            uint4 hh = *(const uint4*)(H + (size_t)e.x * F + l * 8);
            s0[0] += bf_lo(hh.x) * w; s0[1] += bf_hi(hh.x) * w;
            s0[2] += bf_lo(hh.y) * w; s0[3] += bf_hi(hh.y) * w;
            s0[4] += bf_lo(hh.z) * w; s0[5] += bf_hi(hh.z) * w;
            s0[6] += bf_lo(hh.w) * w; s0[7] += bf_hi(hh.w) * w;
        }
        uint4 hv = *(const uint4*)(H + (size_t)node * F + l * 8);
        float4 bv0 = *(const float4*)(bias + l * 8);
        float4 bv1 = *(const float4*)(bias + l * 8 + 4);
        float d2 = dn * dn;
        float hs[8] = {bf_lo(hv.x), bf_hi(hv.x), bf_lo(hv.y), bf_hi(hv.y),
                       bf_lo(hv.z), bf_hi(hv.z), bf_lo(hv.w), bf_hi(hv.w)};
        float bb[8] = {bv0.x, bv0.y, bv0.z, bv0.w, bv1.x, bv1.y, bv1.z, bv1.w};
        float v[8];
#pragma unroll
        for (int j = 0; j < 8; ++j) {
            v[j] = s0[j] + s1[j] + hs[j] * d2 + bb[j];
            if (RELU) v[j] = fmaxf(v[j], 0.0f);
        }
        *(uint4*)(Z + (size_t)node * F + l * 8) =
            uint4{pack2bf(v[0], v[1]), pack2bf(v[2], v[3]), pack2bf(v[4], v[5]),
                  pack2bf(v[6], v[7])};
    } else {  // F == 64
        uint2 h[8];
        float wv[8];
#pragma unroll
        for (int j = 0; j < 8; ++j) {
            int p = (rs + j < re) ? rs + j : pc;
            int2 e = adjw[p];
            h[j] = *(const uint2*)(H + (size_t)e.x * F + l * 4);
            wv[j] = (j < deg) ? __int_as_float(e.y) : 0.0f;
        }
        float s0[4] = {}, s1[4] = {};
#pragma unroll
        for (int j = 0; j < 8; j += 2) {
            s0[0] += bf_lo(h[j].x) * wv[j]; s0[1] += bf_hi(h[j].x) * wv[j];
            s0[2] += bf_lo(h[j].y) * wv[j]; s0[3] += bf_hi(h[j].y) * wv[j];
            s1[0] += bf_lo(h[j + 1].x) * wv[j + 1]; s1[1] += bf_hi(h[j + 1].x) * wv[j + 1];
            s1[2] += bf_lo(h[j + 1].y) * wv[j + 1]; s1[3] += bf_hi(h[j + 1].y) * wv[j + 1];
        }
        for (int p = rs + 8; p < re; ++p) {
            int2 e = adjw[p];
            float w = __int_as_float(e.y);
            uint2 hh = *(const uint2*)(H + (size_t)e.x * F + l * 4);
            s0[0] += bf_lo(hh.x) * w; s0[1] += bf_hi(hh.x) * w;
            s0[2] += bf_lo(hh.y) * w; s0[3] += bf_hi(hh.y) * w;
        }
        uint2 hv = *(const uint2*)(H + (size_t)node * F + l * 4);
        float4 bv = *(const float4*)(bias + l * 4);
        float d2 = dn * dn;
        float hs[4] = {bf_lo(hv.x), bf_hi(hv.x), bf_lo(hv.y), bf_hi(hv.y)};
        float bb[4] = {bv.x, bv.y, bv.z, bv.w};
        float v[4];
#pragma unroll
        for (int j = 0; j < 4; ++j) {
            v[j] = s0[j] + s1[j] + hs[j] * d2 + bb[j];
            if (RELU) v[j] = fmaxf(v[j], 0.0f);
        }
        *(uint2*)(Z + (size_t)node * F + l * 4) = uint2{pack2bf(v[0], v[1]), pack2bf(v[2], v[3])};
    }
}

// ===== decode via MFMA: 32 edges per wave (two 16-edge groups) =====
__global__ void decode_mfma(const int* __restrict__ pos, const int* __restrict__ neg,
                            const short* __restrict__ Z, float* __restrict__ out) {
    int wid = threadIdx.x >> 6;
    int lane = threadIdx.x & 63;
    int l15 = lane & 15;
    int quad = lane >> 4;
    int e0 = (blockIdx.x * 4 + wid) * 32;
    if (e0 >= N_POS + N_NEG) return;
    const int* bp = (e0 < N_POS) ? pos : (neg - N_POS);
    int eA = e0 + l15;
    int eB = e0 + 16 + l15;
    int aA = bp[eA], bA = bp[600000 + eA];
    int aB = bp[eB], bB = bp[600000 + eB];

    const short* zaA = Z + (size_t)aA * OUT_CH + quad * 8;
    const short* zbA = Z + (size_t)bA * OUT_CH + quad * 8;
    const short* zaB = Z + (size_t)aB * OUT_CH + quad * 8;
    const short* zbB = Z + (size_t)bB * OUT_CH + quad * 8;
    bf16x8 a0A = *(const bf16x8*)(zaA);
    bf16x8 a1A = *(const bf16x8*)(zaA + 32);
    bf16x8 b0A = *(const bf16x8*)(zbA);
    bf16x8 b1A = *(const bf16x8*)(zbA + 32);
    bf16x8 a0B = *(const bf16x8*)(zaB);
    bf16x8 a1B = *(const bf16x8*)(zaB + 32);
    bf16x8 b0B = *(const bf16x8*)(zbB);
    bf16x8 b1B = *(const bf16x8*)(zbB + 32);

    f32x4 accA = {}, accB = {};
    accA = __builtin_amdgcn_mfma_f32_16x16x32_bf16(a0A, b0A, accA, 0, 0, 0);
    accB = __builtin_amdgcn_mfma_f32_16x16x32_bf16(a0B, b0B, accB, 0, 0, 0);
    accA = __builtin_amdgcn_mfma_f32_16x16x32_bf16(a1A, b1A, accA, 0, 0, 0);
    accB = __builtin_amdgcn_mfma_f32_16x16x32_bf16(a1B, b1B, accB, 0, 0, 0);

    if (quad == (l15 >> 2)) {
        out[eA] = accA[l15 & 3];
        out[eB] = accB[l15 & 3];
    }
}

extern "C" void kernel_launch(void* const* d_in, const int* in_sizes, int n_in,
                              void* d_out, int out_size, void* d_ws, size_t ws_size,
                              hipStream_t stream) {
    const float* x = (const float*)d_in[0];
    const int* pos = (const int*)d_in[1];  // row0 = src, row1 = dst
    const int* neg = (const int*)d_in[2];
    const float* W1 = (const float*)d_in[3];
    const float* b1 = (const float*)d_in[4];
    const float* W2 = (const float*)d_in[5];
    const float* b2 = (const float*)d_in[6];
    float* out = (float*)d_out;

    // workspace layout (bf16 intermediates)
    ushort16* A = (ushort16*)d_ws;                      // H [N,128]; later z2 [N,64]
    ushort16* B = A + (size_t)N_NODES * 128;            // h2 [N,64]
    float* dinv = (float*)(B + (size_t)N_NODES * 128);  // [N]
    int* hist = (int*)(dinv + N_NODES);                 // [N]
    int* rowstart = hist + N_NODES;                     // [N+1]
    int2* adjw = (int2*)(rowstart + N_NODES + 1);       // [N_POS] (adj, wgt) pairs
    int* partials = (int*)(adjw + N_POS);               // [128]
    ushort16* W1t = (ushort16*)(partials + 128);        // [128*128]
    ushort16* W2t = W1t + 128 * 128;                    // [64*128]
    // rank[N_POS] overlays B: rank is dead before agg1_gemm2 writes h2 into B
    // (csr_gemm1 completes first; same stream).
    int* rank = (int*)B;

    const int* pos_src = pos;
    const int* pos_dst = pos + N_POS;

    constexpr int NB_SCAN = (N_NODES + 1023) / 1024;  // 98

    // ---- CSR build + dinv + weight convert ----
    hipMemsetAsync(hist, 0, N_NODES * sizeof(int), stream);
    hist_wt<<<NB_HIST + 96, 256, 0, stream>>>(pos_dst, hist, rank, W1, W2, W1t, W2t);
    scan_reduce<<<NB_SCAN, 256, 0, stream>>>(hist, partials, N_NODES);
    scan_final<<<NB_SCAN, 256, 0, stream>>>(hist, partials, rowstart, dinv, N_NODES);

    // ---- csr_fill (atomic-free) + layer-1 GEMM fused (one launch) ----
    csr_gemm1<<<NB_FILL + NB_GEMM1, 256, 0, stream>>>(pos_src, pos_dst, dinv, rowstart, rank,
                                                      adjw, x, W1t, A, N_NODES);

    // ---- fused layer-1 aggregation (pair-ILP) + layer-2 GEMM ----
    agg1_gemm2<<<(N_NODES + 63) / 64, 256, 0, stream>>>(rowstart, adjw, dinv, A, b1, W2t, B,
                                                        N_NODES);

    // ---- layer-2 aggregation: reads h2(=B), writes z2(=A) ----
    agg_pull<OUT_CH, false><<<(N_NODES + 15) / 16, 256, 0, stream>>>(rowstart, adjw, dinv, B, b2,
                                                                     A, N_NODES);

    // ---- decode (32 edges/wave, 128/block) ----
    decode_mfma<<<(N_POS + N_NEG) / 128, 256, 0, stream>>>(pos, neg, (const short*)A, out);
}

// Round 8
// 251.618 us; speedup vs baseline: 1.0351x; 1.0248x over previous
//
#include <hip/hip_runtime.h>

#define N_NODES 100000
#define IN_CH 128
#define HIDDEN 128
#define OUT_CH 64
#define N_POS 600000
#define N_NEG 600000

typedef unsigned int uint32;
typedef unsigned short ushort16;
typedef __attribute__((ext_vector_type(8))) short bf16x8;
typedef __attribute__((ext_vector_type(4))) float f32x4;

// ---- bf16 helpers ----
__device__ inline float bf_lo(uint32 u) {
    union { uint32 i; float f; } v;
    v.i = u << 16;
    return v.f;
}
__device__ inline float bf_hi(uint32 u) {
    union { uint32 i; float f; } v;
    v.i = u & 0xffff0000u;
    return v.f;
}
__device__ inline ushort16 f2bf(float f) {
    union { uint32 i; float f; } v;
    v.f = f;
    uint32 r = v.i + 0x7fffu + ((v.i >> 16) & 1u);  // round-to-nearest-even
    return (ushort16)(r >> 16);
}
__device__ inline uint32 pack2bf(float a, float b) {
    return (uint32)f2bf(a) | ((uint32)f2bf(b) << 16);
}

#define NB_HIST ((N_POS + 255) / 256)   // 2344 -- 1 edge/thread (measured best, r0 vs r1/r2)
#define NB_FILL ((N_POS + 255) / 256)   // 2344 -- sequential layout (interleave neutral, r5)
#define NB_GEMM1 ((N_NODES + 63) / 64)  // 1563

// ===== fused: hist_count (+rank persist) + weight transpose/convert =====
// atomicAdd's return value IS the edge's rank among same-dst edges; persisting
// it lets csr-fill compute its slot with pure loads. (verified -13us, r4)
__global__ void hist_wt(const int* __restrict__ dst, int* __restrict__ hist,
                        int* __restrict__ rank,
                        const float* __restrict__ W1, const float* __restrict__ W2,
                        ushort16* __restrict__ W1t, ushort16* __restrict__ W2t) {
    if (blockIdx.x < NB_HIST) {
        int i = blockIdx.x * 256 + threadIdx.x;
        if (i < N_POS) rank[i] = atomicAdd(&hist[dst[i]], 1);
    } else {
        int i = (blockIdx.x - NB_HIST) * 256 + threadIdx.x;
        if (i < 128 * 128) {
            int n = i >> 7, k = i & 127;
            W1t[i] = f2bf(W1[k * 128 + n]);
        } else {
            int j = i - 128 * 128;
            if (j < 64 * 128) {
                int n = j >> 7, k = j & 127;
                W2t[j] = f2bf(W2[k * 64 + n]);
            }
        }
    }
}

__global__ void scan_reduce(const int* __restrict__ hist, int* __restrict__ partials, int n) {
    __shared__ int sdata[256];
    int b = blockIdx.x, t = threadIdx.x;
    int base = b * 1024;
    int s = 0;
    for (int i = t; i < 1024; i += 256) {
        int idx = base + i;
        s += (idx < n) ? hist[idx] : 0;
    }
    sdata[t] = s;
    __syncthreads();
    for (int off = 128; off > 0; off >>= 1) {
        if (t < off) sdata[t] += sdata[t + off];
        __syncthreads();
    }
    if (t == 0) partials[b] = sdata[0];
}

// scan_final computes its own partials-prefix (first wave). NB_SCAN = 98 <= 128.
__global__ void scan_final(const int* __restrict__ hist, const int* __restrict__ partials,
                           int* __restrict__ rowstart, float* __restrict__ dinv, int n) {
    __shared__ int tsum[256];
    __shared__ int base_sh;
    int t = threadIdx.x, b = blockIdx.x;
    if (t < 64) {
        int s0 = (t < b) ? partials[t] : 0;
        int i2 = t + 64;
        int s1 = (i2 < b && i2 < 98) ? partials[i2] : 0;
        int s = s0 + s1;
#pragma unroll
        for (int off = 32; off > 0; off >>= 1) s += __shfl_down(s, off, 64);
        if (t == 0) base_sh = s;
    }
    int base = b * 1024 + t * 4;
    int v[4];
    int s = 0;
#pragma unroll
    for (int j = 0; j < 4; j++) {
        int i = base + j;
        v[j] = (i < n) ? hist[i] : 0;
        s += v[j];
    }
    tsum[t] = s;
    __syncthreads();
    for (int off = 1; off < 256; off <<= 1) {
        int a = (t >= off) ? tsum[t - off] : 0;
        __syncthreads();
        tsum[t] += a;
        __syncthreads();
    }
    int offset = base_sh + (tsum[t] - s);
#pragma unroll
    for (int j = 0; j < 4; j++) {
        int i = base + j;
        if (i < n) {
            rowstart[i] = offset;
            dinv[i] = rsqrtf((float)v[j] + 1.0f);
            offset += v[j];
        }
    }
    if (b == 0 && t == 0) rowstart[n] = N_POS;
}

// ===== shared GEMM tile body: H_bf16[node0..node0+64, M] = X @ W =====
template <int M, bool XBF>
__device__ __forceinline__ void gemm_tile(const void* __restrict__ Xv,
                                          const ushort16* __restrict__ Wt,
                                          ushort16* __restrict__ H, int n, int tileIdx) {
    constexpr int K = 128;
    constexpr int TN = 64;
    constexpr int KH = 64;  // K half
    constexpr int XS = 72;  // padded half-row stride (shorts): 144B -> 2-way bank alias (free)
    __shared__ short Xs[TN * XS];
    __shared__ short Ws[M * XS];
    int tid = threadIdx.x;
    int node0 = tileIdx * TN;

    constexpr int CT = M / 16;
    int w = tid >> 6;
    int lane = tid & 63;
    int l15 = lane & 15;
    int quad = lane >> 4;
    f32x4 acc[CT] = {};

#pragma unroll
    for (int h = 0; h < 2; ++h) {
        if (h) __syncthreads();
        for (int q = tid; q < M * 8; q += 256) {
            int row = q >> 3, c = q & 7;
            uint4 v = *(const uint4*)((const short*)Wt + row * K + h * KH + c * 8);
            *(uint4*)(Ws + row * XS + c * 8) = v;
        }
        if (!XBF) {
            const float* X = (const float*)Xv;
            int row = tid >> 2, part = tid & 3;
            int gn = node0 + row;
#pragma unroll
            for (int c = 0; c < 4; ++c) {
                int kl = part * 16 + c * 4;
                float4 v = (gn < n) ? *(const float4*)(X + (size_t)gn * K + h * KH + kl)
                                    : float4{0, 0, 0, 0};
                uint2 p = {pack2bf(v.x, v.y), pack2bf(v.z, v.w)};
                *(uint2*)(Xs + row * XS + kl) = p;
            }
        } else {
            const short* X = (const short*)Xv;
            for (int q = tid; q < TN * 8; q += 256) {
                int row = q >> 3, c = q & 7;
                int gn = node0 + row;
                uint4 v = (gn < n) ? *(const uint4*)(X + (size_t)gn * K + h * KH + c * 8)
                                   : uint4{0, 0, 0, 0};
                *(uint4*)(Xs + row * XS + c * 8) = v;
            }
        }
        __syncthreads();

        const short* xrow = Xs + (w * 16 + l15) * XS + quad * 8;
#pragma unroll
        for (int kk = 0; kk < 2; ++kk) {
            bf16x8 a = *(const bf16x8*)(xrow + kk * 32);
#pragma unroll
            for (int ct = 0; ct < CT; ++ct) {
                bf16x8 b = *(const bf16x8*)(Ws + (ct * 16 + l15) * XS + quad * 8 + kk * 32);
                acc[ct] = __builtin_amdgcn_mfma_f32_16x16x32_bf16(a, b, acc[ct], 0, 0, 0);
            }
        }
    }

#pragma unroll
    for (int ct = 0; ct < CT; ++ct) {
#pragma unroll
        for (int r = 0; r < 4; ++r) {
            int gn = node0 + w * 16 + quad * 4 + r;
            if (gn < n) H[(size_t)gn * M + ct * 16 + l15] = f2bf(acc[ct][r]);
        }
    }
}

// ===== fused: csr_fill (atomic-free, pure loads) + layer-1 GEMM =====
__global__ __launch_bounds__(256) void csr_gemm1(
    const int* __restrict__ src, const int* __restrict__ dst, const float* __restrict__ dinv,
    const int* __restrict__ rowstart, const int* __restrict__ rank,
    int2* __restrict__ adjw, const float* __restrict__ x,
    const ushort16* __restrict__ W1t, ushort16* __restrict__ H, int n) {
    if (blockIdx.x < NB_FILL) {
        int e = blockIdx.x * 256 + threadIdx.x;
        if (e < N_POS) {
            int s = src[e], d = dst[e];
            int p = rowstart[d] + rank[e];
            adjw[p] = int2{s, __float_as_int(dinv[s] * dinv[d])};
        }
    } else {
        gemm_tile<HIDDEN, false>(x, W1t, H, n, blockIdx.x - NB_FILL);
    }
}

// ===== layer-1 aggregation body for one node (F=128, +bias+relu), 16 lanes =====
// r4 structure (serial nodes, 8-edge prologue) + BATCHED TAIL: edges beyond 8
// were a serial load->FMA chain (one L2/L3 round-trip per edge); batching the
// tail 4-at-a-time keeps 4 gathers in flight (16 transient VGPRs, no spill).
__device__ __forceinline__ uint4 agg_node128(int node, int l, const int* __restrict__ rowstart,
                                             const int2* __restrict__ adjw,
                                             const float* __restrict__ dinv,
                                             const ushort16* __restrict__ H,
                                             const float* __restrict__ bias) {
    float dn = dinv[node];
    int rs = rowstart[node], re = rowstart[node + 1];
    int deg = re - rs;
    int pc = (deg > 0) ? rs : (rs > 0 ? rs - 1 : 0);  // safe clamp index
    uint4 h[8];
    float wv[8];
#pragma unroll
    for (int j = 0; j < 8; ++j) {
        int p = (rs + j < re) ? rs + j : pc;
        int2 e = adjw[p];
        h[j] = *(const uint4*)(H + (size_t)e.x * 128 + l * 8);
        wv[j] = (j < deg) ? __int_as_float(e.y) : 0.0f;
    }
    float s0[8] = {}, s1[8] = {};
#pragma unroll
    for (int j = 0; j < 8; j += 2) {
        s0[0] += bf_lo(h[j].x) * wv[j]; s0[1] += bf_hi(h[j].x) * wv[j];
        s0[2] += bf_lo(h[j].y) * wv[j]; s0[3] += bf_hi(h[j].y) * wv[j];
        s0[4] += bf_lo(h[j].z) * wv[j]; s0[5] += bf_hi(h[j].z) * wv[j];
        s0[6] += bf_lo(h[j].w) * wv[j]; s0[7] += bf_hi(h[j].w) * wv[j];
        s1[0] += bf_lo(h[j + 1].x) * wv[j + 1]; s1[1] += bf_hi(h[j + 1].x) * wv[j + 1];
        s1[2] += bf_lo(h[j + 1].y) * wv[j + 1]; s1[3] += bf_hi(h[j + 1].y) * wv[j + 1];
        s1[4] += bf_lo(h[j + 1].z) * wv[j + 1]; s1[5] += bf_hi(h[j + 1].z) * wv[j + 1];
        s1[6] += bf_lo(h[j + 1].w) * wv[j + 1]; s1[7] += bf_hi(h[j + 1].w) * wv[j + 1];
    }
    // batched tail: 4 predicated gathers in flight per iteration
    for (int p = rs + 8; p < re; p += 4) {
        uint4 ht[4];
        float wt[4];
#pragma unroll
        for (int j = 0; j < 4; ++j) {
            int q = (p + j < re) ? p + j : p;  // p itself is always < re here
            int2 e = adjw[q];
            ht[j] = *(const uint4*)(H + (size_t)e.x * 128 + l * 8);
            wt[j] = (p + j < re) ? __int_as_float(e.y) : 0.0f;
        }
#pragma unroll
        for (int j = 0; j < 4; j += 2) {
            s0[0] += bf_lo(ht[j].x) * wt[j]; s0[1] += bf_hi(ht[j].x) * wt[j];
            s0[2] += bf_lo(ht[j].y) * wt[j]; s0[3] += bf_hi(ht[j].y) * wt[j];
            s0[4] += bf_lo(ht[j].z) * wt[j]; s0[5] += bf_hi(ht[j].z) * wt[j];
            s0[6] += bf_lo(ht[j].w) * wt[j]; s0[7] += bf_hi(ht[j].w) * wt[j];
            s1[0] += bf_lo(ht[j + 1].x) * wt[j + 1]; s1[1] += bf_hi(ht[j + 1].x) * wt[j + 1];
            s1[2] += bf_lo(ht[j + 1].y) * wt[j + 1]; s1[3] += bf_hi(ht[j + 1].y) * wt[j + 1];
            s1[4] += bf_lo(ht[j + 1].z) * wt[j + 1]; s1[5] += bf_hi(ht[j + 1].z) * wt[j + 1];
            s1[6] += bf_lo(ht[j + 1].w) * wt[j + 1]; s1[7] += bf_hi(ht[j + 1].w) * wt[j + 1];
        }
    }
    uint4 hv = *(const uint4*)(H + (size_t)node * 128 + l * 8);
    float4 bv0 = *(const float4*)(bias + l * 8);
    float4 bv1 = *(const float4*)(bias + l * 8 + 4);
    float d2 = dn * dn;
    float hs[8] = {bf_lo(hv.x), bf_hi(hv.x), bf_lo(hv.y), bf_hi(hv.y),
                   bf_lo(hv.z), bf_hi(hv.z), bf_lo(hv.w), bf_hi(hv.w)};
    float bb[8] = {bv0.x, bv0.y, bv0.z, bv0.w, bv1.x, bv1.y, bv1.z, bv1.w};
    float v[8];
#pragma unroll
    for (int j = 0; j < 8; ++j) {
        v[j] = fmaxf(s0[j] + s1[j] + hs[j] * d2 + bb[j], 0.0f);  // relu (layer 1)
    }
    return uint4{pack2bf(v[0], v[1]), pack2bf(v[2], v[3]), pack2bf(v[4], v[5]),
                 pack2bf(v[6], v[7])};
}

// ===== fused: layer-1 agg (+bias+relu) -> LDS -> layer-2 GEMM =====
// r4 anchor structure (41.1us): Ws LDS staging + (256,4) + serial 4-node loop.
// (noWs: +4us r5/r6; pair-ILP: spilled, +9us r7.)
#define ZS 136  // padded row stride (shorts); 272B, 16B-aligned
__global__ __launch_bounds__(256, 4) void agg1_gemm2(
    const int* __restrict__ rowstart, const int2* __restrict__ adjw,
    const float* __restrict__ dinv, const ushort16* __restrict__ H,
    const float* __restrict__ b1, const ushort16* __restrict__ W2t,
    ushort16* __restrict__ h2, int n) {
    __shared__ __align__(16) short Zs[64 * ZS];
    __shared__ __align__(16) short Ws[64 * ZS];
    int tid = threadIdx.x;
    int node0 = blockIdx.x * 64;

    // stage W2t [64 out][128 k] -> Ws (independent of agg; overlaps its latency)
    for (int q = tid; q < 64 * 16; q += 256) {
        int row = q >> 4, c = q & 15;
        uint4 v = *(const uint4*)((const short*)W2t + row * 128 + c * 8);
        *(uint4*)(Ws + row * ZS + c * 8) = v;
    }

    // layer-1 aggregation for 64 nodes: 16 groups x 16 lanes, 4 nodes each
    int g = tid >> 4, l = tid & 15;
#pragma unroll 1
    for (int it = 0; it < 4; ++it) {
        int row = g * 4 + it;
        int node = node0 + row;
        uint4 z = (node < n) ? agg_node128(node, l, rowstart, adjw, dinv, H, b1)
                             : uint4{0, 0, 0, 0};
        *(uint4*)(Zs + row * ZS + l * 8) = z;
    }
    __syncthreads();

    // GEMM: h2[64 x 64] = Zs @ W2 (16 MFMAs per wave)
    int w = tid >> 6, lane = tid & 63, l15 = lane & 15, quad = lane >> 4;
    f32x4 acc[4] = {};
    const short* zrow = Zs + (w * 16 + l15) * ZS + quad * 8;
#pragma unroll
    for (int kk = 0; kk < 4; ++kk) {
        bf16x8 a = *(const bf16x8*)(zrow + kk * 32);
#pragma unroll
        for (int ct = 0; ct < 4; ++ct) {
            bf16x8 b = *(const bf16x8*)(Ws + (ct * 16 + l15) * ZS + quad * 8 + kk * 32);
            acc[ct] = __builtin_amdgcn_mfma_f32_16x16x32_bf16(a, b, acc[ct], 0, 0, 0);
        }
    }
#pragma unroll
    for (int ct = 0; ct < 4; ++ct) {
#pragma unroll
        for (int r = 0; r < 4; ++r) {
            int gn = node0 + w * 16 + quad * 4 + r;
            if (gn < n) h2[(size_t)gn * OUT_CH + ct * 16 + l15] = f2bf(acc[ct][r]);
        }
    }
}

// ========= pull aggregation + self-loop + bias (+relu), bf16 H/Z =========
// FOUR nodes per wave (16 lanes each). 8-edge predicated prologue + BATCHED
// tail (4 gathers in flight; tail was serial one-round-trip-per-edge).
template <int F, bool RELU>
__global__ void agg_pull(const int* __restrict__ rowstart, const int2* __restrict__ adjw,
                         const float* __restrict__ dinv, const ushort16* __restrict__ H,
                         const float* __restrict__ bias, ushort16* __restrict__ Z, int n) {
    int g = threadIdx.x >> 4;  // 16-lane group
    int l = threadIdx.x & 15;
    int node = blockIdx.x * (blockDim.x >> 4) + g;
    if (node >= n) return;
    float dn = dinv[node];
    int rs = rowstart[node], re = rowstart[node + 1];
    int deg = re - rs;
    int pc = (deg > 0) ? rs : (rs > 0 ? rs - 1 : 0);  // safe clamp index
    if (F == 128) {
        uint4 h[8];
        float wv[8];
#pragma unroll
        for (int j = 0; j < 8; ++j) {
            int p = (rs + j < re) ? rs + j : pc;
            int2 e = adjw[p];
            h[j] = *(const uint4*)(H + (size_t)e.x * F + l * 8);
            wv[j] = (j < deg) ? __int_as_float(e.y) : 0.0f;
        }
        float s0[8] = {}, s1[8] = {};
#pragma unroll
        for (int j = 0; j < 8; j += 2) {
            s0[0] += bf_lo(h[j].x) * wv[j]; s0[1] += bf_hi(h[j].x) * wv[j];
            s0[2] += bf_lo(h[j].y) * wv[j]; s0[3] += bf_hi(h[j].y) * wv[j];
            s0[4] += bf_lo(h[j].z) * wv[j]; s0[5] += bf_hi(h[j].z) * wv[j];
            s0[6] += bf_lo(h[j].w) * wv[j]; s0[7] += bf_hi(h[j].w) * wv[j];
            s1[0] += bf_lo(h[j + 1].x) * wv[j + 1]; s1[1] += bf_hi(h[j + 1].x) * wv[j + 1];
            s1[2] += bf_lo(h[j + 1].y) * wv[j + 1]; s1[3] += bf_hi(h[j + 1].y) * wv[j + 1];
            s1[4] += bf_lo(h[j + 1].z) * wv[j + 1]; s1[5] += bf_hi(h[j + 1].z) * wv[j + 1];
            s1[6] += bf_lo(h[j + 1].w) * wv[j + 1]; s1[7] += bf_hi(h[j + 1].w) * wv[j + 1];
        }
        for (int p = rs + 8; p < re; p += 4) {
            uint4 ht[4];
            float wt[4];
#pragma unroll
            for (int j = 0; j < 4; ++j) {
                int q = (p + j < re) ? p + j : p;
                int2 e = adjw[q];
                ht[j] = *(const uint4*)(H + (size_t)e.x * F + l * 8);
                wt[j] = (p + j < re) ? __int_as_float(e.y) : 0.0f;
            }
#pragma unroll
            for (int j = 0; j < 4; ++j) {
                s0[0] += bf_lo(ht[j].x) * wt[j]; s0[1] += bf_hi(ht[j].x) * wt[j];
                s0[2] += bf_lo(ht[j].y) * wt[j]; s0[3] += bf_hi(ht[j].y) * wt[j];
                s0[4] += bf_lo(ht[j].z) * wt[j]; s0[5] += bf_hi(ht[j].z) * wt[j];
                s0[6] += bf_lo(ht[j].w) * wt[j]; s0[7] += bf_hi(ht[j].w) * wt[j];
            }
        }
        uint4 hv = *(const uint4*)(H + (size_t)node * F + l * 8);
        float4 bv0 = *(const float4*)(bias + l * 8);
        float4 bv1 = *(const float4*)(bias + l * 8 + 4);
        float d2 = dn * dn;
        float hs[8] = {bf_lo(hv.x), bf_hi(hv.x), bf_lo(hv.y), bf_hi(hv.y),
                       bf_lo(hv.z), bf_hi(hv.z), bf_lo(hv.w), bf_hi(hv.w)};
        float bb[8] = {bv0.x, bv0.y, bv0.z, bv0.w, bv1.x, bv1.y, bv1.z, bv1.w};
        float v[8];
#pragma unroll
        for (int j = 0; j < 8; ++j) {
            v[j] = s0[j] + s1[j] + hs[j] * d2 + bb[j];
            if (RELU) v[j] = fmaxf(v[j], 0.0f);
        }
        *(uint4*)(Z + (size_t)node * F + l * 8) =
            uint4{pack2bf(v[0], v[1]), pack2bf(v[2], v[3]), pack2bf(v[4], v[5]),
                  pack2bf(v[6], v[7])};
    } else {  // F == 64
        uint2 h[8];
        float wv[8];
#pragma unroll
        for (int j = 0; j < 8; ++j) {
            int p = (rs + j < re) ? rs + j : pc;
            int2 e = adjw[p];
            h[j] = *(const uint2*)(H + (size_t)e.x * F + l * 4);
            wv[j] = (j < deg) ? __int_as_float(e.y) : 0.0f;
        }
        float s0[4] = {}, s1[4] = {};
#pragma unroll
        for (int j = 0; j < 8; j += 2) {
            s0[0] += bf_lo(h[j].x) * wv[j]; s0[1] += bf_hi(h[j].x) * wv[j];
            s0[2] += bf_lo(h[j].y) * wv[j]; s0[3] += bf_hi(h[j].y) * wv[j];
            s1[0] += bf_lo(h[j + 1].x) * wv[j + 1]; s1[1] += bf_hi(h[j + 1].x) * wv[j + 1];
            s1[2] += bf_lo(h[j + 1].y) * wv[j + 1]; s1[3] += bf_hi(h[j + 1].y) * wv[j + 1];
        }
        for (int p = rs + 8; p < re; p += 4) {
            uint2 ht[4];
            float wt[4];
#pragma unroll
            for (int j = 0; j < 4; ++j) {
                int q = (p + j < re) ? p + j : p;
                int2 e = adjw[q];
                ht[j] = *(const uint2*)(H + (size_t)e.x * F + l * 4);
                wt[j] = (p + j < re) ? __int_as_float(e.y) : 0.0f;
            }
#pragma unroll
            for (int j = 0; j < 4; ++j) {
                s0[0] += bf_lo(ht[j].x) * wt[j]; s0[1] += bf_hi(ht[j].x) * wt[j];
                s0[2] += bf_lo(ht[j].y) * wt[j]; s0[3] += bf_hi(ht[j].y) * wt[j];
            }
        }
        uint2 hv = *(const uint2*)(H + (size_t)node * F + l * 4);
        float4 bv = *(const float4*)(bias + l * 4);
        float d2 = dn * dn;
        float hs[4] = {bf_lo(hv.x), bf_hi(hv.x), bf_lo(hv.y), bf_hi(hv.y)};
        float bb[4] = {bv.x, bv.y, bv.z, bv.w};
        float v[4];
#pragma unroll
        for (int j = 0; j < 4; ++j) {
            v[j] = s0[j] + s1[j] + hs[j] * d2 + bb[j];
            if (RELU) v[j] = fmaxf(v[j], 0.0f);
        }
        *(uint2*)(Z + (size_t)node * F + l * 4) = uint2{pack2bf(v[0], v[1]), pack2bf(v[2], v[3])};
    }
}

// ===== decode via MFMA: 32 edges per wave (two 16-edge groups) =====
__global__ void decode_mfma(const int* __restrict__ pos, const int* __restrict__ neg,
                            const short* __restrict__ Z, float* __restrict__ out) {
    int wid = threadIdx.x >> 6;
    int lane = threadIdx.x & 63;
    int l15 = lane & 15;
    int quad = lane >> 4;
    int e0 = (blockIdx.x * 4 + wid) * 32;
    if (e0 >= N_POS + N_NEG) return;
    const int* bp = (e0 < N_POS) ? pos : (neg - N_POS);
    int eA = e0 + l15;
    int eB = e0 + 16 + l15;
    int aA = bp[eA], bA = bp[600000 + eA];
    int aB = bp[eB], bB = bp[600000 + eB];

    const short* zaA = Z + (size_t)aA * OUT_CH + quad * 8;
    const short* zbA = Z + (size_t)bA * OUT_CH + quad * 8;
    const short* zaB = Z + (size_t)aB * OUT_CH + quad * 8;
    const short* zbB = Z + (size_t)bB * OUT_CH + quad * 8;
    bf16x8 a0A = *(const bf16x8*)(zaA);
    bf16x8 a1A = *(const bf16x8*)(zaA + 32);
    bf16x8 b0A = *(const bf16x8*)(zbA);
    bf16x8 b1A = *(const bf16x8*)(zbA + 32);
    bf16x8 a0B = *(const bf16x8*)(zaB);
    bf16x8 a1B = *(const bf16x8*)(zaB + 32);
    bf16x8 b0B = *(const bf16x8*)(zbB);
    bf16x8 b1B = *(const bf16x8*)(zbB + 32);

    f32x4 accA = {}, accB = {};
    accA = __builtin_amdgcn_mfma_f32_16x16x32_bf16(a0A, b0A, accA, 0, 0, 0);
    accB = __builtin_amdgcn_mfma_f32_16x16x32_bf16(a0B, b0B, accB, 0, 0, 0);
    accA = __builtin_amdgcn_mfma_f32_16x16x32_bf16(a1A, b1A, accA, 0, 0, 0);
    accB = __builtin_amdgcn_mfma_f32_16x16x32_bf16(a1B, b1B, accB, 0, 0, 0);

    if (quad == (l15 >> 2)) {
        out[eA] = accA[l15 & 3];
        out[eB] = accB[l15 & 3];
    }
}

extern "C" void kernel_launch(void* const* d_in, const int* in_sizes, int n_in,
                              void* d_out, int out_size, void* d_ws, size_t ws_size,
                              hipStream_t stream) {
    const float* x = (const float*)d_in[0];
    const int* pos = (const int*)d_in[1];  // row0 = src, row1 = dst
    const int* neg = (const int*)d_in[2];
    const float* W1 = (const float*)d_in[3];
    const float* b1 = (const float*)d_in[4];
    const float* W2 = (const float*)d_in[5];
    const float* b2 = (const float*)d_in[6];
    float* out = (float*)d_out;

    // workspace layout (bf16 intermediates)
    ushort16* A = (ushort16*)d_ws;                      // H [N,128]; later z2 [N,64]
    ushort16* B = A + (size_t)N_NODES * 128;            // h2 [N,64]
    float* dinv = (float*)(B + (size_t)N_NODES * 128);  // [N]
    int* hist = (int*)(dinv + N_NODES);                 // [N]
    int* rowstart = hist + N_NODES;                     // [N+1]
    int2* adjw = (int2*)(rowstart + N_NODES + 1);       // [N_POS] (adj, wgt) pairs
    int* partials = (int*)(adjw + N_POS);               // [128]
    ushort16* W1t = (ushort16*)(partials + 128);        // [128*128]
    ushort16* W2t = W1t + 128 * 128;                    // [64*128]
    // rank[N_POS] overlays B: rank is dead before agg1_gemm2 writes h2 into B
    // (csr_gemm1 completes first; same stream).
    int* rank = (int*)B;

    const int* pos_src = pos;
    const int* pos_dst = pos + N_POS;

    constexpr int NB_SCAN = (N_NODES + 1023) / 1024;  // 98

    // ---- CSR build + dinv + weight convert ----
    hipMemsetAsync(hist, 0, N_NODES * sizeof(int), stream);
    hist_wt<<<NB_HIST + 96, 256, 0, stream>>>(pos_dst, hist, rank, W1, W2, W1t, W2t);
    scan_reduce<<<NB_SCAN, 256, 0, stream>>>(hist, partials, N_NODES);
    scan_final<<<NB_SCAN, 256, 0, stream>>>(hist, partials, rowstart, dinv, N_NODES);

    // ---- csr_fill (atomic-free) + layer-1 GEMM fused (one launch) ----
    csr_gemm1<<<NB_FILL + NB_GEMM1, 256, 0, stream>>>(pos_src, pos_dst, dinv, rowstart, rank,
                                                      adjw, x, W1t, A, N_NODES);

    // ---- fused layer-1 aggregation (batched tail) + layer-2 GEMM ----
    agg1_gemm2<<<(N_NODES + 63) / 64, 256, 0, stream>>>(rowstart, adjw, dinv, A, b1, W2t, B,
                                                        N_NODES);

    // ---- layer-2 aggregation: reads h2(=B), writes z2(=A) ----
    agg_pull<OUT_CH, false><<<(N_NODES + 15) / 16, 256, 0, stream>>>(rowstart, adjw, dinv, B, b2,
                                                                     A, N_NODES);

    // ---- decode (32 edges/wave, 128/block) ----
    decode_mfma<<<(N_POS + N_NEG) / 128, 256, 0, stream>>>(pos, neg, (const short*)A, out);
}

// Round 9
// 251.553 us; speedup vs baseline: 1.0354x; 1.0003x over previous
//
#include <hip/hip_runtime.h>

#define N_NODES 100000
#define IN_CH 128
#define HIDDEN 128
#define OUT_CH 64
#define N_POS 600000
#define N_NEG 600000

typedef unsigned int uint32;
typedef unsigned short ushort16;
typedef __attribute__((ext_vector_type(8))) short bf16x8;
typedef __attribute__((ext_vector_type(4))) float f32x4;

// ---- bf16 helpers ----
__device__ inline float bf_lo(uint32 u) {
    union { uint32 i; float f; } v;
    v.i = u << 16;
    return v.f;
}
__device__ inline float bf_hi(uint32 u) {
    union { uint32 i; float f; } v;
    v.i = u & 0xffff0000u;
    return v.f;
}
__device__ inline ushort16 f2bf(float f) {
    union { uint32 i; float f; } v;
    v.f = f;
    uint32 r = v.i + 0x7fffu + ((v.i >> 16) & 1u);  // round-to-nearest-even
    return (ushort16)(r >> 16);
}
__device__ inline uint32 pack2bf(float a, float b) {
    return (uint32)f2bf(a) | ((uint32)f2bf(b) << 16);
}

#define NB_HIST ((N_POS + 255) / 256)   // 2344 -- 1 edge/thread (measured best, r0 vs r1/r2)
#define NB_FILL ((N_POS + 255) / 256)   // 2344 -- sequential layout (interleave neutral, r5)
#define NB_GEMM1 ((N_NODES + 63) / 64)  // 1563

// ===== fused: hist_count (+rank persist) + weight transpose/convert =====
// atomicAdd's return value IS the edge's rank among same-dst edges; persisting
// it lets csr-fill compute its slot with pure loads. (verified -13us, r4)
__global__ void hist_wt(const int* __restrict__ dst, int* __restrict__ hist,
                        int* __restrict__ rank,
                        const float* __restrict__ W1, const float* __restrict__ W2,
                        ushort16* __restrict__ W1t, ushort16* __restrict__ W2t) {
    if (blockIdx.x < NB_HIST) {
        int i = blockIdx.x * 256 + threadIdx.x;
        if (i < N_POS) rank[i] = atomicAdd(&hist[dst[i]], 1);
    } else {
        int i = (blockIdx.x - NB_HIST) * 256 + threadIdx.x;
        if (i < 128 * 128) {
            int n = i >> 7, k = i & 127;
            W1t[i] = f2bf(W1[k * 128 + n]);
        } else {
            int j = i - 128 * 128;
            if (j < 64 * 128) {
                int n = j >> 7, k = j & 127;
                W2t[j] = f2bf(W2[k * 64 + n]);
            }
        }
    }
}

__global__ void scan_reduce(const int* __restrict__ hist, int* __restrict__ partials, int n) {
    __shared__ int sdata[256];
    int b = blockIdx.x, t = threadIdx.x;
    int base = b * 1024;
    int s = 0;
    for (int i = t; i < 1024; i += 256) {
        int idx = base + i;
        s += (idx < n) ? hist[idx] : 0;
    }
    sdata[t] = s;
    __syncthreads();
    for (int off = 128; off > 0; off >>= 1) {
        if (t < off) sdata[t] += sdata[t + off];
        __syncthreads();
    }
    if (t == 0) partials[b] = sdata[0];
}

// scan_final computes its own partials-prefix (first wave). NB_SCAN = 98 <= 128.
__global__ void scan_final(const int* __restrict__ hist, const int* __restrict__ partials,
                           int* __restrict__ rowstart, float* __restrict__ dinv, int n) {
    __shared__ int tsum[256];
    __shared__ int base_sh;
    int t = threadIdx.x, b = blockIdx.x;
    if (t < 64) {
        int s0 = (t < b) ? partials[t] : 0;
        int i2 = t + 64;
        int s1 = (i2 < b && i2 < 98) ? partials[i2] : 0;
        int s = s0 + s1;
#pragma unroll
        for (int off = 32; off > 0; off >>= 1) s += __shfl_down(s, off, 64);
        if (t == 0) base_sh = s;
    }
    int base = b * 1024 + t * 4;
    int v[4];
    int s = 0;
#pragma unroll
    for (int j = 0; j < 4; j++) {
        int i = base + j;
        v[j] = (i < n) ? hist[i] : 0;
        s += v[j];
    }
    tsum[t] = s;
    __syncthreads();
    for (int off = 1; off < 256; off <<= 1) {
        int a = (t >= off) ? tsum[t - off] : 0;
        __syncthreads();
        tsum[t] += a;
        __syncthreads();
    }
    int offset = base_sh + (tsum[t] - s);
#pragma unroll
    for (int j = 0; j < 4; j++) {
        int i = base + j;
        if (i < n) {
            rowstart[i] = offset;
            dinv[i] = rsqrtf((float)v[j] + 1.0f);
            offset += v[j];
        }
    }
    if (b == 0 && t == 0) rowstart[n] = N_POS;
}

// ===== shared GEMM tile body: H_bf16[node0..node0+64, M] = X @ W =====
template <int M, bool XBF>
__device__ __forceinline__ void gemm_tile(const void* __restrict__ Xv,
                                          const ushort16* __restrict__ Wt,
                                          ushort16* __restrict__ H, int n, int tileIdx) {
    constexpr int K = 128;
    constexpr int TN = 64;
    constexpr int KH = 64;  // K half
    constexpr int XS = 72;  // padded half-row stride (shorts): 144B -> 2-way bank alias (free)
    __shared__ short Xs[TN * XS];
    __shared__ short Ws[M * XS];
    int tid = threadIdx.x;
    int node0 = tileIdx * TN;

    constexpr int CT = M / 16;
    int w = tid >> 6;
    int lane = tid & 63;
    int l15 = lane & 15;
    int quad = lane >> 4;
    f32x4 acc[CT] = {};

#pragma unroll
    for (int h = 0; h < 2; ++h) {
        if (h) __syncthreads();
        for (int q = tid; q < M * 8; q += 256) {
            int row = q >> 3, c = q & 7;
            uint4 v = *(const uint4*)((const short*)Wt + row * K + h * KH + c * 8);
            *(uint4*)(Ws + row * XS + c * 8) = v;
        }
        if (!XBF) {
            const float* X = (const float*)Xv;
            int row = tid >> 2, part = tid & 3;
            int gn = node0 + row;
#pragma unroll
            for (int c = 0; c < 4; ++c) {
                int kl = part * 16 + c * 4;
                float4 v = (gn < n) ? *(const float4*)(X + (size_t)gn * K + h * KH + kl)
                                    : float4{0, 0, 0, 0};
                uint2 p = {pack2bf(v.x, v.y), pack2bf(v.z, v.w)};
                *(uint2*)(Xs + row * XS + kl) = p;
            }
        } else {
            const short* X = (const short*)Xv;
            for (int q = tid; q < TN * 8; q += 256) {
                int row = q >> 3, c = q & 7;
                int gn = node0 + row;
                uint4 v = (gn < n) ? *(const uint4*)(X + (size_t)gn * K + h * KH + c * 8)
                                   : uint4{0, 0, 0, 0};
                *(uint4*)(Xs + row * XS + c * 8) = v;
            }
        }
        __syncthreads();

        const short* xrow = Xs + (w * 16 + l15) * XS + quad * 8;
#pragma unroll
        for (int kk = 0; kk < 2; ++kk) {
            bf16x8 a = *(const bf16x8*)(xrow + kk * 32);
#pragma unroll
            for (int ct = 0; ct < CT; ++ct) {
                bf16x8 b = *(const bf16x8*)(Ws + (ct * 16 + l15) * XS + quad * 8 + kk * 32);
                acc[ct] = __builtin_amdgcn_mfma_f32_16x16x32_bf16(a, b, acc[ct], 0, 0, 0);
            }
        }
    }

#pragma unroll
    for (int ct = 0; ct < CT; ++ct) {
#pragma unroll
        for (int r = 0; r < 4; ++r) {
            int gn = node0 + w * 16 + quad * 4 + r;
            if (gn < n) H[(size_t)gn * M + ct * 16 + l15] = f2bf(acc[ct][r]);
        }
    }
}

// ===== fused: csr_fill (atomic-free, pure loads) + layer-1 GEMM =====
__global__ __launch_bounds__(256) void csr_gemm1(
    const int* __restrict__ src, const int* __restrict__ dst, const float* __restrict__ dinv,
    const int* __restrict__ rowstart, const int* __restrict__ rank,
    int2* __restrict__ adjw, const float* __restrict__ x,
    const ushort16* __restrict__ W1t, ushort16* __restrict__ H, int n) {
    if (blockIdx.x < NB_FILL) {
        int e = blockIdx.x * 256 + threadIdx.x;
        if (e < N_POS) {
            int s = src[e], d = dst[e];
            int p = rowstart[d] + rank[e];
            adjw[p] = int2{s, __float_as_int(dinv[s] * dinv[d])};
        }
    } else {
        gemm_tile<HIDDEN, false>(x, W1t, H, n, blockIdx.x - NB_FILL);
    }
}

// ===== layer-1 aggregation body for one node (F=128, +bias+relu), 16 lanes =====
// 8-edge predicated prologue + batched tail (4 gathers in flight; verified
// -6us total, r8).
__device__ __forceinline__ uint4 agg_node128(int node, int l, const int* __restrict__ rowstart,
                                             const int2* __restrict__ adjw,
                                             const float* __restrict__ dinv,
                                             const ushort16* __restrict__ H,
                                             const float* __restrict__ bias) {
    float dn = dinv[node];
    int rs = rowstart[node], re = rowstart[node + 1];
    int deg = re - rs;
    int pc = (deg > 0) ? rs : (rs > 0 ? rs - 1 : 0);  // safe clamp index
    uint4 h[8];
    float wv[8];
#pragma unroll
    for (int j = 0; j < 8; ++j) {
        int p = (rs + j < re) ? rs + j : pc;
        int2 e = adjw[p];
        h[j] = *(const uint4*)(H + (size_t)e.x * 128 + l * 8);
        wv[j] = (j < deg) ? __int_as_float(e.y) : 0.0f;
    }
    float s0[8] = {}, s1[8] = {};
#pragma unroll
    for (int j = 0; j < 8; j += 2) {
        s0[0] += bf_lo(h[j].x) * wv[j]; s0[1] += bf_hi(h[j].x) * wv[j];
        s0[2] += bf_lo(h[j].y) * wv[j]; s0[3] += bf_hi(h[j].y) * wv[j];
        s0[4] += bf_lo(h[j].z) * wv[j]; s0[5] += bf_hi(h[j].z) * wv[j];
        s0[6] += bf_lo(h[j].w) * wv[j]; s0[7] += bf_hi(h[j].w) * wv[j];
        s1[0] += bf_lo(h[j + 1].x) * wv[j + 1]; s1[1] += bf_hi(h[j + 1].x) * wv[j + 1];
        s1[2] += bf_lo(h[j + 1].y) * wv[j + 1]; s1[3] += bf_hi(h[j + 1].y) * wv[j + 1];
        s1[4] += bf_lo(h[j + 1].z) * wv[j + 1]; s1[5] += bf_hi(h[j + 1].z) * wv[j + 1];
        s1[6] += bf_lo(h[j + 1].w) * wv[j + 1]; s1[7] += bf_hi(h[j + 1].w) * wv[j + 1];
    }
    // batched tail: 4 predicated gathers in flight per iteration
    for (int p = rs + 8; p < re; p += 4) {
        uint4 ht[4];
        float wt[4];
#pragma unroll
        for (int j = 0; j < 4; ++j) {
            int q = (p + j < re) ? p + j : p;  // p itself is always < re here
            int2 e = adjw[q];
            ht[j] = *(const uint4*)(H + (size_t)e.x * 128 + l * 8);
            wt[j] = (p + j < re) ? __int_as_float(e.y) : 0.0f;
        }
#pragma unroll
        for (int j = 0; j < 4; j += 2) {
            s0[0] += bf_lo(ht[j].x) * wt[j]; s0[1] += bf_hi(ht[j].x) * wt[j];
            s0[2] += bf_lo(ht[j].y) * wt[j]; s0[3] += bf_hi(ht[j].y) * wt[j];
            s0[4] += bf_lo(ht[j].z) * wt[j]; s0[5] += bf_hi(ht[j].z) * wt[j];
            s0[6] += bf_lo(ht[j].w) * wt[j]; s0[7] += bf_hi(ht[j].w) * wt[j];
            s1[0] += bf_lo(ht[j + 1].x) * wt[j + 1]; s1[1] += bf_hi(ht[j + 1].x) * wt[j + 1];
            s1[2] += bf_lo(ht[j + 1].y) * wt[j + 1]; s1[3] += bf_hi(ht[j + 1].y) * wt[j + 1];
            s1[4] += bf_lo(ht[j + 1].z) * wt[j + 1]; s1[5] += bf_hi(ht[j + 1].z) * wt[j + 1];
            s1[6] += bf_lo(ht[j + 1].w) * wt[j + 1]; s1[7] += bf_hi(ht[j + 1].w) * wt[j + 1];
        }
    }
    uint4 hv = *(const uint4*)(H + (size_t)node * 128 + l * 8);
    float4 bv0 = *(const float4*)(bias + l * 8);
    float4 bv1 = *(const float4*)(bias + l * 8 + 4);
    float d2 = dn * dn;
    float hs[8] = {bf_lo(hv.x), bf_hi(hv.x), bf_lo(hv.y), bf_hi(hv.y),
                   bf_lo(hv.z), bf_hi(hv.z), bf_lo(hv.w), bf_hi(hv.w)};
    float bb[8] = {bv0.x, bv0.y, bv0.z, bv0.w, bv1.x, bv1.y, bv1.z, bv1.w};
    float v[8];
#pragma unroll
    for (int j = 0; j < 8; ++j) {
        v[j] = fmaxf(s0[j] + s1[j] + hs[j] * d2 + bb[j], 0.0f);  // relu (layer 1)
    }
    return uint4{pack2bf(v[0], v[1]), pack2bf(v[2], v[3]), pack2bf(v[4], v[5]),
                 pack2bf(v[6], v[7])};
}

// ===== fused: layer-1 agg -> LDS -> layer-2 GEMM, 32 nodes/block =====
// TN 64->32: LDS 34.8KB->26.1KB -> 6 blocks/CU (was 4). Occupancy was the
// binding limit (r4/r8: occ ~30%, nothing saturated, r7 proved per-wave MLP
// can't grow without spill). Per-thread agg body unchanged.
#define ZS 136  // padded row stride (shorts); 272B, 16B-aligned
#define TN2 32  // nodes per block
__global__ __launch_bounds__(256, 4) void agg1_gemm2(
    const int* __restrict__ rowstart, const int2* __restrict__ adjw,
    const float* __restrict__ dinv, const ushort16* __restrict__ H,
    const float* __restrict__ b1, const ushort16* __restrict__ W2t,
    ushort16* __restrict__ h2, int n) {
    __shared__ __align__(16) short Zs[TN2 * ZS];
    __shared__ __align__(16) short Ws[64 * ZS];
    int tid = threadIdx.x;
    int node0 = blockIdx.x * TN2;

    // stage W2t [64 out][128 k] -> Ws (independent of agg; overlaps its latency)
    for (int q = tid; q < 64 * 16; q += 256) {
        int row = q >> 4, c = q & 15;
        uint4 v = *(const uint4*)((const short*)W2t + row * 128 + c * 8);
        *(uint4*)(Ws + row * ZS + c * 8) = v;
    }

    // layer-1 aggregation for 32 nodes: 16 groups x 16 lanes, 2 nodes each
    int g = tid >> 4, l = tid & 15;
#pragma unroll 1
    for (int it = 0; it < 2; ++it) {
        int row = g * 2 + it;
        int node = node0 + row;
        uint4 z = (node < n) ? agg_node128(node, l, rowstart, adjw, dinv, H, b1)
                             : uint4{0, 0, 0, 0};
        *(uint4*)(Zs + row * ZS + l * 8) = z;
    }
    __syncthreads();

    // GEMM: h2[32 x 64] = Zs @ W2. 4 waves: wave w -> row-tile (w>>1),
    // col-tiles (w&1)*32 .. +31 (2 tiles). 8 MFMAs/wave.
    int w = tid >> 6, lane = tid & 63, l15 = lane & 15, quad = lane >> 4;
    int wr = w >> 1, wc = w & 1;
    f32x4 acc[2] = {};
    const short* zrow = Zs + (wr * 16 + l15) * ZS + quad * 8;
#pragma unroll
    for (int kk = 0; kk < 4; ++kk) {
        bf16x8 a = *(const bf16x8*)(zrow + kk * 32);
#pragma unroll
        for (int ct = 0; ct < 2; ++ct) {
            bf16x8 b = *(const bf16x8*)(Ws + (wc * 32 + ct * 16 + l15) * ZS + quad * 8 + kk * 32);
            acc[ct] = __builtin_amdgcn_mfma_f32_16x16x32_bf16(a, b, acc[ct], 0, 0, 0);
        }
    }
#pragma unroll
    for (int ct = 0; ct < 2; ++ct) {
#pragma unroll
        for (int r = 0; r < 4; ++r) {
            int gn = node0 + wr * 16 + quad * 4 + r;
            if (gn < n) h2[(size_t)gn * OUT_CH + wc * 32 + ct * 16 + l15] = f2bf(acc[ct][r]);
        }
    }
}

// ========= pull aggregation + self-loop + bias (+relu), bf16 H/Z =========
// FOUR nodes per wave (16 lanes each). 8-edge predicated prologue + BATCHED
// tail (4 gathers in flight; tail was serial one-round-trip-per-edge).
template <int F, bool RELU>
__global__ void agg_pull(const int* __restrict__ rowstart, const int2* __restrict__ adjw,
                         const float* __restrict__ dinv, const ushort16* __restrict__ H,
                         const float* __restrict__ bias, ushort16* __restrict__ Z, int n) {
    int g = threadIdx.x >> 4;  // 16-lane group
    int l = threadIdx.x & 15;
    int node = blockIdx.x * (blockDim.x >> 4) + g;
    if (node >= n) return;
    float dn = dinv[node];
    int rs = rowstart[node], re = rowstart[node + 1];
    int deg = re - rs;
    int pc = (deg > 0) ? rs : (rs > 0 ? rs - 1 : 0);  // safe clamp index
    if (F == 128) {
        uint4 h[8];
        float wv[8];
#pragma unroll
        for (int j = 0; j < 8; ++j) {
            int p = (rs + j < re) ? rs + j : pc;
            int2 e = adjw[p];
            h[j] = *(const uint4*)(H + (size_t)e.x * F + l * 8);
            wv[j] = (j < deg) ? __int_as_float(e.y) : 0.0f;
        }
        float s0[8] = {}, s1[8] = {};
#pragma unroll
        for (int j = 0; j < 8; j += 2) {
            s0[0] += bf_lo(h[j].x) * wv[j]; s0[1] += bf_hi(h[j].x) * wv[j];
            s0[2] += bf_lo(h[j].y) * wv[j]; s0[3] += bf_hi(h[j].y) * wv[j];
            s0[4] += bf_lo(h[j].z) * wv[j]; s0[5] += bf_hi(h[j].z) * wv[j];
            s0[6] += bf_lo(h[j].w) * wv[j]; s0[7] += bf_hi(h[j].w) * wv[j];
            s1[0] += bf_lo(h[j + 1].x) * wv[j + 1]; s1[1] += bf_hi(h[j + 1].x) * wv[j + 1];
            s1[2] += bf_lo(h[j + 1].y) * wv[j + 1]; s1[3] += bf_hi(h[j + 1].y) * wv[j + 1];
            s1[4] += bf_lo(h[j + 1].z) * wv[j + 1]; s1[5] += bf_hi(h[j + 1].z) * wv[j + 1];
            s1[6] += bf_lo(h[j + 1].w) * wv[j + 1]; s1[7] += bf_hi(h[j + 1].w) * wv[j + 1];
        }
        for (int p = rs + 8; p < re; p += 4) {
            uint4 ht[4];
            float wt[4];
#pragma unroll
            for (int j = 0; j < 4; ++j) {
                int q = (p + j < re) ? p + j : p;
                int2 e = adjw[q];
                ht[j] = *(const uint4*)(H + (size_t)e.x * F + l * 8);
                wt[j] = (p + j < re) ? __int_as_float(e.y) : 0.0f;
            }
#pragma unroll
            for (int j = 0; j < 4; ++j) {
                s0[0] += bf_lo(ht[j].x) * wt[j]; s0[1] += bf_hi(ht[j].x) * wt[j];
                s0[2] += bf_lo(ht[j].y) * wt[j]; s0[3] += bf_hi(ht[j].y) * wt[j];
                s0[4] += bf_lo(ht[j].z) * wt[j]; s0[5] += bf_hi(ht[j].z) * wt[j];
                s0[6] += bf_lo(ht[j].w) * wt[j]; s0[7] += bf_hi(ht[j].w) * wt[j];
            }
        }
        uint4 hv = *(const uint4*)(H + (size_t)node * F + l * 8);
        float4 bv0 = *(const float4*)(bias + l * 8);
        float4 bv1 = *(const float4*)(bias + l * 8 + 4);
        float d2 = dn * dn;
        float hs[8] = {bf_lo(hv.x), bf_hi(hv.x), bf_lo(hv.y), bf_hi(hv.y),
                       bf_lo(hv.z), bf_hi(hv.z), bf_lo(hv.w), bf_hi(hv.w)};
        float bb[8] = {bv0.x, bv0.y, bv0.z, bv0.w, bv1.x, bv1.y, bv1.z, bv1.w};
        float v[8];
#pragma unroll
        for (int j = 0; j < 8; ++j) {
            v[j] = s0[j] + s1[j] + hs[j] * d2 + bb[j];
            if (RELU) v[j] = fmaxf(v[j], 0.0f);
        }
        *(uint4*)(Z + (size_t)node * F + l * 8) =
            uint4{pack2bf(v[0], v[1]), pack2bf(v[2], v[3]), pack2bf(v[4], v[5]),
                  pack2bf(v[6], v[7])};
    } else {  // F == 64
        uint2 h[8];
        float wv[8];
#pragma unroll
        for (int j = 0; j < 8; ++j) {
            int p = (rs + j < re) ? rs + j : pc;
            int2 e = adjw[p];
            h[j] = *(const uint2*)(H + (size_t)e.x * F + l * 4);
            wv[j] = (j < deg) ? __int_as_float(e.y) : 0.0f;
        }
        float s0[4] = {}, s1[4] = {};
#pragma unroll
        for (int j = 0; j < 8; j += 2) {
            s0[0] += bf_lo(h[j].x) * wv[j]; s0[1] += bf_hi(h[j].x) * wv[j];
            s0[2] += bf_lo(h[j].y) * wv[j]; s0[3] += bf_hi(h[j].y) * wv[j];
            s1[0] += bf_lo(h[j + 1].x) * wv[j + 1]; s1[1] += bf_hi(h[j + 1].x) * wv[j + 1];
            s1[2] += bf_lo(h[j + 1].y) * wv[j + 1]; s1[3] += bf_hi(h[j + 1].y) * wv[j + 1];
        }
        for (int p = rs + 8; p < re; p += 4) {
            uint2 ht[4];
            float wt[4];
#pragma unroll
            for (int j = 0; j < 4; ++j) {
                int q = (p + j < re) ? p + j : p;
                int2 e = adjw[q];
                ht[j] = *(const uint2*)(H + (size_t)e.x * F + l * 4);
                wt[j] = (p + j < re) ? __int_as_float(e.y) : 0.0f;
            }
#pragma unroll
            for (int j = 0; j < 4; ++j) {
                s0[0] += bf_lo(ht[j].x) * wt[j]; s0[1] += bf_hi(ht[j].x) * wt[j];
                s0[2] += bf_lo(ht[j].y) * wt[j]; s0[3] += bf_hi(ht[j].y) * wt[j];
            }
        }
        uint2 hv = *(const uint2*)(H + (size_t)node * F + l * 4);
        float4 bv = *(const float4*)(bias + l * 4);
        float d2 = dn * dn;
        float hs[4] = {bf_lo(hv.x), bf_hi(hv.x), bf_lo(hv.y), bf_hi(hv.y)};
        float bb[4] = {bv.x, bv.y, bv.z, bv.w};
        float v[4];
#pragma unroll
        for (int j = 0; j < 4; ++j) {
            v[j] = s0[j] + s1[j] + hs[j] * d2 + bb[j];
            if (RELU) v[j] = fmaxf(v[j], 0.0f);
        }
        *(uint2*)(Z + (size_t)node * F + l * 4) = uint2{pack2bf(v[0], v[1]), pack2bf(v[2], v[3])};
    }
}

// ===== decode via MFMA: 32 edges per wave (two 16-edge groups) =====
__global__ void decode_mfma(const int* __restrict__ pos, const int* __restrict__ neg,
                            const short* __restrict__ Z, float* __restrict__ out) {
    int wid = threadIdx.x >> 6;
    int lane = threadIdx.x & 63;
    int l15 = lane & 15;
    int quad = lane >> 4;
    int e0 = (blockIdx.x * 4 + wid) * 32;
    if (e0 >= N_POS + N_NEG) return;
    const int* bp = (e0 < N_POS) ? pos : (neg - N_POS);
    int eA = e0 + l15;
    int eB = e0 + 16 + l15;
    int aA = bp[eA], bA = bp[600000 + eA];
    int aB = bp[eB], bB = bp[600000 + eB];

    const short* zaA = Z + (size_t)aA * OUT_CH + quad * 8;
    const short* zbA = Z + (size_t)bA * OUT_CH + quad * 8;
    const short* zaB = Z + (size_t)aB * OUT_CH + quad * 8;
    const short* zbB = Z + (size_t)bB * OUT_CH + quad * 8;
    bf16x8 a0A = *(const bf16x8*)(zaA);
    bf16x8 a1A = *(const bf16x8*)(zaA + 32);
    bf16x8 b0A = *(const bf16x8*)(zbA);
    bf16x8 b1A = *(const bf16x8*)(zbA + 32);
    bf16x8 a0B = *(const bf16x8*)(zaB);
    bf16x8 a1B = *(const bf16x8*)(zaB + 32);
    bf16x8 b0B = *(const bf16x8*)(zbB);
    bf16x8 b1B = *(const bf16x8*)(zbB + 32);

    f32x4 accA = {}, accB = {};
    accA = __builtin_amdgcn_mfma_f32_16x16x32_bf16(a0A, b0A, accA, 0, 0, 0);
    accB = __builtin_amdgcn_mfma_f32_16x16x32_bf16(a0B, b0B, accB, 0, 0, 0);
    accA = __builtin_amdgcn_mfma_f32_16x16x32_bf16(a1A, b1A, accA, 0, 0, 0);
    accB = __builtin_amdgcn_mfma_f32_16x16x32_bf16(a1B, b1B, accB, 0, 0, 0);

    if (quad == (l15 >> 2)) {
        out[eA] = accA[l15 & 3];
        out[eB] = accB[l15 & 3];
    }
}

extern "C" void kernel_launch(void* const* d_in, const int* in_sizes, int n_in,
                              void* d_out, int out_size, void* d_ws, size_t ws_size,
                              hipStream_t stream) {
    const float* x = (const float*)d_in[0];
    const int* pos = (const int*)d_in[1];  // row0 = src, row1 = dst
    const int* neg = (const int*)d_in[2];
    const float* W1 = (const float*)d_in[3];
    const float* b1 = (const float*)d_in[4];
    const float* W2 = (const float*)d_in[5];
    const float* b2 = (const float*)d_in[6];
    float* out = (float*)d_out;

    // workspace layout (bf16 intermediates)
    ushort16* A = (ushort16*)d_ws;                      // H [N,128]; later z2 [N,64]
    ushort16* B = A + (size_t)N_NODES * 128;            // h2 [N,64]
    float* dinv = (float*)(B + (size_t)N_NODES * 128);  // [N]
    int* hist = (int*)(dinv + N_NODES);                 // [N]
    int* rowstart = hist + N_NODES;                     // [N+1]
    int2* adjw = (int2*)(rowstart + N_NODES + 1);       // [N_POS] (adj, wgt) pairs
    int* partials = (int*)(adjw + N_POS);               // [128]
    ushort16* W1t = (ushort16*)(partials + 128);        // [128*128]
    ushort16* W2t = W1t + 128 * 128;                    // [64*128]
    // rank[N_POS] overlays B: rank is dead before agg1_gemm2 writes h2 into B
    // (csr_gemm1 completes first; same stream).
    int* rank = (int*)B;

    const int* pos_src = pos;
    const int* pos_dst = pos + N_POS;

    constexpr int NB_SCAN = (N_NODES + 1023) / 1024;  // 98

    // ---- CSR build + dinv + weight convert ----
    hipMemsetAsync(hist, 0, N_NODES * sizeof(int), stream);
    hist_wt<<<NB_HIST + 96, 256, 0, stream>>>(pos_dst, hist, rank, W1, W2, W1t, W2t);
    scan_reduce<<<NB_SCAN, 256, 0, stream>>>(hist, partials, N_NODES);
    scan_final<<<NB_SCAN, 256, 0, stream>>>(hist, partials, rowstart, dinv, N_NODES);

    // ---- csr_fill (atomic-free) + layer-1 GEMM fused (one launch) ----
    csr_gemm1<<<NB_FILL + NB_GEMM1, 256, 0, stream>>>(pos_src, pos_dst, dinv, rowstart, rank,
                                                      adjw, x, W1t, A, N_NODES);

    // ---- fused layer-1 aggregation (batched tail) + layer-2 GEMM, 32 nodes/blk ----
    agg1_gemm2<<<(N_NODES + TN2 - 1) / TN2, 256, 0, stream>>>(rowstart, adjw, dinv, A, b1, W2t,
                                                              B, N_NODES);

    // ---- layer-2 aggregation: reads h2(=B), writes z2(=A) ----
    agg_pull<OUT_CH, false><<<(N_NODES + 15) / 16, 256, 0, stream>>>(rowstart, adjw, dinv, B, b2,
                                                                     A, N_NODES);

    // ---- decode (32 edges/wave, 128/block) ----
    decode_mfma<<<(N_POS + N_NEG) / 128, 256, 0, stream>>>(pos, neg, (const short*)A, out);
}

// Round 10
// 250.880 us; speedup vs baseline: 1.0382x; 1.0027x over previous
//
#include <hip/hip_runtime.h>

#define N_NODES 100000
#define IN_CH 128
#define HIDDEN 128
#define OUT_CH 64
#define N_POS 600000
#define N_NEG 600000

typedef unsigned int uint32;
typedef unsigned short ushort16;
typedef __attribute__((ext_vector_type(8))) short bf16x8;
typedef __attribute__((ext_vector_type(4))) float f32x4;

// ---- bf16 helpers ----
__device__ inline float bf_lo(uint32 u) {
    union { uint32 i; float f; } v;
    v.i = u << 16;
    return v.f;
}
__device__ inline float bf_hi(uint32 u) {
    union { uint32 i; float f; } v;
    v.i = u & 0xffff0000u;
    return v.f;
}
__device__ inline ushort16 f2bf(float f) {
    union { uint32 i; float f; } v;
    v.f = f;
    uint32 r = v.i + 0x7fffu + ((v.i >> 16) & 1u);  // round-to-nearest-even
    return (ushort16)(r >> 16);
}
__device__ inline uint32 pack2bf(float a, float b) {
    return (uint32)f2bf(a) | ((uint32)f2bf(b) << 16);
}

#define NB_HIST ((N_POS + 255) / 256)   // 2344 -- 1 edge/thread (measured best, r0 vs r1/r2)
#define NB_FILL ((N_POS + 255) / 256)   // 2344
#define NB_GEMM1 ((N_NODES + 63) / 64)  // 1563
#define NB_ZERO ((N_NODES + 255) / 256) // 391

// ===== init: zero hist + weight transpose/convert (replaces memset) =====
__global__ void init_wt(int* __restrict__ hist,
                        const float* __restrict__ W1, const float* __restrict__ W2,
                        ushort16* __restrict__ W1t, ushort16* __restrict__ W2t) {
    if (blockIdx.x < NB_ZERO) {
        int i = blockIdx.x * 256 + threadIdx.x;
        if (i < N_NODES) hist[i] = 0;
    } else {
        int i = (blockIdx.x - NB_ZERO) * 256 + threadIdx.x;
        if (i < 128 * 128) {
            int n = i >> 7, k = i & 127;
            W1t[i] = f2bf(W1[k * 128 + n]);
        } else {
            int j = i - 128 * 128;
            if (j < 64 * 128) {
                int n = j >> 7, k = j & 127;
                W2t[j] = f2bf(W2[k * 64 + n]);
            }
        }
    }
}

// ===== shared GEMM tile body: H_bf16[node0..node0+64, M] = X @ W =====
template <int M, bool XBF>
__device__ __forceinline__ void gemm_tile(const void* __restrict__ Xv,
                                          const ushort16* __restrict__ Wt,
                                          ushort16* __restrict__ H, int n, int tileIdx) {
    constexpr int K = 128;
    constexpr int TN = 64;
    constexpr int KH = 64;  // K half
    constexpr int XS = 72;  // padded half-row stride (shorts): 144B -> 2-way bank alias (free)
    __shared__ short Xs[TN * XS];
    __shared__ short Ws[M * XS];
    int tid = threadIdx.x;
    int node0 = tileIdx * TN;

    constexpr int CT = M / 16;
    int w = tid >> 6;
    int lane = tid & 63;
    int l15 = lane & 15;
    int quad = lane >> 4;
    f32x4 acc[CT] = {};

#pragma unroll
    for (int h = 0; h < 2; ++h) {
        if (h) __syncthreads();
        for (int q = tid; q < M * 8; q += 256) {
            int row = q >> 3, c = q & 7;
            uint4 v = *(const uint4*)((const short*)Wt + row * K + h * KH + c * 8);
            *(uint4*)(Ws + row * XS + c * 8) = v;
        }
        if (!XBF) {
            const float* X = (const float*)Xv;
            int row = tid >> 2, part = tid & 3;
            int gn = node0 + row;
#pragma unroll
            for (int c = 0; c < 4; ++c) {
                int kl = part * 16 + c * 4;
                float4 v = (gn < n) ? *(const float4*)(X + (size_t)gn * K + h * KH + kl)
                                    : float4{0, 0, 0, 0};
                uint2 p = {pack2bf(v.x, v.y), pack2bf(v.z, v.w)};
                *(uint2*)(Xs + row * XS + kl) = p;
            }
        } else {
            const short* X = (const short*)Xv;
            for (int q = tid; q < TN * 8; q += 256) {
                int row = q >> 3, c = q & 7;
                int gn = node0 + row;
                uint4 v = (gn < n) ? *(const uint4*)(X + (size_t)gn * K + h * KH + c * 8)
                                   : uint4{0, 0, 0, 0};
                *(uint4*)(Xs + row * XS + c * 8) = v;
            }
        }
        __syncthreads();

        const short* xrow = Xs + (w * 16 + l15) * XS + quad * 8;
#pragma unroll
        for (int kk = 0; kk < 2; ++kk) {
            bf16x8 a = *(const bf16x8*)(xrow + kk * 32);
#pragma unroll
            for (int ct = 0; ct < CT; ++ct) {
                bf16x8 b = *(const bf16x8*)(Ws + (ct * 16 + l15) * XS + quad * 8 + kk * 32);
                acc[ct] = __builtin_amdgcn_mfma_f32_16x16x32_bf16(a, b, acc[ct], 0, 0, 0);
            }
        }
    }

#pragma unroll
    for (int ct = 0; ct < CT; ++ct) {
#pragma unroll
        for (int r = 0; r < 4; ++r) {
            int gn = node0 + w * 16 + quad * 4 + r;
            if (gn < n) H[(size_t)gn * M + ct * 16 + l15] = f2bf(acc[ct][r]);
        }
    }
}

// ===== fused: hist_count (+rank persist) || layer-1 GEMM =====
// These are truly independent (hist: dst only; gemm: x+W1t only) — an
// atomic-latency workload overlapping an MFMA workload. The old fill+gemm
// fusion is dissolved: fill no longer depends on gemm and was paying gemm's
// 27.6KB LDS reservation (5 blocks/CU cap) for nothing (r5: co-residency of
// fill+gemm was neutral).
__global__ __launch_bounds__(256) void hist_gemm(
    const int* __restrict__ dst, int* __restrict__ hist, int* __restrict__ rank,
    const float* __restrict__ x, const ushort16* __restrict__ W1t,
    ushort16* __restrict__ H, int n) {
    if (blockIdx.x < NB_HIST) {
        int i = blockIdx.x * 256 + threadIdx.x;
        if (i < N_POS) rank[i] = atomicAdd(&hist[dst[i]], 1);
    } else {
        gemm_tile<HIDDEN, false>(x, W1t, H, n, blockIdx.x - NB_HIST);
    }
}

__global__ void scan_reduce(const int* __restrict__ hist, int* __restrict__ partials, int n) {
    __shared__ int sdata[256];
    int b = blockIdx.x, t = threadIdx.x;
    int base = b * 1024;
    int s = 0;
    for (int i = t; i < 1024; i += 256) {
        int idx = base + i;
        s += (idx < n) ? hist[idx] : 0;
    }
    sdata[t] = s;
    __syncthreads();
    for (int off = 128; off > 0; off >>= 1) {
        if (t < off) sdata[t] += sdata[t + off];
        __syncthreads();
    }
    if (t == 0) partials[b] = sdata[0];
}

// scan_final computes its own partials-prefix (first wave). NB_SCAN = 98 <= 128.
__global__ void scan_final(const int* __restrict__ hist, const int* __restrict__ partials,
                           int* __restrict__ rowstart, float* __restrict__ dinv, int n) {
    __shared__ int tsum[256];
    __shared__ int base_sh;
    int t = threadIdx.x, b = blockIdx.x;
    if (t < 64) {
        int s0 = (t < b) ? partials[t] : 0;
        int i2 = t + 64;
        int s1 = (i2 < b && i2 < 98) ? partials[i2] : 0;
        int s = s0 + s1;
#pragma unroll
        for (int off = 32; off > 0; off >>= 1) s += __shfl_down(s, off, 64);
        if (t == 0) base_sh = s;
    }
    int base = b * 1024 + t * 4;
    int v[4];
    int s = 0;
#pragma unroll
    for (int j = 0; j < 4; j++) {
        int i = base + j;
        v[j] = (i < n) ? hist[i] : 0;
        s += v[j];
    }
    tsum[t] = s;
    __syncthreads();
    for (int off = 1; off < 256; off <<= 1) {
        int a = (t >= off) ? tsum[t - off] : 0;
        __syncthreads();
        tsum[t] += a;
        __syncthreads();
    }
    int offset = base_sh + (tsum[t] - s);
#pragma unroll
    for (int j = 0; j < 4; j++) {
        int i = base + j;
        if (i < n) {
            rowstart[i] = offset;
            dinv[i] = rsqrtf((float)v[j] + 1.0f);
            offset += v[j];
        }
    }
    if (b == 0 && t == 0) rowstart[n] = N_POS;
}

// ===== csr_fill standalone: atomic-free, NO LDS -> 8 blocks/CU =====
// (was capped at 5 blocks/CU by the fused kernel's 27.6KB LDS reservation)
__global__ __launch_bounds__(256) void csr_fill(
    const int* __restrict__ src, const int* __restrict__ dst, const float* __restrict__ dinv,
    const int* __restrict__ rowstart, const int* __restrict__ rank,
    int2* __restrict__ adjw) {
    int e = blockIdx.x * 256 + threadIdx.x;
    if (e < N_POS) {
        int s = src[e], d = dst[e];
        int p = rowstart[d] + rank[e];
        adjw[p] = int2{s, __float_as_int(dinv[s] * dinv[d])};
    }
}

// ===== layer-1 aggregation body for one node (F=128, +bias+relu), 16 lanes =====
// 8-edge predicated prologue + batched tail (4 gathers in flight; -6us, r8).
__device__ __forceinline__ uint4 agg_node128(int node, int l, const int* __restrict__ rowstart,
                                             const int2* __restrict__ adjw,
                                             const float* __restrict__ dinv,
                                             const ushort16* __restrict__ H,
                                             const float* __restrict__ bias) {
    float dn = dinv[node];
    int rs = rowstart[node], re = rowstart[node + 1];
    int deg = re - rs;
    int pc = (deg > 0) ? rs : (rs > 0 ? rs - 1 : 0);  // safe clamp index
    uint4 h[8];
    float wv[8];
#pragma unroll
    for (int j = 0; j < 8; ++j) {
        int p = (rs + j < re) ? rs + j : pc;
        int2 e = adjw[p];
        h[j] = *(const uint4*)(H + (size_t)e.x * 128 + l * 8);
        wv[j] = (j < deg) ? __int_as_float(e.y) : 0.0f;
    }
    float s0[8] = {}, s1[8] = {};
#pragma unroll
    for (int j = 0; j < 8; j += 2) {
        s0[0] += bf_lo(h[j].x) * wv[j]; s0[1] += bf_hi(h[j].x) * wv[j];
        s0[2] += bf_lo(h[j].y) * wv[j]; s0[3] += bf_hi(h[j].y) * wv[j];
        s0[4] += bf_lo(h[j].z) * wv[j]; s0[5] += bf_hi(h[j].z) * wv[j];
        s0[6] += bf_lo(h[j].w) * wv[j]; s0[7] += bf_hi(h[j].w) * wv[j];
        s1[0] += bf_lo(h[j + 1].x) * wv[j + 1]; s1[1] += bf_hi(h[j + 1].x) * wv[j + 1];
        s1[2] += bf_lo(h[j + 1].y) * wv[j + 1]; s1[3] += bf_hi(h[j + 1].y) * wv[j + 1];
        s1[4] += bf_lo(h[j + 1].z) * wv[j + 1]; s1[5] += bf_hi(h[j + 1].z) * wv[j + 1];
        s1[6] += bf_lo(h[j + 1].w) * wv[j + 1]; s1[7] += bf_hi(h[j + 1].w) * wv[j + 1];
    }
    // batched tail: 4 predicated gathers in flight per iteration
    for (int p = rs + 8; p < re; p += 4) {
        uint4 ht[4];
        float wt[4];
#pragma unroll
        for (int j = 0; j < 4; ++j) {
            int q = (p + j < re) ? p + j : p;  // p itself is always < re here
            int2 e = adjw[q];
            ht[j] = *(const uint4*)(H + (size_t)e.x * 128 + l * 8);
            wt[j] = (p + j < re) ? __int_as_float(e.y) : 0.0f;
        }
#pragma unroll
        for (int j = 0; j < 4; j += 2) {
            s0[0] += bf_lo(ht[j].x) * wt[j]; s0[1] += bf_hi(ht[j].x) * wt[j];
            s0[2] += bf_lo(ht[j].y) * wt[j]; s0[3] += bf_hi(ht[j].y) * wt[j];
            s0[4] += bf_lo(ht[j].z) * wt[j]; s0[5] += bf_hi(ht[j].z) * wt[j];
            s0[6] += bf_lo(ht[j].w) * wt[j]; s0[7] += bf_hi(ht[j].w) * wt[j];
            s1[0] += bf_lo(ht[j + 1].x) * wt[j + 1]; s1[1] += bf_hi(ht[j + 1].x) * wt[j + 1];
            s1[2] += bf_lo(ht[j + 1].y) * wt[j + 1]; s1[3] += bf_hi(ht[j + 1].y) * wt[j + 1];
            s1[4] += bf_lo(ht[j + 1].z) * wt[j + 1]; s1[5] += bf_hi(ht[j + 1].z) * wt[j + 1];
            s1[6] += bf_lo(ht[j + 1].w) * wt[j + 1]; s1[7] += bf_hi(ht[j + 1].w) * wt[j + 1];
        }
    }
    uint4 hv = *(const uint4*)(H + (size_t)node * 128 + l * 8);
    float4 bv0 = *(const float4*)(bias + l * 8);
    float4 bv1 = *(const float4*)(bias + l * 8 + 4);
    float d2 = dn * dn;
    float hs[8] = {bf_lo(hv.x), bf_hi(hv.x), bf_lo(hv.y), bf_hi(hv.y),
                   bf_lo(hv.z), bf_hi(hv.z), bf_lo(hv.w), bf_hi(hv.w)};
    float bb[8] = {bv0.x, bv0.y, bv0.z, bv0.w, bv1.x, bv1.y, bv1.z, bv1.w};
    float v[8];
#pragma unroll
    for (int j = 0; j < 8; ++j) {
        v[j] = fmaxf(s0[j] + s1[j] + hs[j] * d2 + bb[j], 0.0f);  // relu (layer 1)
    }
    return uint4{pack2bf(v[0], v[1]), pack2bf(v[2], v[3]), pack2bf(v[4], v[5]),
                 pack2bf(v[6], v[7])};
}

// ===== fused: layer-1 agg -> LDS -> layer-2 GEMM, 32 nodes/block =====
// (r9: TN2=32 neutral vs 64 -> gather-issue/L2-bound, not occupancy-bound.
// Keeping 32; stop touching this kernel.)
#define ZS 136  // padded row stride (shorts); 272B, 16B-aligned
#define TN2 32  // nodes per block
__global__ __launch_bounds__(256, 4) void agg1_gemm2(
    const int* __restrict__ rowstart, const int2* __restrict__ adjw,
    const float* __restrict__ dinv, const ushort16* __restrict__ H,
    const float* __restrict__ b1, const ushort16* __restrict__ W2t,
    ushort16* __restrict__ h2, int n) {
    __shared__ __align__(16) short Zs[TN2 * ZS];
    __shared__ __align__(16) short Ws[64 * ZS];
    int tid = threadIdx.x;
    int node0 = blockIdx.x * TN2;

    // stage W2t [64 out][128 k] -> Ws (independent of agg; overlaps its latency)
    for (int q = tid; q < 64 * 16; q += 256) {
        int row = q >> 4, c = q & 15;
        uint4 v = *(const uint4*)((const short*)W2t + row * 128 + c * 8);
        *(uint4*)(Ws + row * ZS + c * 8) = v;
    }

    // layer-1 aggregation for 32 nodes: 16 groups x 16 lanes, 2 nodes each
    int g = tid >> 4, l = tid & 15;
#pragma unroll 1
    for (int it = 0; it < 2; ++it) {
        int row = g * 2 + it;
        int node = node0 + row;
        uint4 z = (node < n) ? agg_node128(node, l, rowstart, adjw, dinv, H, b1)
                             : uint4{0, 0, 0, 0};
        *(uint4*)(Zs + row * ZS + l * 8) = z;
    }
    __syncthreads();

    // GEMM: h2[32 x 64] = Zs @ W2. 4 waves: wave w -> row-tile (w>>1),
    // col-tiles (w&1)*32 .. +31 (2 tiles). 8 MFMAs/wave.
    int w = tid >> 6, lane = tid & 63, l15 = lane & 15, quad = lane >> 4;
    int wr = w >> 1, wc = w & 1;
    f32x4 acc[2] = {};
    const short* zrow = Zs + (wr * 16 + l15) * ZS + quad * 8;
#pragma unroll
    for (int kk = 0; kk < 4; ++kk) {
        bf16x8 a = *(const bf16x8*)(zrow + kk * 32);
#pragma unroll
        for (int ct = 0; ct < 2; ++ct) {
            bf16x8 b = *(const bf16x8*)(Ws + (wc * 32 + ct * 16 + l15) * ZS + quad * 8 + kk * 32);
            acc[ct] = __builtin_amdgcn_mfma_f32_16x16x32_bf16(a, b, acc[ct], 0, 0, 0);
        }
    }
#pragma unroll
    for (int ct = 0; ct < 2; ++ct) {
#pragma unroll
        for (int r = 0; r < 4; ++r) {
            int gn = node0 + wr * 16 + quad * 4 + r;
            if (gn < n) h2[(size_t)gn * OUT_CH + wc * 32 + ct * 16 + l15] = f2bf(acc[ct][r]);
        }
    }
}

// ========= pull aggregation + self-loop + bias (+relu), bf16 H/Z =========
// FOUR nodes per wave (16 lanes each). 8-edge predicated prologue + BATCHED
// tail (4 gathers in flight).
template <int F, bool RELU>
__global__ void agg_pull(const int* __restrict__ rowstart, const int2* __restrict__ adjw,
                         const float* __restrict__ dinv, const ushort16* __restrict__ H,
                         const float* __restrict__ bias, ushort16* __restrict__ Z, int n) {
    int g = threadIdx.x >> 4;  // 16-lane group
    int l = threadIdx.x & 15;
    int node = blockIdx.x * (blockDim.x >> 4) + g;
    if (node >= n) return;
    float dn = dinv[node];
    int rs = rowstart[node], re = rowstart[node + 1];
    int deg = re - rs;
    int pc = (deg > 0) ? rs : (rs > 0 ? rs - 1 : 0);  // safe clamp index
    if (F == 128) {
        uint4 h[8];
        float wv[8];
#pragma unroll
        for (int j = 0; j < 8; ++j) {
            int p = (rs + j < re) ? rs + j : pc;
            int2 e = adjw[p];
            h[j] = *(const uint4*)(H + (size_t)e.x * F + l * 8);
            wv[j] = (j < deg) ? __int_as_float(e.y) : 0.0f;
        }
        float s0[8] = {}, s1[8] = {};
#pragma unroll
        for (int j = 0; j < 8; j += 2) {
            s0[0] += bf_lo(h[j].x) * wv[j]; s0[1] += bf_hi(h[j].x) * wv[j];
            s0[2] += bf_lo(h[j].y) * wv[j]; s0[3] += bf_hi(h[j].y) * wv[j];
            s0[4] += bf_lo(h[j].z) * wv[j]; s0[5] += bf_hi(h[j].z) * wv[j];
            s0[6] += bf_lo(h[j].w) * wv[j]; s0[7] += bf_hi(h[j].w) * wv[j];
            s1[0] += bf_lo(h[j + 1].x) * wv[j + 1]; s1[1] += bf_hi(h[j + 1].x) * wv[j + 1];
            s1[2] += bf_lo(h[j + 1].y) * wv[j + 1]; s1[3] += bf_hi(h[j + 1].y) * wv[j + 1];
            s1[4] += bf_lo(h[j + 1].z) * wv[j + 1]; s1[5] += bf_hi(h[j + 1].z) * wv[j + 1];
            s1[6] += bf_lo(h[j + 1].w) * wv[j + 1]; s1[7] += bf_hi(h[j + 1].w) * wv[j + 1];
        }
        for (int p = rs + 8; p < re; p += 4) {
            uint4 ht[4];
            float wt[4];
#pragma unroll
            for (int j = 0; j < 4; ++j) {
                int q = (p + j < re) ? p + j : p;
                int2 e = adjw[q];
                ht[j] = *(const uint4*)(H + (size_t)e.x * F + l * 8);
                wt[j] = (p + j < re) ? __int_as_float(e.y) : 0.0f;
            }
#pragma unroll
            for (int j = 0; j < 4; ++j) {
                s0[0] += bf_lo(ht[j].x) * wt[j]; s0[1] += bf_hi(ht[j].x) * wt[j];
                s0[2] += bf_lo(ht[j].y) * wt[j]; s0[3] += bf_hi(ht[j].y) * wt[j];
                s0[4] += bf_lo(ht[j].z) * wt[j]; s0[5] += bf_hi(ht[j].z) * wt[j];
                s0[6] += bf_lo(ht[j].w) * wt[j]; s0[7] += bf_hi(ht[j].w) * wt[j];
            }
        }
        uint4 hv = *(const uint4*)(H + (size_t)node * F + l * 8);
        float4 bv0 = *(const float4*)(bias + l * 8);
        float4 bv1 = *(const float4*)(bias + l * 8 + 4);
        float d2 = dn * dn;
        float hs[8] = {bf_lo(hv.x), bf_hi(hv.x), bf_lo(hv.y), bf_hi(hv.y),
                       bf_lo(hv.z), bf_hi(hv.z), bf_lo(hv.w), bf_hi(hv.w)};
        float bb[8] = {bv0.x, bv0.y, bv0.z, bv0.w, bv1.x, bv1.y, bv1.z, bv1.w};
        float v[8];
#pragma unroll
        for (int j = 0; j < 8; ++j) {
            v[j] = s0[j] + s1[j] + hs[j] * d2 + bb[j];
            if (RELU) v[j] = fmaxf(v[j], 0.0f);
        }
        *(uint4*)(Z + (size_t)node * F + l * 8) =
            uint4{pack2bf(v[0], v[1]), pack2bf(v[2], v[3]), pack2bf(v[4], v[5]),
                  pack2bf(v[6], v[7])};
    } else {  // F == 64
        uint2 h[8];
        float wv[8];
#pragma unroll
        for (int j = 0; j < 8; ++j) {
            int p = (rs + j < re) ? rs + j : pc;
            int2 e = adjw[p];
            h[j] = *(const uint2*)(H + (size_t)e.x * F + l * 4);
            wv[j] = (j < deg) ? __int_as_float(e.y) : 0.0f;
        }
        float s0[4] = {}, s1[4] = {};
#pragma unroll
        for (int j = 0; j < 8; j += 2) {
            s0[0] += bf_lo(h[j].x) * wv[j]; s0[1] += bf_hi(h[j].x) * wv[j];
            s0[2] += bf_lo(h[j].y) * wv[j]; s0[3] += bf_hi(h[j].y) * wv[j];
            s1[0] += bf_lo(h[j + 1].x) * wv[j + 1]; s1[1] += bf_hi(h[j + 1].x) * wv[j + 1];
            s1[2] += bf_lo(h[j + 1].y) * wv[j + 1]; s1[3] += bf_hi(h[j + 1].y) * wv[j + 1];
        }
        for (int p = rs + 8; p < re; p += 4) {
            uint2 ht[4];
            float wt[4];
#pragma unroll
            for (int j = 0; j < 4; ++j) {
                int q = (p + j < re) ? p + j : p;
                int2 e = adjw[q];
                ht[j] = *(const uint2*)(H + (size_t)e.x * F + l * 4);
                wt[j] = (p + j < re) ? __int_as_float(e.y) : 0.0f;
            }
#pragma unroll
            for (int j = 0; j < 4; ++j) {
                s0[0] += bf_lo(ht[j].x) * wt[j]; s0[1] += bf_hi(ht[j].x) * wt[j];
                s0[2] += bf_lo(ht[j].y) * wt[j]; s0[3] += bf_hi(ht[j].y) * wt[j];
            }
        }
        uint2 hv = *(const uint2*)(H + (size_t)node * F + l * 4);
        float4 bv = *(const float4*)(bias + l * 4);
        float d2 = dn * dn;
        float hs[4] = {bf_lo(hv.x), bf_hi(hv.x), bf_lo(hv.y), bf_hi(hv.y)};
        float bb[4] = {bv.x, bv.y, bv.z, bv.w};
        float v[4];
#pragma unroll
        for (int j = 0; j < 4; ++j) {
            v[j] = s0[j] + s1[j] + hs[j] * d2 + bb[j];
            if (RELU) v[j] = fmaxf(v[j], 0.0f);
        }
        *(uint2*)(Z + (size_t)node * F + l * 4) = uint2{pack2bf(v[0], v[1]), pack2bf(v[2], v[3])};
    }
}

// ===== decode via MFMA: 32 edges per wave (two 16-edge groups) =====
__global__ void decode_mfma(const int* __restrict__ pos, const int* __restrict__ neg,
                            const short* __restrict__ Z, float* __restrict__ out) {
    int wid = threadIdx.x >> 6;
    int lane = threadIdx.x & 63;
    int l15 = lane & 15;
    int quad = lane >> 4;
    int e0 = (blockIdx.x * 4 + wid) * 32;
    if (e0 >= N_POS + N_NEG) return;
    const int* bp = (e0 < N_POS) ? pos : (neg - N_POS);
    int eA = e0 + l15;
    int eB = e0 + 16 + l15;
    int aA = bp[eA], bA = bp[600000 + eA];
    int aB = bp[eB], bB = bp[600000 + eB];

    const short* zaA = Z + (size_t)aA * OUT_CH + quad * 8;
    const short* zbA = Z + (size_t)bA * OUT_CH + quad * 8;
    const short* zaB = Z + (size_t)aB * OUT_CH + quad * 8;
    const short* zbB = Z + (size_t)bB * OUT_CH + quad * 8;
    bf16x8 a0A = *(const bf16x8*)(zaA);
    bf16x8 a1A = *(const bf16x8*)(zaA + 32);
    bf16x8 b0A = *(const bf16x8*)(zbA);
    bf16x8 b1A = *(const bf16x8*)(zbA + 32);
    bf16x8 a0B = *(const bf16x8*)(zaB);
    bf16x8 a1B = *(const bf16x8*)(zaB + 32);
    bf16x8 b0B = *(const bf16x8*)(zbB);
    bf16x8 b1B = *(const bf16x8*)(zbB + 32);

    f32x4 accA = {}, accB = {};
    accA = __builtin_amdgcn_mfma_f32_16x16x32_bf16(a0A, b0A, accA, 0, 0, 0);
    accB = __builtin_amdgcn_mfma_f32_16x16x32_bf16(a0B, b0B, accB, 0, 0, 0);
    accA = __builtin_amdgcn_mfma_f32_16x16x32_bf16(a1A, b1A, accA, 0, 0, 0);
    accB = __builtin_amdgcn_mfma_f32_16x16x32_bf16(a1B, b1B, accB, 0, 0, 0);

    if (quad == (l15 >> 2)) {
        out[eA] = accA[l15 & 3];
        out[eB] = accB[l15 & 3];
    }
}

extern "C" void kernel_launch(void* const* d_in, const int* in_sizes, int n_in,
                              void* d_out, int out_size, void* d_ws, size_t ws_size,
                              hipStream_t stream) {
    const float* x = (const float*)d_in[0];
    const int* pos = (const int*)d_in[1];  // row0 = src, row1 = dst
    const int* neg = (const int*)d_in[2];
    const float* W1 = (const float*)d_in[3];
    const float* b1 = (const float*)d_in[4];
    const float* W2 = (const float*)d_in[5];
    const float* b2 = (const float*)d_in[6];
    float* out = (float*)d_out;

    // workspace layout (bf16 intermediates)
    ushort16* A = (ushort16*)d_ws;                      // H [N,128]; later z2 [N,64]
    ushort16* B = A + (size_t)N_NODES * 128;            // h2 [N,64]
    float* dinv = (float*)(B + (size_t)N_NODES * 128);  // [N]
    int* hist = (int*)(dinv + N_NODES);                 // [N]
    int* rowstart = hist + N_NODES;                     // [N+1]
    int2* adjw = (int2*)(rowstart + N_NODES + 1);       // [N_POS] (adj, wgt) pairs
    int* partials = (int*)(adjw + N_POS);               // [128]
    ushort16* W1t = (ushort16*)(partials + 128);        // [128*128]
    ushort16* W2t = W1t + 128 * 128;                    // [64*128]
    // rank[N_POS] overlays B: rank is dead before agg1_gemm2 writes h2 into B.
    int* rank = (int*)B;

    const int* pos_src = pos;
    const int* pos_dst = pos + N_POS;

    constexpr int NB_SCAN = (N_NODES + 1023) / 1024;  // 98

    // ---- init: zero hist + weight convert (one kernel, replaces memset) ----
    init_wt<<<NB_ZERO + 96, 256, 0, stream>>>(hist, W1, W2, W1t, W2t);

    // ---- hist+rank (atomics) || layer-1 GEMM (MFMA) — truly independent ----
    hist_gemm<<<NB_HIST + NB_GEMM1, 256, 0, stream>>>(pos_dst, hist, rank, x, W1t, A, N_NODES);

    // ---- scan ----
    scan_reduce<<<NB_SCAN, 256, 0, stream>>>(hist, partials, N_NODES);
    scan_final<<<NB_SCAN, 256, 0, stream>>>(hist, partials, rowstart, dinv, N_NODES);

    // ---- csr_fill standalone (no LDS, 8 blocks/CU) ----
    csr_fill<<<NB_FILL, 256, 0, stream>>>(pos_src, pos_dst, dinv, rowstart, rank, adjw);

    // ---- fused layer-1 aggregation (batched tail) + layer-2 GEMM, 32 nodes/blk ----
    agg1_gemm2<<<(N_NODES + TN2 - 1) / TN2, 256, 0, stream>>>(rowstart, adjw, dinv, A, b1, W2t,
                                                              B, N_NODES);

    // ---- layer-2 aggregation: reads h2(=B), writes z2(=A) ----
    agg_pull<OUT_CH, false><<<(N_NODES + 15) / 16, 256, 0, stream>>>(rowstart, adjw, dinv, B, b2,
                                                                     A, N_NODES);

    // ---- decode (32 edges/wave, 128/block) ----
    decode_mfma<<<(N_POS + N_NEG) / 128, 256, 0, stream>>>(pos, neg, (const short*)A, out);
}

// Round 11
// 247.500 us; speedup vs baseline: 1.0523x; 1.0137x over previous
//
#include <hip/hip_runtime.h>

#define N_NODES 100000
#define IN_CH 128
#define HIDDEN 128
#define OUT_CH 64
#define N_POS 600000
#define N_NEG 600000

typedef unsigned int uint32;
typedef unsigned short ushort16;
typedef __attribute__((ext_vector_type(8))) short bf16x8;
typedef __attribute__((ext_vector_type(4))) float f32x4;

// ---- bf16 helpers ----
__device__ inline float bf_lo(uint32 u) {
    union { uint32 i; float f; } v;
    v.i = u << 16;
    return v.f;
}
__device__ inline float bf_hi(uint32 u) {
    union { uint32 i; float f; } v;
    v.i = u & 0xffff0000u;
    return v.f;
}
__device__ inline ushort16 f2bf(float f) {
    union { uint32 i; float f; } v;
    v.f = f;
    uint32 r = v.i + 0x7fffu + ((v.i >> 16) & 1u);  // round-to-nearest-even
    return (ushort16)(r >> 16);
}
__device__ inline uint32 pack2bf(float a, float b) {
    return (uint32)f2bf(a) | ((uint32)f2bf(b) << 16);
}

#define NB_HIST ((N_POS + 255) / 256)   // 2344 -- 1 edge/thread (measured best, r0 vs r1/r2)
#define NB_FILL ((N_POS + 255) / 256)   // 2344
#define NB_GEMM1 ((N_NODES + 63) / 64)  // 1563
#define NB_ZERO ((N_NODES + 255) / 256) // 391
// hist||gemm interleave: groups of 5 = 3 hist + 2 gemm (2344:1563 ~ 3:2).
// r10 counters: sequential-role dispatch gave 53.5us = hist(29)+gemm(27) SUM
// (zero overlap). hist is atomic-unit-bound (~0 BW), gemm is MFMA/LDS-bound —
// resource-orthogonal, so co-residency should give ~max not sum. (r5's null
// was fill+gemm: fill contends on the vector-memory pipe; hist doesn't.)
#define NB_HG_GROUPS ((NB_HIST + 2) / 3)  // 782
#define NB_HG (NB_HG_GROUPS * 5)          // 3910

// ===== init: zero hist + weight transpose/convert (replaces memset) =====
__global__ void init_wt(int* __restrict__ hist,
                        const float* __restrict__ W1, const float* __restrict__ W2,
                        ushort16* __restrict__ W1t, ushort16* __restrict__ W2t) {
    if (blockIdx.x < NB_ZERO) {
        int i = blockIdx.x * 256 + threadIdx.x;
        if (i < N_NODES) hist[i] = 0;
    } else {
        int i = (blockIdx.x - NB_ZERO) * 256 + threadIdx.x;
        if (i < 128 * 128) {
            int n = i >> 7, k = i & 127;
            W1t[i] = f2bf(W1[k * 128 + n]);
        } else {
            int j = i - 128 * 128;
            if (j < 64 * 128) {
                int n = j >> 7, k = j & 127;
                W2t[j] = f2bf(W2[k * 64 + n]);
            }
        }
    }
}

// ===== shared GEMM tile body: H_bf16[node0..node0+64, M] = X @ W =====
template <int M, bool XBF>
__device__ __forceinline__ void gemm_tile(const void* __restrict__ Xv,
                                          const ushort16* __restrict__ Wt,
                                          ushort16* __restrict__ H, int n, int tileIdx) {
    constexpr int K = 128;
    constexpr int TN = 64;
    constexpr int KH = 64;  // K half
    constexpr int XS = 72;  // padded half-row stride (shorts): 144B -> 2-way bank alias (free)
    __shared__ short Xs[TN * XS];
    __shared__ short Ws[M * XS];
    int tid = threadIdx.x;
    int node0 = tileIdx * TN;

    constexpr int CT = M / 16;
    int w = tid >> 6;
    int lane = tid & 63;
    int l15 = lane & 15;
    int quad = lane >> 4;
    f32x4 acc[CT] = {};

#pragma unroll
    for (int h = 0; h < 2; ++h) {
        if (h) __syncthreads();
        for (int q = tid; q < M * 8; q += 256) {
            int row = q >> 3, c = q & 7;
            uint4 v = *(const uint4*)((const short*)Wt + row * K + h * KH + c * 8);
            *(uint4*)(Ws + row * XS + c * 8) = v;
        }
        if (!XBF) {
            const float* X = (const float*)Xv;
            int row = tid >> 2, part = tid & 3;
            int gn = node0 + row;
#pragma unroll
            for (int c = 0; c < 4; ++c) {
                int kl = part * 16 + c * 4;
                float4 v = (gn < n) ? *(const float4*)(X + (size_t)gn * K + h * KH + kl)
                                    : float4{0, 0, 0, 0};
                uint2 p = {pack2bf(v.x, v.y), pack2bf(v.z, v.w)};
                *(uint2*)(Xs + row * XS + kl) = p;
            }
        } else {
            const short* X = (const short*)Xv;
            for (int q = tid; q < TN * 8; q += 256) {
                int row = q >> 3, c = q & 7;
                int gn = node0 + row;
                uint4 v = (gn < n) ? *(const uint4*)(X + (size_t)gn * K + h * KH + c * 8)
                                   : uint4{0, 0, 0, 0};
                *(uint4*)(Xs + row * XS + c * 8) = v;
            }
        }
        __syncthreads();

        const short* xrow = Xs + (w * 16 + l15) * XS + quad * 8;
#pragma unroll
        for (int kk = 0; kk < 2; ++kk) {
            bf16x8 a = *(const bf16x8*)(xrow + kk * 32);
#pragma unroll
            for (int ct = 0; ct < CT; ++ct) {
                bf16x8 b = *(const bf16x8*)(Ws + (ct * 16 + l15) * XS + quad * 8 + kk * 32);
                acc[ct] = __builtin_amdgcn_mfma_f32_16x16x32_bf16(a, b, acc[ct], 0, 0, 0);
            }
        }
    }

#pragma unroll
    for (int ct = 0; ct < CT; ++ct) {
#pragma unroll
        for (int r = 0; r < 4; ++r) {
            int gn = node0 + w * 16 + quad * 4 + r;
            if (gn < n) H[(size_t)gn * M + ct * 16 + l15] = f2bf(acc[ct][r]);
        }
    }
}

// ===== hist_count (+rank persist) || layer-1 GEMM, role-INTERLEAVED =====
__global__ __launch_bounds__(256) void hist_gemm(
    const int* __restrict__ dst, int* __restrict__ hist, int* __restrict__ rank,
    const float* __restrict__ x, const ushort16* __restrict__ W1t,
    ushort16* __restrict__ H, int n) {
    int bid = blockIdx.x;
    int g = bid / 5, r = bid % 5;
    if (r < 3) {
        int hb = g * 3 + r;
        if (hb >= NB_HIST) return;
        int i = hb * 256 + threadIdx.x;
        if (i < N_POS) rank[i] = atomicAdd(&hist[dst[i]], 1);
    } else {
        int gb = g * 2 + (r - 3);
        if (gb >= NB_GEMM1) return;
        gemm_tile<HIDDEN, false>(x, W1t, H, n, gb);
    }
}

__global__ void scan_reduce(const int* __restrict__ hist, int* __restrict__ partials, int n) {
    __shared__ int sdata[256];
    int b = blockIdx.x, t = threadIdx.x;
    int base = b * 1024;
    int s = 0;
    for (int i = t; i < 1024; i += 256) {
        int idx = base + i;
        s += (idx < n) ? hist[idx] : 0;
    }
    sdata[t] = s;
    __syncthreads();
    for (int off = 128; off > 0; off >>= 1) {
        if (t < off) sdata[t] += sdata[t + off];
        __syncthreads();
    }
    if (t == 0) partials[b] = sdata[0];
}

// scan_final computes its own partials-prefix (first wave). NB_SCAN = 98 <= 128.
__global__ void scan_final(const int* __restrict__ hist, const int* __restrict__ partials,
                           int* __restrict__ rowstart, float* __restrict__ dinv, int n) {
    __shared__ int tsum[256];
    __shared__ int base_sh;
    int t = threadIdx.x, b = blockIdx.x;
    if (t < 64) {
        int s0 = (t < b) ? partials[t] : 0;
        int i2 = t + 64;
        int s1 = (i2 < b && i2 < 98) ? partials[i2] : 0;
        int s = s0 + s1;
#pragma unroll
        for (int off = 32; off > 0; off >>= 1) s += __shfl_down(s, off, 64);
        if (t == 0) base_sh = s;
    }
    int base = b * 1024 + t * 4;
    int v[4];
    int s = 0;
#pragma unroll
    for (int j = 0; j < 4; j++) {
        int i = base + j;
        v[j] = (i < n) ? hist[i] : 0;
        s += v[j];
    }
    tsum[t] = s;
    __syncthreads();
    for (int off = 1; off < 256; off <<= 1) {
        int a = (t >= off) ? tsum[t - off] : 0;
        __syncthreads();
        tsum[t] += a;
        __syncthreads();
    }
    int offset = base_sh + (tsum[t] - s);
#pragma unroll
    for (int j = 0; j < 4; j++) {
        int i = base + j;
        if (i < n) {
            rowstart[i] = offset;
            dinv[i] = rsqrtf((float)v[j] + 1.0f);
            offset += v[j];
        }
    }
    if (b == 0 && t == 0) rowstart[n] = N_POS;
}

// ===== csr_fill standalone: atomic-free, NO LDS -> 8 blocks/CU =====
__global__ __launch_bounds__(256) void csr_fill(
    const int* __restrict__ src, const int* __restrict__ dst, const float* __restrict__ dinv,
    const int* __restrict__ rowstart, const int* __restrict__ rank,
    int2* __restrict__ adjw) {
    int e = blockIdx.x * 256 + threadIdx.x;
    if (e < N_POS) {
        int s = src[e], d = dst[e];
        int p = rowstart[d] + rank[e];
        adjw[p] = int2{s, __float_as_int(dinv[s] * dinv[d])};
    }
}

// ===== layer-1 aggregation body for one node (F=128, +bias+relu), 16 lanes =====
// 8-edge predicated prologue + batched tail (4 gathers in flight; -6us, r8).
__device__ __forceinline__ uint4 agg_node128(int node, int l, const int* __restrict__ rowstart,
                                             const int2* __restrict__ adjw,
                                             const float* __restrict__ dinv,
                                             const ushort16* __restrict__ H,
                                             const float* __restrict__ bias) {
    float dn = dinv[node];
    int rs = rowstart[node], re = rowstart[node + 1];
    int deg = re - rs;
    int pc = (deg > 0) ? rs : (rs > 0 ? rs - 1 : 0);  // safe clamp index
    uint4 h[8];
    float wv[8];
#pragma unroll
    for (int j = 0; j < 8; ++j) {
        int p = (rs + j < re) ? rs + j : pc;
        int2 e = adjw[p];
        h[j] = *(const uint4*)(H + (size_t)e.x * 128 + l * 8);
        wv[j] = (j < deg) ? __int_as_float(e.y) : 0.0f;
    }
    float s0[8] = {}, s1[8] = {};
#pragma unroll
    for (int j = 0; j < 8; j += 2) {
        s0[0] += bf_lo(h[j].x) * wv[j]; s0[1] += bf_hi(h[j].x) * wv[j];
        s0[2] += bf_lo(h[j].y) * wv[j]; s0[3] += bf_hi(h[j].y) * wv[j];
        s0[4] += bf_lo(h[j].z) * wv[j]; s0[5] += bf_hi(h[j].z) * wv[j];
        s0[6] += bf_lo(h[j].w) * wv[j]; s0[7] += bf_hi(h[j].w) * wv[j];
        s1[0] += bf_lo(h[j + 1].x) * wv[j + 1]; s1[1] += bf_hi(h[j + 1].x) * wv[j + 1];
        s1[2] += bf_lo(h[j + 1].y) * wv[j + 1]; s1[3] += bf_hi(h[j + 1].y) * wv[j + 1];
        s1[4] += bf_lo(h[j + 1].z) * wv[j + 1]; s1[5] += bf_hi(h[j + 1].z) * wv[j + 1];
        s1[6] += bf_lo(h[j + 1].w) * wv[j + 1]; s1[7] += bf_hi(h[j + 1].w) * wv[j + 1];
    }
    // batched tail: 4 predicated gathers in flight per iteration
    for (int p = rs + 8; p < re; p += 4) {
        uint4 ht[4];
        float wt[4];
#pragma unroll
        for (int j = 0; j < 4; ++j) {
            int q = (p + j < re) ? p + j : p;  // p itself is always < re here
            int2 e = adjw[q];
            ht[j] = *(const uint4*)(H + (size_t)e.x * 128 + l * 8);
            wt[j] = (p + j < re) ? __int_as_float(e.y) : 0.0f;
        }
#pragma unroll
        for (int j = 0; j < 4; j += 2) {
            s0[0] += bf_lo(ht[j].x) * wt[j]; s0[1] += bf_hi(ht[j].x) * wt[j];
            s0[2] += bf_lo(ht[j].y) * wt[j]; s0[3] += bf_hi(ht[j].y) * wt[j];
            s0[4] += bf_lo(ht[j].z) * wt[j]; s0[5] += bf_hi(ht[j].z) * wt[j];
            s0[6] += bf_lo(ht[j].w) * wt[j]; s0[7] += bf_hi(ht[j].w) * wt[j];
            s1[0] += bf_lo(ht[j + 1].x) * wt[j + 1]; s1[1] += bf_hi(ht[j + 1].x) * wt[j + 1];
            s1[2] += bf_lo(ht[j + 1].y) * wt[j + 1]; s1[3] += bf_hi(ht[j + 1].y) * wt[j + 1];
            s1[4] += bf_lo(ht[j + 1].z) * wt[j + 1]; s1[5] += bf_hi(ht[j + 1].z) * wt[j + 1];
            s1[6] += bf_lo(ht[j + 1].w) * wt[j + 1]; s1[7] += bf_hi(ht[j + 1].w) * wt[j + 1];
        }
    }
    uint4 hv = *(const uint4*)(H + (size_t)node * 128 + l * 8);
    float4 bv0 = *(const float4*)(bias + l * 8);
    float4 bv1 = *(const float4*)(bias + l * 8 + 4);
    float d2 = dn * dn;
    float hs[8] = {bf_lo(hv.x), bf_hi(hv.x), bf_lo(hv.y), bf_hi(hv.y),
                   bf_lo(hv.z), bf_hi(hv.z), bf_lo(hv.w), bf_hi(hv.w)};
    float bb[8] = {bv0.x, bv0.y, bv0.z, bv0.w, bv1.x, bv1.y, bv1.z, bv1.w};
    float v[8];
#pragma unroll
    for (int j = 0; j < 8; ++j) {
        v[j] = fmaxf(s0[j] + s1[j] + hs[j] * d2 + bb[j], 0.0f);  // relu (layer 1)
    }
    return uint4{pack2bf(v[0], v[1]), pack2bf(v[2], v[3]), pack2bf(v[4], v[5]),
                 pack2bf(v[6], v[7])};
}

// ===== fused: layer-1 agg -> LDS -> layer-2 GEMM, 32 nodes/block =====
// (r9: TN2=32 neutral vs 64 -> gather-issue/L2-bound, not occupancy-bound.)
#define ZS 136  // padded row stride (shorts); 272B, 16B-aligned
#define TN2 32  // nodes per block
__global__ __launch_bounds__(256, 4) void agg1_gemm2(
    const int* __restrict__ rowstart, const int2* __restrict__ adjw,
    const float* __restrict__ dinv, const ushort16* __restrict__ H,
    const float* __restrict__ b1, const ushort16* __restrict__ W2t,
    ushort16* __restrict__ h2, int n) {
    __shared__ __align__(16) short Zs[TN2 * ZS];
    __shared__ __align__(16) short Ws[64 * ZS];
    int tid = threadIdx.x;
    int node0 = blockIdx.x * TN2;

    // stage W2t [64 out][128 k] -> Ws (independent of agg; overlaps its latency)
    for (int q = tid; q < 64 * 16; q += 256) {
        int row = q >> 4, c = q & 15;
        uint4 v = *(const uint4*)((const short*)W2t + row * 128 + c * 8);
        *(uint4*)(Ws + row * ZS + c * 8) = v;
    }

    // layer-1 aggregation for 32 nodes: 16 groups x 16 lanes, 2 nodes each
    int g = tid >> 4, l = tid & 15;
#pragma unroll 1
    for (int it = 0; it < 2; ++it) {
        int row = g * 2 + it;
        int node = node0 + row;
        uint4 z = (node < n) ? agg_node128(node, l, rowstart, adjw, dinv, H, b1)
                             : uint4{0, 0, 0, 0};
        *(uint4*)(Zs + row * ZS + l * 8) = z;
    }
    __syncthreads();

    // GEMM: h2[32 x 64] = Zs @ W2. 4 waves: wave w -> row-tile (w>>1),
    // col-tiles (w&1)*32 .. +31 (2 tiles). 8 MFMAs/wave.
    int w = tid >> 6, lane = tid & 63, l15 = lane & 15, quad = lane >> 4;
    int wr = w >> 1, wc = w & 1;
    f32x4 acc[2] = {};
    const short* zrow = Zs + (wr * 16 + l15) * ZS + quad * 8;
#pragma unroll
    for (int kk = 0; kk < 4; ++kk) {
        bf16x8 a = *(const bf16x8*)(zrow + kk * 32);
#pragma unroll
        for (int ct = 0; ct < 2; ++ct) {
            bf16x8 b = *(const bf16x8*)(Ws + (wc * 32 + ct * 16 + l15) * ZS + quad * 8 + kk * 32);
            acc[ct] = __builtin_amdgcn_mfma_f32_16x16x32_bf16(a, b, acc[ct], 0, 0, 0);
        }
    }
#pragma unroll
    for (int ct = 0; ct < 2; ++ct) {
#pragma unroll
        for (int r = 0; r < 4; ++r) {
            int gn = node0 + wr * 16 + quad * 4 + r;
            if (gn < n) h2[(size_t)gn * OUT_CH + wc * 32 + ct * 16 + l15] = f2bf(acc[ct][r]);
        }
    }
}

// ========= pull aggregation + self-loop + bias (+relu), bf16 H/Z =========
// FOUR nodes per wave (16 lanes each). 8-edge predicated prologue + BATCHED
// tail (4 gathers in flight).
template <int F, bool RELU>
__global__ void agg_pull(const int* __restrict__ rowstart, const int2* __restrict__ adjw,
                         const float* __restrict__ dinv, const ushort16* __restrict__ H,
                         const float* __restrict__ bias, ushort16* __restrict__ Z, int n) {
    int g = threadIdx.x >> 4;  // 16-lane group
    int l = threadIdx.x & 15;
    int node = blockIdx.x * (blockDim.x >> 4) + g;
    if (node >= n) return;
    float dn = dinv[node];
    int rs = rowstart[node], re = rowstart[node + 1];
    int deg = re - rs;
    int pc = (deg > 0) ? rs : (rs > 0 ? rs - 1 : 0);  // safe clamp index
    if (F == 128) {
        uint4 h[8];
        float wv[8];
#pragma unroll
        for (int j = 0; j < 8; ++j) {
            int p = (rs + j < re) ? rs + j : pc;
            int2 e = adjw[p];
            h[j] = *(const uint4*)(H + (size_t)e.x * F + l * 8);
            wv[j] = (j < deg) ? __int_as_float(e.y) : 0.0f;
        }
        float s0[8] = {}, s1[8] = {};
#pragma unroll
        for (int j = 0; j < 8; j += 2) {
            s0[0] += bf_lo(h[j].x) * wv[j]; s0[1] += bf_hi(h[j].x) * wv[j];
            s0[2] += bf_lo(h[j].y) * wv[j]; s0[3] += bf_hi(h[j].y) * wv[j];
            s0[4] += bf_lo(h[j].z) * wv[j]; s0[5] += bf_hi(h[j].z) * wv[j];
            s0[6] += bf_lo(h[j].w) * wv[j]; s0[7] += bf_hi(h[j].w) * wv[j];
            s1[0] += bf_lo(h[j + 1].x) * wv[j + 1]; s1[1] += bf_hi(h[j + 1].x) * wv[j + 1];
            s1[2] += bf_lo(h[j + 1].y) * wv[j + 1]; s1[3] += bf_hi(h[j + 1].y) * wv[j + 1];
            s1[4] += bf_lo(h[j + 1].z) * wv[j + 1]; s1[5] += bf_hi(h[j + 1].z) * wv[j + 1];
            s1[6] += bf_lo(h[j + 1].w) * wv[j + 1]; s1[7] += bf_hi(h[j + 1].w) * wv[j + 1];
        }
        for (int p = rs + 8; p < re; p += 4) {
            uint4 ht[4];
            float wt[4];
#pragma unroll
            for (int j = 0; j < 4; ++j) {
                int q = (p + j < re) ? p + j : p;
                int2 e = adjw[q];
                ht[j] = *(const uint4*)(H + (size_t)e.x * F + l * 8);
                wt[j] = (p + j < re) ? __int_as_float(e.y) : 0.0f;
            }
#pragma unroll
            for (int j = 0; j < 4; ++j) {
                s0[0] += bf_lo(ht[j].x) * wt[j]; s0[1] += bf_hi(ht[j].x) * wt[j];
                s0[2] += bf_lo(ht[j].y) * wt[j]; s0[3] += bf_hi(ht[j].y) * wt[j];
                s0[4] += bf_lo(ht[j].z) * wt[j]; s0[5] += bf_hi(ht[j].z) * wt[j];
                s0[6] += bf_lo(ht[j].w) * wt[j]; s0[7] += bf_hi(ht[j].w) * wt[j];
            }
        }
        uint4 hv = *(const uint4*)(H + (size_t)node * F + l * 8);
        float4 bv0 = *(const float4*)(bias + l * 8);
        float4 bv1 = *(const float4*)(bias + l * 8 + 4);
        float d2 = dn * dn;
        float hs[8] = {bf_lo(hv.x), bf_hi(hv.x), bf_lo(hv.y), bf_hi(hv.y),
                       bf_lo(hv.z), bf_hi(hv.z), bf_lo(hv.w), bf_hi(hv.w)};
        float bb[8] = {bv0.x, bv0.y, bv0.z, bv0.w, bv1.x, bv1.y, bv1.z, bv1.w};
        float v[8];
#pragma unroll
        for (int j = 0; j < 8; ++j) {
            v[j] = s0[j] + s1[j] + hs[j] * d2 + bb[j];
            if (RELU) v[j] = fmaxf(v[j], 0.0f);
        }
        *(uint4*)(Z + (size_t)node * F + l * 8) =
            uint4{pack2bf(v[0], v[1]), pack2bf(v[2], v[3]), pack2bf(v[4], v[5]),
                  pack2bf(v[6], v[7])};
    } else {  // F == 64
        uint2 h[8];
        float wv[8];
#pragma unroll
        for (int j = 0; j < 8; ++j) {
            int p = (rs + j < re) ? rs + j : pc;
            int2 e = adjw[p];
            h[j] = *(const uint2*)(H + (size_t)e.x * F + l * 4);
            wv[j] = (j < deg) ? __int_as_float(e.y) : 0.0f;
        }
        float s0[4] = {}, s1[4] = {};
#pragma unroll
        for (int j = 0; j < 8; j += 2) {
            s0[0] += bf_lo(h[j].x) * wv[j]; s0[1] += bf_hi(h[j].x) * wv[j];
            s0[2] += bf_lo(h[j].y) * wv[j]; s0[3] += bf_hi(h[j].y) * wv[j];
            s1[0] += bf_lo(h[j + 1].x) * wv[j + 1]; s1[1] += bf_hi(h[j + 1].x) * wv[j + 1];
            s1[2] += bf_lo(h[j + 1].y) * wv[j + 1]; s1[3] += bf_hi(h[j + 1].y) * wv[j + 1];
        }
        for (int p = rs + 8; p < re; p += 4) {
            uint2 ht[4];
            float wt[4];
#pragma unroll
            for (int j = 0; j < 4; ++j) {
                int q = (p + j < re) ? p + j : p;
                int2 e = adjw[q];
                ht[j] = *(const uint2*)(H + (size_t)e.x * F + l * 4);
                wt[j] = (p + j < re) ? __int_as_float(e.y) : 0.0f;
            }
#pragma unroll
            for (int j = 0; j < 4; ++j) {
                s0[0] += bf_lo(ht[j].x) * wt[j]; s0[1] += bf_hi(ht[j].x) * wt[j];
                s0[2] += bf_lo(ht[j].y) * wt[j]; s0[3] += bf_hi(ht[j].y) * wt[j];
            }
        }
        uint2 hv = *(const uint2*)(H + (size_t)node * F + l * 4);
        float4 bv = *(const float4*)(bias + l * 4);
        float d2 = dn * dn;
        float hs[4] = {bf_lo(hv.x), bf_hi(hv.x), bf_lo(hv.y), bf_hi(hv.y)};
        float bb[4] = {bv.x, bv.y, bv.z, bv.w};
        float v[4];
#pragma unroll
        for (int j = 0; j < 4; ++j) {
            v[j] = s0[j] + s1[j] + hs[j] * d2 + bb[j];
            if (RELU) v[j] = fmaxf(v[j], 0.0f);
        }
        *(uint2*)(Z + (size_t)node * F + l * 4) = uint2{pack2bf(v[0], v[1]), pack2bf(v[2], v[3])};
    }
}

// ===== decode via MFMA: 32 edges per wave (two 16-edge groups) =====
__global__ void decode_mfma(const int* __restrict__ pos, const int* __restrict__ neg,
                            const short* __restrict__ Z, float* __restrict__ out) {
    int wid = threadIdx.x >> 6;
    int lane = threadIdx.x & 63;
    int l15 = lane & 15;
    int quad = lane >> 4;
    int e0 = (blockIdx.x * 4 + wid) * 32;
    if (e0 >= N_POS + N_NEG) return;
    const int* bp = (e0 < N_POS) ? pos : (neg - N_POS);
    int eA = e0 + l15;
    int eB = e0 + 16 + l15;
    int aA = bp[eA], bA = bp[600000 + eA];
    int aB = bp[eB], bB = bp[600000 + eB];

    const short* zaA = Z + (size_t)aA * OUT_CH + quad * 8;
    const short* zbA = Z + (size_t)bA * OUT_CH + quad * 8;
    const short* zaB = Z + (size_t)aB * OUT_CH + quad * 8;
    const short* zbB = Z + (size_t)bB * OUT_CH + quad * 8;
    bf16x8 a0A = *(const bf16x8*)(zaA);
    bf16x8 a1A = *(const bf16x8*)(zaA + 32);
    bf16x8 b0A = *(const bf16x8*)(zbA);
    bf16x8 b1A = *(const bf16x8*)(zbA + 32);
    bf16x8 a0B = *(const bf16x8*)(zaB);
    bf16x8 a1B = *(const bf16x8*)(zaB + 32);
    bf16x8 b0B = *(const bf16x8*)(zbB);
    bf16x8 b1B = *(const bf16x8*)(zbB + 32);

    f32x4 accA = {}, accB = {};
    accA = __builtin_amdgcn_mfma_f32_16x16x32_bf16(a0A, b0A, accA, 0, 0, 0);
    accB = __builtin_amdgcn_mfma_f32_16x16x32_bf16(a0B, b0B, accB, 0, 0, 0);
    accA = __builtin_amdgcn_mfma_f32_16x16x32_bf16(a1A, b1A, accA, 0, 0, 0);
    accB = __builtin_amdgcn_mfma_f32_16x16x32_bf16(a1B, b1B, accB, 0, 0, 0);

    if (quad == (l15 >> 2)) {
        out[eA] = accA[l15 & 3];
        out[eB] = accB[l15 & 3];
    }
}

extern "C" void kernel_launch(void* const* d_in, const int* in_sizes, int n_in,
                              void* d_out, int out_size, void* d_ws, size_t ws_size,
                              hipStream_t stream) {
    const float* x = (const float*)d_in[0];
    const int* pos = (const int*)d_in[1];  // row0 = src, row1 = dst
    const int* neg = (const int*)d_in[2];
    const float* W1 = (const float*)d_in[3];
    const float* b1 = (const float*)d_in[4];
    const float* W2 = (const float*)d_in[5];
    const float* b2 = (const float*)d_in[6];
    float* out = (float*)d_out;

    // workspace layout (bf16 intermediates)
    ushort16* A = (ushort16*)d_ws;                      // H [N,128]; later z2 [N,64]
    ushort16* B = A + (size_t)N_NODES * 128;            // h2 [N,64]
    float* dinv = (float*)(B + (size_t)N_NODES * 128);  // [N]
    int* hist = (int*)(dinv + N_NODES);                 // [N]
    int* rowstart = hist + N_NODES;                     // [N+1]
    int2* adjw = (int2*)(rowstart + N_NODES + 1);       // [N_POS] (adj, wgt) pairs
    int* partials = (int*)(adjw + N_POS);               // [128]
    ushort16* W1t = (ushort16*)(partials + 128);        // [128*128]
    ushort16* W2t = W1t + 128 * 128;                    // [64*128]
    // rank[N_POS] overlays B: rank is dead before agg1_gemm2 writes h2 into B.
    int* rank = (int*)B;

    const int* pos_src = pos;
    const int* pos_dst = pos + N_POS;

    constexpr int NB_SCAN = (N_NODES + 1023) / 1024;  // 98

    // ---- init: zero hist + weight convert (one kernel, replaces memset) ----
    init_wt<<<NB_ZERO + 96, 256, 0, stream>>>(hist, W1, W2, W1t, W2t);

    // ---- hist+rank (atomics) || layer-1 GEMM (MFMA), role-interleaved ----
    hist_gemm<<<NB_HG, 256, 0, stream>>>(pos_dst, hist, rank, x, W1t, A, N_NODES);

    // ---- scan ----
    scan_reduce<<<NB_SCAN, 256, 0, stream>>>(hist, partials, N_NODES);
    scan_final<<<NB_SCAN, 256, 0, stream>>>(hist, partials, rowstart, dinv, N_NODES);

    // ---- csr_fill standalone (no LDS, 8 blocks/CU) ----
    csr_fill<<<NB_FILL, 256, 0, stream>>>(pos_src, pos_dst, dinv, rowstart, rank, adjw);

    // ---- fused layer-1 aggregation (batched tail) + layer-2 GEMM, 32 nodes/blk ----
    agg1_gemm2<<<(N_NODES + TN2 - 1) / TN2, 256, 0, stream>>>(rowstart, adjw, dinv, A, b1, W2t,
                                                              B, N_NODES);

    // ---- layer-2 aggregation: reads h2(=B), writes z2(=A) ----
    agg_pull<OUT_CH, false><<<(N_NODES + 15) / 16, 256, 0, stream>>>(rowstart, adjw, dinv, B, b2,
                                                                     A, N_NODES);

    // ---- decode (32 edges/wave, 128/block) ----
    decode_mfma<<<(N_POS + N_NEG) / 128, 256, 0, stream>>>(pos, neg, (const short*)A, out);
}

// Round 12
// 243.421 us; speedup vs baseline: 1.0700x; 1.0168x over previous
//
#include <hip/hip_runtime.h>

#define N_NODES 100000
#define IN_CH 128
#define HIDDEN 128
#define OUT_CH 64
#define N_POS 600000
#define N_NEG 600000

typedef unsigned int uint32;
typedef unsigned short ushort16;
typedef __attribute__((ext_vector_type(8))) short bf16x8;
typedef __attribute__((ext_vector_type(4))) float f32x4;

// ---- bf16 helpers ----
__device__ inline float bf_lo(uint32 u) {
    union { uint32 i; float f; } v;
    v.i = u << 16;
    return v.f;
}
__device__ inline float bf_hi(uint32 u) {
    union { uint32 i; float f; } v;
    v.i = u & 0xffff0000u;
    return v.f;
}
__device__ inline ushort16 f2bf(float f) {
    union { uint32 i; float f; } v;
    v.f = f;
    uint32 r = v.i + 0x7fffu + ((v.i >> 16) & 1u);  // round-to-nearest-even
    return (ushort16)(r >> 16);
}
__device__ inline uint32 pack2bf(float a, float b) {
    return (uint32)f2bf(a) | ((uint32)f2bf(b) << 16);
}

#define NB_HIST ((N_POS + 255) / 256)   // 2344 -- 1 edge/thread (measured best, r0 vs r1/r2)
#define NB_FILL ((N_POS + 255) / 256)   // 2344
#define NB_GEMM1 ((N_NODES + 63) / 64)  // 1563
#define NB_ZERO ((N_NODES + 255) / 256) // 391
// hist||gemm interleave 3:2 (verified -6.5us, r11). Both roles share the
// kernel's static LDS reservation -> shrinking gemm LDS lifts BOTH roles'
// blocks/CU (this round: 27.6KB -> 15KB, 5 -> 7 blocks/CU).
#define NB_HG_GROUPS ((NB_HIST + 2) / 3)  // 782
#define NB_HG (NB_HG_GROUPS * 5)          // 3910

// ===== init: zero hist + weight transpose/convert (replaces memset) =====
__global__ void init_wt(int* __restrict__ hist,
                        const float* __restrict__ W1, const float* __restrict__ W2,
                        ushort16* __restrict__ W1t, ushort16* __restrict__ W2t) {
    if (blockIdx.x < NB_ZERO) {
        int i = blockIdx.x * 256 + threadIdx.x;
        if (i < N_NODES) hist[i] = 0;
    } else {
        int i = (blockIdx.x - NB_ZERO) * 256 + threadIdx.x;
        if (i < 128 * 128) {
            int n = i >> 7, k = i & 127;
            W1t[i] = f2bf(W1[k * 128 + n]);
        } else {
            int j = i - 128 * 128;
            if (j < 64 * 128) {
                int n = j >> 7, k = j & 127;
                W2t[j] = f2bf(W2[k * 64 + n]);
            }
        }
    }
}

// ===== shared GEMM tile body: H_bf16[node0..node0+64, M] = X @ W =====
// K-QUARTER staging (KH=32): LDS (64+128)x40 shorts x2B = 15KB (was 27.6KB
// at KH=64) so the co-scheduled hist blocks in hist_gemm get 7 blocks/CU
// instead of 5. W still staged through LDS (broadcast reuse — direct-global
// was a measured regression r5/r6). XS=40 shorts = 80B: 16B-aligned for
// b128 LDS ops; 2-way bank alias (free, m136).
template <int M, bool XBF>
__device__ __forceinline__ void gemm_tile(const void* __restrict__ Xv,
                                          const ushort16* __restrict__ Wt,
                                          ushort16* __restrict__ H, int n, int tileIdx) {
    constexpr int K = 128;
    constexpr int TN = 64;
    constexpr int KH = 32;  // K quarter
    constexpr int XS = 40;  // padded quarter-row stride (shorts)
    __shared__ short Xs[TN * XS];
    __shared__ short Ws[M * XS];
    int tid = threadIdx.x;
    int node0 = tileIdx * TN;

    constexpr int CT = M / 16;
    int w = tid >> 6;
    int lane = tid & 63;
    int l15 = lane & 15;
    int quad = lane >> 4;
    f32x4 acc[CT] = {};

#pragma unroll
    for (int h = 0; h < 4; ++h) {
        if (h) __syncthreads();  // all waves done reading previous quarter
        // stage W quarter: M rows x 32 shorts (4 x 16B chunks per row)
        for (int q = tid; q < M * 4; q += 256) {
            int row = q >> 2, c = q & 3;
            uint4 v = *(const uint4*)((const short*)Wt + row * K + h * KH + c * 8);
            *(uint4*)(Ws + row * XS + c * 8) = v;
        }
        // stage X quarter
        if (!XBF) {
            const float* X = (const float*)Xv;
            int row = tid >> 2, part = tid & 3;  // 4 threads/row, 8 floats each
            int gn = node0 + row;
            int kl = part * 8;
            float4 v0 = (gn < n) ? *(const float4*)(X + (size_t)gn * K + h * KH + kl)
                                 : float4{0, 0, 0, 0};
            float4 v1 = (gn < n) ? *(const float4*)(X + (size_t)gn * K + h * KH + kl + 4)
                                 : float4{0, 0, 0, 0};
            uint4 p = {pack2bf(v0.x, v0.y), pack2bf(v0.z, v0.w),
                       pack2bf(v1.x, v1.y), pack2bf(v1.z, v1.w)};
            *(uint4*)(Xs + row * XS + kl) = p;
        } else {
            const short* X = (const short*)Xv;
            for (int q = tid; q < TN * 4; q += 256) {
                int row = q >> 2, c = q & 3;
                int gn = node0 + row;
                uint4 v = (gn < n) ? *(const uint4*)(X + (size_t)gn * K + h * KH + c * 8)
                                   : uint4{0, 0, 0, 0};
                *(uint4*)(Xs + row * XS + c * 8) = v;
            }
        }
        __syncthreads();

        // one bf16x8 per lane covers the full K=32 quarter (quad*8)
        bf16x8 a = *(const bf16x8*)(Xs + (w * 16 + l15) * XS + quad * 8);
#pragma unroll
        for (int ct = 0; ct < CT; ++ct) {
            bf16x8 b = *(const bf16x8*)(Ws + (ct * 16 + l15) * XS + quad * 8);
            acc[ct] = __builtin_amdgcn_mfma_f32_16x16x32_bf16(a, b, acc[ct], 0, 0, 0);
        }
    }

#pragma unroll
    for (int ct = 0; ct < CT; ++ct) {
#pragma unroll
        for (int r = 0; r < 4; ++r) {
            int gn = node0 + w * 16 + quad * 4 + r;
            if (gn < n) H[(size_t)gn * M + ct * 16 + l15] = f2bf(acc[ct][r]);
        }
    }
}

// ===== hist_count (+rank persist) || layer-1 GEMM, role-INTERLEAVED =====
__global__ __launch_bounds__(256) void hist_gemm(
    const int* __restrict__ dst, int* __restrict__ hist, int* __restrict__ rank,
    const float* __restrict__ x, const ushort16* __restrict__ W1t,
    ushort16* __restrict__ H, int n) {
    int bid = blockIdx.x;
    int g = bid / 5, r = bid % 5;
    if (r < 3) {
        int hb = g * 3 + r;
        if (hb >= NB_HIST) return;
        int i = hb * 256 + threadIdx.x;
        if (i < N_POS) rank[i] = atomicAdd(&hist[dst[i]], 1);
    } else {
        int gb = g * 2 + (r - 3);
        if (gb >= NB_GEMM1) return;
        gemm_tile<HIDDEN, false>(x, W1t, H, n, gb);
    }
}

__global__ void scan_reduce(const int* __restrict__ hist, int* __restrict__ partials, int n) {
    __shared__ int sdata[256];
    int b = blockIdx.x, t = threadIdx.x;
    int base = b * 1024;
    int s = 0;
    for (int i = t; i < 1024; i += 256) {
        int idx = base + i;
        s += (idx < n) ? hist[idx] : 0;
    }
    sdata[t] = s;
    __syncthreads();
    for (int off = 128; off > 0; off >>= 1) {
        if (t < off) sdata[t] += sdata[t + off];
        __syncthreads();
    }
    if (t == 0) partials[b] = sdata[0];
}

// scan_final computes its own partials-prefix (first wave). NB_SCAN = 98 <= 128.
__global__ void scan_final(const int* __restrict__ hist, const int* __restrict__ partials,
                           int* __restrict__ rowstart, float* __restrict__ dinv, int n) {
    __shared__ int tsum[256];
    __shared__ int base_sh;
    int t = threadIdx.x, b = blockIdx.x;
    if (t < 64) {
        int s0 = (t < b) ? partials[t] : 0;
        int i2 = t + 64;
        int s1 = (i2 < b && i2 < 98) ? partials[i2] : 0;
        int s = s0 + s1;
#pragma unroll
        for (int off = 32; off > 0; off >>= 1) s += __shfl_down(s, off, 64);
        if (t == 0) base_sh = s;
    }
    int base = b * 1024 + t * 4;
    int v[4];
    int s = 0;
#pragma unroll
    for (int j = 0; j < 4; j++) {
        int i = base + j;
        v[j] = (i < n) ? hist[i] : 0;
        s += v[j];
    }
    tsum[t] = s;
    __syncthreads();
    for (int off = 1; off < 256; off <<= 1) {
        int a = (t >= off) ? tsum[t - off] : 0;
        __syncthreads();
        tsum[t] += a;
        __syncthreads();
    }
    int offset = base_sh + (tsum[t] - s);
#pragma unroll
    for (int j = 0; j < 4; j++) {
        int i = base + j;
        if (i < n) {
            rowstart[i] = offset;
            dinv[i] = rsqrtf((float)v[j] + 1.0f);
            offset += v[j];
        }
    }
    if (b == 0 && t == 0) rowstart[n] = N_POS;
}

// ===== csr_fill standalone: atomic-free, NO LDS -> 8 blocks/CU =====
__global__ __launch_bounds__(256) void csr_fill(
    const int* __restrict__ src, const int* __restrict__ dst, const float* __restrict__ dinv,
    const int* __restrict__ rowstart, const int* __restrict__ rank,
    int2* __restrict__ adjw) {
    int e = blockIdx.x * 256 + threadIdx.x;
    if (e < N_POS) {
        int s = src[e], d = dst[e];
        int p = rowstart[d] + rank[e];
        adjw[p] = int2{s, __float_as_int(dinv[s] * dinv[d])};
    }
}

// ===== layer-1 aggregation body for one node (F=128, +bias+relu), 16 lanes =====
// 8-edge predicated prologue + batched tail (4 gathers in flight; -6us, r8).
__device__ __forceinline__ uint4 agg_node128(int node, int l, const int* __restrict__ rowstart,
                                             const int2* __restrict__ adjw,
                                             const float* __restrict__ dinv,
                                             const ushort16* __restrict__ H,
                                             const float* __restrict__ bias) {
    float dn = dinv[node];
    int rs = rowstart[node], re = rowstart[node + 1];
    int deg = re - rs;
    int pc = (deg > 0) ? rs : (rs > 0 ? rs - 1 : 0);  // safe clamp index
    uint4 h[8];
    float wv[8];
#pragma unroll
    for (int j = 0; j < 8; ++j) {
        int p = (rs + j < re) ? rs + j : pc;
        int2 e = adjw[p];
        h[j] = *(const uint4*)(H + (size_t)e.x * 128 + l * 8);
        wv[j] = (j < deg) ? __int_as_float(e.y) : 0.0f;
    }
    float s0[8] = {}, s1[8] = {};
#pragma unroll
    for (int j = 0; j < 8; j += 2) {
        s0[0] += bf_lo(h[j].x) * wv[j]; s0[1] += bf_hi(h[j].x) * wv[j];
        s0[2] += bf_lo(h[j].y) * wv[j]; s0[3] += bf_hi(h[j].y) * wv[j];
        s0[4] += bf_lo(h[j].z) * wv[j]; s0[5] += bf_hi(h[j].z) * wv[j];
        s0[6] += bf_lo(h[j].w) * wv[j]; s0[7] += bf_hi(h[j].w) * wv[j];
        s1[0] += bf_lo(h[j + 1].x) * wv[j + 1]; s1[1] += bf_hi(h[j + 1].x) * wv[j + 1];
        s1[2] += bf_lo(h[j + 1].y) * wv[j + 1]; s1[3] += bf_hi(h[j + 1].y) * wv[j + 1];
        s1[4] += bf_lo(h[j + 1].z) * wv[j + 1]; s1[5] += bf_hi(h[j + 1].z) * wv[j + 1];
        s1[6] += bf_lo(h[j + 1].w) * wv[j + 1]; s1[7] += bf_hi(h[j + 1].w) * wv[j + 1];
    }
    // batched tail: 4 predicated gathers in flight per iteration
    for (int p = rs + 8; p < re; p += 4) {
        uint4 ht[4];
        float wt[4];
#pragma unroll
        for (int j = 0; j < 4; ++j) {
            int q = (p + j < re) ? p + j : p;  // p itself is always < re here
            int2 e = adjw[q];
            ht[j] = *(const uint4*)(H + (size_t)e.x * 128 + l * 8);
            wt[j] = (p + j < re) ? __int_as_float(e.y) : 0.0f;
        }
#pragma unroll
        for (int j = 0; j < 4; j += 2) {
            s0[0] += bf_lo(ht[j].x) * wt[j]; s0[1] += bf_hi(ht[j].x) * wt[j];
            s0[2] += bf_lo(ht[j].y) * wt[j]; s0[3] += bf_hi(ht[j].y) * wt[j];
            s0[4] += bf_lo(ht[j].z) * wt[j]; s0[5] += bf_hi(ht[j].z) * wt[j];
            s0[6] += bf_lo(ht[j].w) * wt[j]; s0[7] += bf_hi(ht[j].w) * wt[j];
            s1[0] += bf_lo(ht[j + 1].x) * wt[j + 1]; s1[1] += bf_hi(ht[j + 1].x) * wt[j + 1];
            s1[2] += bf_lo(ht[j + 1].y) * wt[j + 1]; s1[3] += bf_hi(ht[j + 1].y) * wt[j + 1];
            s1[4] += bf_lo(ht[j + 1].z) * wt[j + 1]; s1[5] += bf_hi(ht[j + 1].z) * wt[j + 1];
            s1[6] += bf_lo(ht[j + 1].w) * wt[j + 1]; s1[7] += bf_hi(ht[j + 1].w) * wt[j + 1];
        }
    }
    uint4 hv = *(const uint4*)(H + (size_t)node * 128 + l * 8);
    float4 bv0 = *(const float4*)(bias + l * 8);
    float4 bv1 = *(const float4*)(bias + l * 8 + 4);
    float d2 = dn * dn;
    float hs[8] = {bf_lo(hv.x), bf_hi(hv.x), bf_lo(hv.y), bf_hi(hv.y),
                   bf_lo(hv.z), bf_hi(hv.z), bf_lo(hv.w), bf_hi(hv.w)};
    float bb[8] = {bv0.x, bv0.y, bv0.z, bv0.w, bv1.x, bv1.y, bv1.z, bv1.w};
    float v[8];
#pragma unroll
    for (int j = 0; j < 8; ++j) {
        v[j] = fmaxf(s0[j] + s1[j] + hs[j] * d2 + bb[j], 0.0f);  // relu (layer 1)
    }
    return uint4{pack2bf(v[0], v[1]), pack2bf(v[2], v[3]), pack2bf(v[4], v[5]),
                 pack2bf(v[6], v[7])};
}

// ===== fused: layer-1 agg -> LDS -> layer-2 GEMM, 32 nodes/block =====
// (r9: TN2=32 neutral vs 64 -> gather-issue/L2-bound, not occupancy-bound.)
#define ZS 136  // padded row stride (shorts); 272B, 16B-aligned
#define TN2 32  // nodes per block
__global__ __launch_bounds__(256, 4) void agg1_gemm2(
    const int* __restrict__ rowstart, const int2* __restrict__ adjw,
    const float* __restrict__ dinv, const ushort16* __restrict__ H,
    const float* __restrict__ b1, const ushort16* __restrict__ W2t,
    ushort16* __restrict__ h2, int n) {
    __shared__ __align__(16) short Zs[TN2 * ZS];
    __shared__ __align__(16) short Ws[64 * ZS];
    int tid = threadIdx.x;
    int node0 = blockIdx.x * TN2;

    // stage W2t [64 out][128 k] -> Ws (independent of agg; overlaps its latency)
    for (int q = tid; q < 64 * 16; q += 256) {
        int row = q >> 4, c = q & 15;
        uint4 v = *(const uint4*)((const short*)W2t + row * 128 + c * 8);
        *(uint4*)(Ws + row * ZS + c * 8) = v;
    }

    // layer-1 aggregation for 32 nodes: 16 groups x 16 lanes, 2 nodes each
    int g = tid >> 4, l = tid & 15;
#pragma unroll 1
    for (int it = 0; it < 2; ++it) {
        int row = g * 2 + it;
        int node = node0 + row;
        uint4 z = (node < n) ? agg_node128(node, l, rowstart, adjw, dinv, H, b1)
                             : uint4{0, 0, 0, 0};
        *(uint4*)(Zs + row * ZS + l * 8) = z;
    }
    __syncthreads();

    // GEMM: h2[32 x 64] = Zs @ W2. 4 waves: wave w -> row-tile (w>>1),
    // col-tiles (w&1)*32 .. +31 (2 tiles). 8 MFMAs/wave.
    int w = tid >> 6, lane = tid & 63, l15 = lane & 15, quad = lane >> 4;
    int wr = w >> 1, wc = w & 1;
    f32x4 acc[2] = {};
    const short* zrow = Zs + (wr * 16 + l15) * ZS + quad * 8;
#pragma unroll
    for (int kk = 0; kk < 4; ++kk) {
        bf16x8 a = *(const bf16x8*)(zrow + kk * 32);
#pragma unroll
        for (int ct = 0; ct < 2; ++ct) {
            bf16x8 b = *(const bf16x8*)(Ws + (wc * 32 + ct * 16 + l15) * ZS + quad * 8 + kk * 32);
            acc[ct] = __builtin_amdgcn_mfma_f32_16x16x32_bf16(a, b, acc[ct], 0, 0, 0);
        }
    }
#pragma unroll
    for (int ct = 0; ct < 2; ++ct) {
#pragma unroll
        for (int r = 0; r < 4; ++r) {
            int gn = node0 + wr * 16 + quad * 4 + r;
            if (gn < n) h2[(size_t)gn * OUT_CH + wc * 32 + ct * 16 + l15] = f2bf(acc[ct][r]);
        }
    }
}

// ========= pull aggregation + self-loop + bias (+relu), bf16 H/Z =========
// FOUR nodes per wave (16 lanes each). 8-edge predicated prologue + BATCHED
// tail (4 gathers in flight).
template <int F, bool RELU>
__global__ void agg_pull(const int* __restrict__ rowstart, const int2* __restrict__ adjw,
                         const float* __restrict__ dinv, const ushort16* __restrict__ H,
                         const float* __restrict__ bias, ushort16* __restrict__ Z, int n) {
    int g = threadIdx.x >> 4;  // 16-lane group
    int l = threadIdx.x & 15;
    int node = blockIdx.x * (blockDim.x >> 4) + g;
    if (node >= n) return;
    float dn = dinv[node];
    int rs = rowstart[node], re = rowstart[node + 1];
    int deg = re - rs;
    int pc = (deg > 0) ? rs : (rs > 0 ? rs - 1 : 0);  // safe clamp index
    if (F == 128) {
        uint4 h[8];
        float wv[8];
#pragma unroll
        for (int j = 0; j < 8; ++j) {
            int p = (rs + j < re) ? rs + j : pc;
            int2 e = adjw[p];
            h[j] = *(const uint4*)(H + (size_t)e.x * F + l * 8);
            wv[j] = (j < deg) ? __int_as_float(e.y) : 0.0f;
        }
        float s0[8] = {}, s1[8] = {};
#pragma unroll
        for (int j = 0; j < 8; j += 2) {
            s0[0] += bf_lo(h[j].x) * wv[j]; s0[1] += bf_hi(h[j].x) * wv[j];
            s0[2] += bf_lo(h[j].y) * wv[j]; s0[3] += bf_hi(h[j].y) * wv[j];
            s0[4] += bf_lo(h[j].z) * wv[j]; s0[5] += bf_hi(h[j].z) * wv[j];
            s0[6] += bf_lo(h[j].w) * wv[j]; s0[7] += bf_hi(h[j].w) * wv[j];
            s1[0] += bf_lo(h[j + 1].x) * wv[j + 1]; s1[1] += bf_hi(h[j + 1].x) * wv[j + 1];
            s1[2] += bf_lo(h[j + 1].y) * wv[j + 1]; s1[3] += bf_hi(h[j + 1].y) * wv[j + 1];
            s1[4] += bf_lo(h[j + 1].z) * wv[j + 1]; s1[5] += bf_hi(h[j + 1].z) * wv[j + 1];
            s1[6] += bf_lo(h[j + 1].w) * wv[j + 1]; s1[7] += bf_hi(h[j + 1].w) * wv[j + 1];
        }
        for (int p = rs + 8; p < re; p += 4) {
            uint4 ht[4];
            float wt[4];
#pragma unroll
            for (int j = 0; j < 4; ++j) {
                int q = (p + j < re) ? p + j : p;
                int2 e = adjw[q];
                ht[j] = *(const uint4*)(H + (size_t)e.x * F + l * 8);
                wt[j] = (p + j < re) ? __int_as_float(e.y) : 0.0f;
            }
#pragma unroll
            for (int j = 0; j < 4; ++j) {
                s0[0] += bf_lo(ht[j].x) * wt[j]; s0[1] += bf_hi(ht[j].x) * wt[j];
                s0[2] += bf_lo(ht[j].y) * wt[j]; s0[3] += bf_hi(ht[j].y) * wt[j];
                s0[4] += bf_lo(ht[j].z) * wt[j]; s0[5] += bf_hi(ht[j].z) * wt[j];
                s0[6] += bf_lo(ht[j].w) * wt[j]; s0[7] += bf_hi(ht[j].w) * wt[j];
            }
        }
        uint4 hv = *(const uint4*)(H + (size_t)node * F + l * 8);
        float4 bv0 = *(const float4*)(bias + l * 8);
        float4 bv1 = *(const float4*)(bias + l * 8 + 4);
        float d2 = dn * dn;
        float hs[8] = {bf_lo(hv.x), bf_hi(hv.x), bf_lo(hv.y), bf_hi(hv.y),
                       bf_lo(hv.z), bf_hi(hv.z), bf_lo(hv.w), bf_hi(hv.w)};
        float bb[8] = {bv0.x, bv0.y, bv0.z, bv0.w, bv1.x, bv1.y, bv1.z, bv1.w};
        float v[8];
#pragma unroll
        for (int j = 0; j < 8; ++j) {
            v[j] = s0[j] + s1[j] + hs[j] * d2 + bb[j];
            if (RELU) v[j] = fmaxf(v[j], 0.0f);
        }
        *(uint4*)(Z + (size_t)node * F + l * 8) =
            uint4{pack2bf(v[0], v[1]), pack2bf(v[2], v[3]), pack2bf(v[4], v[5]),
                  pack2bf(v[6], v[7])};
    } else {  // F == 64
        uint2 h[8];
        float wv[8];
#pragma unroll
        for (int j = 0; j < 8; ++j) {
            int p = (rs + j < re) ? rs + j : pc;
            int2 e = adjw[p];
            h[j] = *(const uint2*)(H + (size_t)e.x * F + l * 4);
            wv[j] = (j < deg) ? __int_as_float(e.y) : 0.0f;
        }
        float s0[4] = {}, s1[4] = {};
#pragma unroll
        for (int j = 0; j < 8; j += 2) {
            s0[0] += bf_lo(h[j].x) * wv[j]; s0[1] += bf_hi(h[j].x) * wv[j];
            s0[2] += bf_lo(h[j].y) * wv[j]; s0[3] += bf_hi(h[j].y) * wv[j];
            s1[0] += bf_lo(h[j + 1].x) * wv[j + 1]; s1[1] += bf_hi(h[j + 1].x) * wv[j + 1];
            s1[2] += bf_lo(h[j + 1].y) * wv[j + 1]; s1[3] += bf_hi(h[j + 1].y) * wv[j + 1];
        }
        for (int p = rs + 8; p < re; p += 4) {
            uint2 ht[4];
            float wt[4];
#pragma unroll
            for (int j = 0; j < 4; ++j) {
                int q = (p + j < re) ? p + j : p;
                int2 e = adjw[q];
                ht[j] = *(const uint2*)(H + (size_t)e.x * F + l * 4);
                wt[j] = (p + j < re) ? __int_as_float(e.y) : 0.0f;
            }
#pragma unroll
            for (int j = 0; j < 4; ++j) {
                s0[0] += bf_lo(ht[j].x) * wt[j]; s0[1] += bf_hi(ht[j].x) * wt[j];
                s0[2] += bf_lo(ht[j].y) * wt[j]; s0[3] += bf_hi(ht[j].y) * wt[j];
            }
        }
        uint2 hv = *(const uint2*)(H + (size_t)node * F + l * 4);
        float4 bv = *(const float4*)(bias + l * 4);
        float d2 = dn * dn;
        float hs[4] = {bf_lo(hv.x), bf_hi(hv.x), bf_lo(hv.y), bf_hi(hv.y)};
        float bb[4] = {bv.x, bv.y, bv.z, bv.w};
        float v[4];
#pragma unroll
        for (int j = 0; j < 4; ++j) {
            v[j] = s0[j] + s1[j] + hs[j] * d2 + bb[j];
            if (RELU) v[j] = fmaxf(v[j], 0.0f);
        }
        *(uint2*)(Z + (size_t)node * F + l * 4) = uint2{pack2bf(v[0], v[1]), pack2bf(v[2], v[3])};
    }
}

// ===== decode via MFMA: 32 edges per wave (two 16-edge groups) =====
__global__ void decode_mfma(const int* __restrict__ pos, const int* __restrict__ neg,
                            const short* __restrict__ Z, float* __restrict__ out) {
    int wid = threadIdx.x >> 6;
    int lane = threadIdx.x & 63;
    int l15 = lane & 15;
    int quad = lane >> 4;
    int e0 = (blockIdx.x * 4 + wid) * 32;
    if (e0 >= N_POS + N_NEG) return;
    const int* bp = (e0 < N_POS) ? pos : (neg - N_POS);
    int eA = e0 + l15;
    int eB = e0 + 16 + l15;
    int aA = bp[eA], bA = bp[600000 + eA];
    int aB = bp[eB], bB = bp[600000 + eB];

    const short* zaA = Z + (size_t)aA * OUT_CH + quad * 8;
    const short* zbA = Z + (size_t)bA * OUT_CH + quad * 8;
    const short* zaB = Z + (size_t)aB * OUT_CH + quad * 8;
    const short* zbB = Z + (size_t)bB * OUT_CH + quad * 8;
    bf16x8 a0A = *(const bf16x8*)(zaA);
    bf16x8 a1A = *(const bf16x8*)(zaA + 32);
    bf16x8 b0A = *(const bf16x8*)(zbA);
    bf16x8 b1A = *(const bf16x8*)(zbA + 32);
    bf16x8 a0B = *(const bf16x8*)(zaB);
    bf16x8 a1B = *(const bf16x8*)(zaB + 32);
    bf16x8 b0B = *(const bf16x8*)(zbB);
    bf16x8 b1B = *(const bf16x8*)(zbB + 32);

    f32x4 accA = {}, accB = {};
    accA = __builtin_amdgcn_mfma_f32_16x16x32_bf16(a0A, b0A, accA, 0, 0, 0);
    accB = __builtin_amdgcn_mfma_f32_16x16x32_bf16(a0B, b0B, accB, 0, 0, 0);
    accA = __builtin_amdgcn_mfma_f32_16x16x32_bf16(a1A, b1A, accA, 0, 0, 0);
    accB = __builtin_amdgcn_mfma_f32_16x16x32_bf16(a1B, b1B, accB, 0, 0, 0);

    if (quad == (l15 >> 2)) {
        out[eA] = accA[l15 & 3];
        out[eB] = accB[l15 & 3];
    }
}

extern "C" void kernel_launch(void* const* d_in, const int* in_sizes, int n_in,
                              void* d_out, int out_size, void* d_ws, size_t ws_size,
                              hipStream_t stream) {
    const float* x = (const float*)d_in[0];
    const int* pos = (const int*)d_in[1];  // row0 = src, row1 = dst
    const int* neg = (const int*)d_in[2];
    const float* W1 = (const float*)d_in[3];
    const float* b1 = (const float*)d_in[4];
    const float* W2 = (const float*)d_in[5];
    const float* b2 = (const float*)d_in[6];
    float* out = (float*)d_out;

    // workspace layout (bf16 intermediates)
    ushort16* A = (ushort16*)d_ws;                      // H [N,128]; later z2 [N,64]
    ushort16* B = A + (size_t)N_NODES * 128;            // h2 [N,64]
    float* dinv = (float*)(B + (size_t)N_NODES * 128);  // [N]
    int* hist = (int*)(dinv + N_NODES);                 // [N]
    int* rowstart = hist + N_NODES;                     // [N+1]
    int2* adjw = (int2*)(rowstart + N_NODES + 1);       // [N_POS] (adj, wgt) pairs
    int* partials = (int*)(adjw + N_POS);               // [128]
    ushort16* W1t = (ushort16*)(partials + 128);        // [128*128]
    ushort16* W2t = W1t + 128 * 128;                    // [64*128]
    // rank[N_POS] overlays B: rank is dead before agg1_gemm2 writes h2 into B.
    int* rank = (int*)B;

    const int* pos_src = pos;
    const int* pos_dst = pos + N_POS;

    constexpr int NB_SCAN = (N_NODES + 1023) / 1024;  // 98

    // ---- init: zero hist + weight convert (one kernel, replaces memset) ----
    init_wt<<<NB_ZERO + 96, 256, 0, stream>>>(hist, W1, W2, W1t, W2t);

    // ---- hist+rank (atomics) || layer-1 GEMM (MFMA), role-interleaved ----
    hist_gemm<<<NB_HG, 256, 0, stream>>>(pos_dst, hist, rank, x, W1t, A, N_NODES);

    // ---- scan ----
    scan_reduce<<<NB_SCAN, 256, 0, stream>>>(hist, partials, N_NODES);
    scan_final<<<NB_SCAN, 256, 0, stream>>>(hist, partials, rowstart, dinv, N_NODES);

    // ---- csr_fill standalone (no LDS, 8 blocks/CU) ----
    csr_fill<<<NB_FILL, 256, 0, stream>>>(pos_src, pos_dst, dinv, rowstart, rank, adjw);

    // ---- fused layer-1 aggregation (batched tail) + layer-2 GEMM, 32 nodes/blk ----
    agg1_gemm2<<<(N_NODES + TN2 - 1) / TN2, 256, 0, stream>>>(rowstart, adjw, dinv, A, b1, W2t,
                                                              B, N_NODES);

    // ---- layer-2 aggregation: reads h2(=B), writes z2(=A) ----
    agg_pull<OUT_CH, false><<<(N_NODES + 15) / 16, 256, 0, stream>>>(rowstart, adjw, dinv, B, b2,
                                                                     A, N_NODES);

    // ---- decode (32 edges/wave, 128/block) ----
    decode_mfma<<<(N_POS + N_NEG) / 128, 256, 0, stream>>>(pos, neg, (const short*)A, out);
}

// Round 13
// 243.060 us; speedup vs baseline: 1.0715x; 1.0015x over previous
//
#include <hip/hip_runtime.h>

#define N_NODES 100000
#define IN_CH 128
#define HIDDEN 128
#define OUT_CH 64
#define N_POS 600000
#define N_NEG 600000

typedef unsigned int uint32;
typedef unsigned short ushort16;
typedef __attribute__((ext_vector_type(8))) short bf16x8;
typedef __attribute__((ext_vector_type(4))) float f32x4;

// ---- bf16 helpers ----
__device__ inline float bf_lo(uint32 u) {
    union { uint32 i; float f; } v;
    v.i = u << 16;
    return v.f;
}
__device__ inline float bf_hi(uint32 u) {
    union { uint32 i; float f; } v;
    v.i = u & 0xffff0000u;
    return v.f;
}
__device__ inline ushort16 f2bf(float f) {
    union { uint32 i; float f; } v;
    v.f = f;
    uint32 r = v.i + 0x7fffu + ((v.i >> 16) & 1u);  // round-to-nearest-even
    return (ushort16)(r >> 16);
}
__device__ inline uint32 pack2bf(float a, float b) {
    return (uint32)f2bf(a) | ((uint32)f2bf(b) << 16);
}

#define NB_HIST ((N_POS + 255) / 256)   // 2344 -- 1 edge/thread (measured best, r0 vs r1/r2)
#define NB_FILL ((N_POS + 255) / 256)   // 2344
#define NB_GEMM1 ((N_NODES + 63) / 64)  // 1563
#define NB_ZERO ((N_NODES + 255) / 256) // 391
// hist||gemm interleave 3:2 (verified -6.5us r11; +occupancy via 15KB LDS -3us r12).
#define NB_HG_GROUPS ((NB_HIST + 2) / 3)  // 782
#define NB_HG (NB_HG_GROUPS * 5)          // 3910

// ===== init: zero hist + weight transpose/convert (replaces memset) =====
__global__ void init_wt(int* __restrict__ hist,
                        const float* __restrict__ W1, const float* __restrict__ W2,
                        ushort16* __restrict__ W1t, ushort16* __restrict__ W2t) {
    if (blockIdx.x < NB_ZERO) {
        int i = blockIdx.x * 256 + threadIdx.x;
        if (i < N_NODES) hist[i] = 0;
    } else {
        int i = (blockIdx.x - NB_ZERO) * 256 + threadIdx.x;
        if (i < 128 * 128) {
            int n = i >> 7, k = i & 127;
            W1t[i] = f2bf(W1[k * 128 + n]);
        } else {
            int j = i - 128 * 128;
            if (j < 64 * 128) {
                int n = j >> 7, k = j & 127;
                W2t[j] = f2bf(W2[k * 64 + n]);
            }
        }
    }
}

// ===== GEMM tile body: H_bf16[node0..node0+64, 128] = X @ W1 =====
// K-quarter staging (KH=32, LDS pool 15KB -> 7 blocks/CU in hist_gemm, r12).
// COALESCED EPILOGUE (new): acc is staged into the freed LDS pool in two
// 32-row passes, then written as 16B uint4 full-line stores — replaces the
// old 32x 2B scattered stores/lane (WRITE_SIZE showed ~18MB partial-line
// amplification, r12).
__device__ __forceinline__ void gemm_tile(const float* __restrict__ X,
                                          const ushort16* __restrict__ Wt,
                                          ushort16* __restrict__ H, int n, int tileIdx) {
    constexpr int K = 128;
    constexpr int TN = 64;
    constexpr int KH = 32;  // K quarter
    constexpr int XS = 40;  // padded quarter-row stride (shorts)
    __shared__ __align__(16) short pool[(TN + 128) * XS];  // 15360B
    short* Xs = pool;
    short* Ws = pool + TN * XS;
    int tid = threadIdx.x;
    int node0 = tileIdx * TN;

    constexpr int CT = 8;  // 128/16
    int w = tid >> 6;
    int lane = tid & 63;
    int l15 = lane & 15;
    int quad = lane >> 4;
    f32x4 acc[CT] = {};

#pragma unroll
    for (int h = 0; h < 4; ++h) {
        if (h) __syncthreads();  // all waves done reading previous quarter
        // stage W quarter: 128 rows x 32 shorts (4 x 16B chunks per row)
        for (int q = tid; q < 128 * 4; q += 256) {
            int row = q >> 2, c = q & 3;
            uint4 v = *(const uint4*)((const short*)Wt + row * K + h * KH + c * 8);
            *(uint4*)(Ws + row * XS + c * 8) = v;
        }
        // stage X quarter: 4 threads/row, 8 floats each
        {
            int row = tid >> 2, part = tid & 3;
            int gn = node0 + row;
            int kl = part * 8;
            float4 v0 = (gn < n) ? *(const float4*)(X + (size_t)gn * K + h * KH + kl)
                                 : float4{0, 0, 0, 0};
            float4 v1 = (gn < n) ? *(const float4*)(X + (size_t)gn * K + h * KH + kl + 4)
                                 : float4{0, 0, 0, 0};
            uint4 p = {pack2bf(v0.x, v0.y), pack2bf(v0.z, v0.w),
                       pack2bf(v1.x, v1.y), pack2bf(v1.z, v1.w)};
            *(uint4*)(Xs + row * XS + kl) = p;
        }
        __syncthreads();

        // one bf16x8 per lane covers the full K=32 quarter
        bf16x8 a = *(const bf16x8*)(Xs + (w * 16 + l15) * XS + quad * 8);
#pragma unroll
        for (int ct = 0; ct < CT; ++ct) {
            bf16x8 b = *(const bf16x8*)(Ws + (ct * 16 + l15) * XS + quad * 8);
            acc[ct] = __builtin_amdgcn_mfma_f32_16x16x32_bf16(a, b, acc[ct], 0, 0, 0);
        }
    }

    // ---- coalesced epilogue: 2 passes x 32 rows through LDS ----
    short* TB = pool;  // 32 rows x 136 stride = 4352 shorts (pool is free now)
#pragma unroll
    for (int p = 0; p < 2; ++p) {
        __syncthreads();  // pool free (K-loop reads / prev-pass TB reads done)
        if ((w >> 1) == p) {  // waves 2p, 2p+1 own rows [32p, 32p+32)
            int rbase = (w & 1) * 16 + quad * 4;
#pragma unroll
            for (int ct = 0; ct < CT; ++ct) {
#pragma unroll
                for (int r = 0; r < 4; ++r) {
                    TB[(rbase + r) * 136 + ct * 16 + l15] = f2bf(acc[ct][r]);
                }
            }
        }
        __syncthreads();
        // 256 threads store 32 rows x 16 uint4 (full-line, coalesced)
#pragma unroll
        for (int k = 0; k < 2; ++k) {
            int idx = tid + 256 * k;
            int row = idx >> 4, c = idx & 15;
            int gn = node0 + p * 32 + row;
            if (gn < n) {
                uint4 v = *(const uint4*)(TB + row * 136 + c * 8);
                *(uint4*)((short*)H + (size_t)gn * 128 + c * 8) = v;
            }
        }
    }
}

// ===== hist_count (+rank persist) || layer-1 GEMM, role-INTERLEAVED =====
__global__ __launch_bounds__(256) void hist_gemm(
    const int* __restrict__ dst, int* __restrict__ hist, int* __restrict__ rank,
    const float* __restrict__ x, const ushort16* __restrict__ W1t,
    ushort16* __restrict__ H, int n) {
    int bid = blockIdx.x;
    int g = bid / 5, r = bid % 5;
    if (r < 3) {
        int hb = g * 3 + r;
        if (hb >= NB_HIST) return;
        int i = hb * 256 + threadIdx.x;
        if (i < N_POS) rank[i] = atomicAdd(&hist[dst[i]], 1);
    } else {
        int gb = g * 2 + (r - 3);
        if (gb >= NB_GEMM1) return;
        gemm_tile(x, W1t, H, n, gb);
    }
}

__global__ void scan_reduce(const int* __restrict__ hist, int* __restrict__ partials, int n) {
    __shared__ int sdata[256];
    int b = blockIdx.x, t = threadIdx.x;
    int base = b * 1024;
    int s = 0;
    for (int i = t; i < 1024; i += 256) {
        int idx = base + i;
        s += (idx < n) ? hist[idx] : 0;
    }
    sdata[t] = s;
    __syncthreads();
    for (int off = 128; off > 0; off >>= 1) {
        if (t < off) sdata[t] += sdata[t + off];
        __syncthreads();
    }
    if (t == 0) partials[b] = sdata[0];
}

// scan_final computes its own partials-prefix (first wave). NB_SCAN = 98 <= 128.
__global__ void scan_final(const int* __restrict__ hist, const int* __restrict__ partials,
                           int* __restrict__ rowstart, float* __restrict__ dinv, int n) {
    __shared__ int tsum[256];
    __shared__ int base_sh;
    int t = threadIdx.x, b = blockIdx.x;
    if (t < 64) {
        int s0 = (t < b) ? partials[t] : 0;
        int i2 = t + 64;
        int s1 = (i2 < b && i2 < 98) ? partials[i2] : 0;
        int s = s0 + s1;
#pragma unroll
        for (int off = 32; off > 0; off >>= 1) s += __shfl_down(s, off, 64);
        if (t == 0) base_sh = s;
    }
    int base = b * 1024 + t * 4;
    int v[4];
    int s = 0;
#pragma unroll
    for (int j = 0; j < 4; j++) {
        int i = base + j;
        v[j] = (i < n) ? hist[i] : 0;
        s += v[j];
    }
    tsum[t] = s;
    __syncthreads();
    for (int off = 1; off < 256; off <<= 1) {
        int a = (t >= off) ? tsum[t - off] : 0;
        __syncthreads();
        tsum[t] += a;
        __syncthreads();
    }
    int offset = base_sh + (tsum[t] - s);
#pragma unroll
    for (int j = 0; j < 4; j++) {
        int i = base + j;
        if (i < n) {
            rowstart[i] = offset;
            dinv[i] = rsqrtf((float)v[j] + 1.0f);
            offset += v[j];
        }
    }
    if (b == 0 && t == 0) rowstart[n] = N_POS;
}

// ===== csr_fill standalone: atomic-free, NO LDS -> 8 blocks/CU =====
__global__ __launch_bounds__(256) void csr_fill(
    const int* __restrict__ src, const int* __restrict__ dst, const float* __restrict__ dinv,
    const int* __restrict__ rowstart, const int* __restrict__ rank,
    int2* __restrict__ adjw) {
    int e = blockIdx.x * 256 + threadIdx.x;
    if (e < N_POS) {
        int s = src[e], d = dst[e];
        int p = rowstart[d] + rank[e];
        adjw[p] = int2{s, __float_as_int(dinv[s] * dinv[d])};
    }
}

// ===== layer-1 aggregation body for one node (F=128, +bias+relu), 16 lanes =====
// 8-edge predicated prologue + batched tail (4 gathers in flight; -6us, r8).
__device__ __forceinline__ uint4 agg_node128(int node, int l, const int* __restrict__ rowstart,
                                             const int2* __restrict__ adjw,
                                             const float* __restrict__ dinv,
                                             const ushort16* __restrict__ H,
                                             const float* __restrict__ bias) {
    float dn = dinv[node];
    int rs = rowstart[node], re = rowstart[node + 1];
    int deg = re - rs;
    int pc = (deg > 0) ? rs : (rs > 0 ? rs - 1 : 0);  // safe clamp index
    uint4 h[8];
    float wv[8];
#pragma unroll
    for (int j = 0; j < 8; ++j) {
        int p = (rs + j < re) ? rs + j : pc;
        int2 e = adjw[p];
        h[j] = *(const uint4*)(H + (size_t)e.x * 128 + l * 8);
        wv[j] = (j < deg) ? __int_as_float(e.y) : 0.0f;
    }
    float s0[8] = {}, s1[8] = {};
#pragma unroll
    for (int j = 0; j < 8; j += 2) {
        s0[0] += bf_lo(h[j].x) * wv[j]; s0[1] += bf_hi(h[j].x) * wv[j];
        s0[2] += bf_lo(h[j].y) * wv[j]; s0[3] += bf_hi(h[j].y) * wv[j];
        s0[4] += bf_lo(h[j].z) * wv[j]; s0[5] += bf_hi(h[j].z) * wv[j];
        s0[6] += bf_lo(h[j].w) * wv[j]; s0[7] += bf_hi(h[j].w) * wv[j];
        s1[0] += bf_lo(h[j + 1].x) * wv[j + 1]; s1[1] += bf_hi(h[j + 1].x) * wv[j + 1];
        s1[2] += bf_lo(h[j + 1].y) * wv[j + 1]; s1[3] += bf_hi(h[j + 1].y) * wv[j + 1];
        s1[4] += bf_lo(h[j + 1].z) * wv[j + 1]; s1[5] += bf_hi(h[j + 1].z) * wv[j + 1];
        s1[6] += bf_lo(h[j + 1].w) * wv[j + 1]; s1[7] += bf_hi(h[j + 1].w) * wv[j + 1];
    }
    // batched tail: 4 predicated gathers in flight per iteration
    for (int p = rs + 8; p < re; p += 4) {
        uint4 ht[4];
        float wt[4];
#pragma unroll
        for (int j = 0; j < 4; ++j) {
            int q = (p + j < re) ? p + j : p;  // p itself is always < re here
            int2 e = adjw[q];
            ht[j] = *(const uint4*)(H + (size_t)e.x * 128 + l * 8);
            wt[j] = (p + j < re) ? __int_as_float(e.y) : 0.0f;
        }
#pragma unroll
        for (int j = 0; j < 4; j += 2) {
            s0[0] += bf_lo(ht[j].x) * wt[j]; s0[1] += bf_hi(ht[j].x) * wt[j];
            s0[2] += bf_lo(ht[j].y) * wt[j]; s0[3] += bf_hi(ht[j].y) * wt[j];
            s0[4] += bf_lo(ht[j].z) * wt[j]; s0[5] += bf_hi(ht[j].z) * wt[j];
            s0[6] += bf_lo(ht[j].w) * wt[j]; s0[7] += bf_hi(ht[j].w) * wt[j];
            s1[0] += bf_lo(ht[j + 1].x) * wt[j + 1]; s1[1] += bf_hi(ht[j + 1].x) * wt[j + 1];
            s1[2] += bf_lo(ht[j + 1].y) * wt[j + 1]; s1[3] += bf_hi(ht[j + 1].y) * wt[j + 1];
            s1[4] += bf_lo(ht[j + 1].z) * wt[j + 1]; s1[5] += bf_hi(ht[j + 1].z) * wt[j + 1];
            s1[6] += bf_lo(ht[j + 1].w) * wt[j + 1]; s1[7] += bf_hi(ht[j + 1].w) * wt[j + 1];
        }
    }
    uint4 hv = *(const uint4*)(H + (size_t)node * 128 + l * 8);
    float4 bv0 = *(const float4*)(bias + l * 8);
    float4 bv1 = *(const float4*)(bias + l * 8 + 4);
    float d2 = dn * dn;
    float hs[8] = {bf_lo(hv.x), bf_hi(hv.x), bf_lo(hv.y), bf_hi(hv.y),
                   bf_lo(hv.z), bf_hi(hv.z), bf_lo(hv.w), bf_hi(hv.w)};
    float bb[8] = {bv0.x, bv0.y, bv0.z, bv0.w, bv1.x, bv1.y, bv1.z, bv1.w};
    float v[8];
#pragma unroll
    for (int j = 0; j < 8; ++j) {
        v[j] = fmaxf(s0[j] + s1[j] + hs[j] * d2 + bb[j], 0.0f);  // relu (layer 1)
    }
    return uint4{pack2bf(v[0], v[1]), pack2bf(v[2], v[3]), pack2bf(v[4], v[5]),
                 pack2bf(v[6], v[7])};
}

// ===== fused: layer-1 agg -> LDS -> layer-2 GEMM, 32 nodes/block =====
// (r9: TN2=32 neutral vs 64 -> gather-issue/L2-bound, not occupancy-bound.)
#define ZS 136  // padded row stride (shorts); 272B, 16B-aligned
#define TN2 32  // nodes per block
__global__ __launch_bounds__(256, 4) void agg1_gemm2(
    const int* __restrict__ rowstart, const int2* __restrict__ adjw,
    const float* __restrict__ dinv, const ushort16* __restrict__ H,
    const float* __restrict__ b1, const ushort16* __restrict__ W2t,
    ushort16* __restrict__ h2, int n) {
    __shared__ __align__(16) short Zs[TN2 * ZS];
    __shared__ __align__(16) short Ws[64 * ZS];
    int tid = threadIdx.x;
    int node0 = blockIdx.x * TN2;

    // stage W2t [64 out][128 k] -> Ws (independent of agg; overlaps its latency)
    for (int q = tid; q < 64 * 16; q += 256) {
        int row = q >> 4, c = q & 15;
        uint4 v = *(const uint4*)((const short*)W2t + row * 128 + c * 8);
        *(uint4*)(Ws + row * ZS + c * 8) = v;
    }

    // layer-1 aggregation for 32 nodes: 16 groups x 16 lanes, 2 nodes each
    int g = tid >> 4, l = tid & 15;
#pragma unroll 1
    for (int it = 0; it < 2; ++it) {
        int row = g * 2 + it;
        int node = node0 + row;
        uint4 z = (node < n) ? agg_node128(node, l, rowstart, adjw, dinv, H, b1)
                             : uint4{0, 0, 0, 0};
        *(uint4*)(Zs + row * ZS + l * 8) = z;
    }
    __syncthreads();

    // GEMM: h2[32 x 64] = Zs @ W2. 4 waves: wave w -> row-tile (w>>1),
    // col-tiles (w&1)*32 .. +31 (2 tiles). 8 MFMAs/wave.
    int w = tid >> 6, lane = tid & 63, l15 = lane & 15, quad = lane >> 4;
    int wr = w >> 1, wc = w & 1;
    f32x4 acc[2] = {};
    const short* zrow = Zs + (wr * 16 + l15) * ZS + quad * 8;
#pragma unroll
    for (int kk = 0; kk < 4; ++kk) {
        bf16x8 a = *(const bf16x8*)(zrow + kk * 32);
#pragma unroll
        for (int ct = 0; ct < 2; ++ct) {
            bf16x8 b = *(const bf16x8*)(Ws + (wc * 32 + ct * 16 + l15) * ZS + quad * 8 + kk * 32);
            acc[ct] = __builtin_amdgcn_mfma_f32_16x16x32_bf16(a, b, acc[ct], 0, 0, 0);
        }
    }
#pragma unroll
    for (int ct = 0; ct < 2; ++ct) {
#pragma unroll
        for (int r = 0; r < 4; ++r) {
            int gn = node0 + wr * 16 + quad * 4 + r;
            if (gn < n) h2[(size_t)gn * OUT_CH + wc * 32 + ct * 16 + l15] = f2bf(acc[ct][r]);
        }
    }
}

// ========= layer-2 pull aggregation, PAIRED (2 nodes per 16-lane group) =========
// r7's pair-ILP spilled at F=128 (64 VGPR gather state); at F=64 the pair
// batch is 16 VGPRs — same mechanism, safe budget. 16 gathers in flight in
// the prologue; batched 4-gather tails per node.
__global__ void agg_pull64(const int* __restrict__ rowstart, const int2* __restrict__ adjw,
                           const float* __restrict__ dinv, const ushort16* __restrict__ H,
                           const float* __restrict__ bias, ushort16* __restrict__ Z, int n) {
    int g = threadIdx.x >> 4;  // 16-lane group
    int l = threadIdx.x & 15;
    int nodeA = blockIdx.x * 32 + g * 2;
    if (nodeA >= n) return;
    int nodeB = nodeA + 1;
    bool hasB = nodeB < n;
    int nB = hasB ? nodeB : nodeA;
    float dnA = dinv[nodeA], dnB = dinv[nB];
    int rsA = rowstart[nodeA], reA = rowstart[nodeA + 1];
    int rsB = rowstart[nB], reB = rowstart[nB + 1];
    int degA = reA - rsA, degB = reB - rsB;
    int pcA = (degA > 0) ? rsA : (rsA > 0 ? rsA - 1 : 0);
    int pcB = (degB > 0) ? rsB : (rsB > 0 ? rsB - 1 : 0);
    uint2 hA[8], hB[8];
    float wA[8], wB[8];
#pragma unroll
    for (int j = 0; j < 8; ++j) {
        int2 ea = adjw[(rsA + j < reA) ? rsA + j : pcA];
        int2 eb = adjw[(rsB + j < reB) ? rsB + j : pcB];
        hA[j] = *(const uint2*)(H + (size_t)ea.x * 64 + l * 4);
        hB[j] = *(const uint2*)(H + (size_t)eb.x * 64 + l * 4);
        wA[j] = (j < degA) ? __int_as_float(ea.y) : 0.0f;
        wB[j] = (j < degB) ? __int_as_float(eb.y) : 0.0f;
    }
    float sA[4] = {}, sB[4] = {};
#pragma unroll
    for (int j = 0; j < 8; ++j) {
        sA[0] += bf_lo(hA[j].x) * wA[j]; sA[1] += bf_hi(hA[j].x) * wA[j];
        sA[2] += bf_lo(hA[j].y) * wA[j]; sA[3] += bf_hi(hA[j].y) * wA[j];
        sB[0] += bf_lo(hB[j].x) * wB[j]; sB[1] += bf_hi(hB[j].x) * wB[j];
        sB[2] += bf_lo(hB[j].y) * wB[j]; sB[3] += bf_hi(hB[j].y) * wB[j];
    }
    for (int p = rsA + 8; p < reA; p += 4) {
        uint2 ht[4];
        float wt[4];
#pragma unroll
        for (int j = 0; j < 4; ++j) {
            int q = (p + j < reA) ? p + j : p;
            int2 e = adjw[q];
            ht[j] = *(const uint2*)(H + (size_t)e.x * 64 + l * 4);
            wt[j] = (p + j < reA) ? __int_as_float(e.y) : 0.0f;
        }
#pragma unroll
        for (int j = 0; j < 4; ++j) {
            sA[0] += bf_lo(ht[j].x) * wt[j]; sA[1] += bf_hi(ht[j].x) * wt[j];
            sA[2] += bf_lo(ht[j].y) * wt[j]; sA[3] += bf_hi(ht[j].y) * wt[j];
        }
    }
    for (int p = rsB + 8; p < reB; p += 4) {
        uint2 ht[4];
        float wt[4];
#pragma unroll
        for (int j = 0; j < 4; ++j) {
            int q = (p + j < reB) ? p + j : p;
            int2 e = adjw[q];
            ht[j] = *(const uint2*)(H + (size_t)e.x * 64 + l * 4);
            wt[j] = (p + j < reB) ? __int_as_float(e.y) : 0.0f;
        }
#pragma unroll
        for (int j = 0; j < 4; ++j) {
            sB[0] += bf_lo(ht[j].x) * wt[j]; sB[1] += bf_hi(ht[j].x) * wt[j];
            sB[2] += bf_lo(ht[j].y) * wt[j]; sB[3] += bf_hi(ht[j].y) * wt[j];
        }
    }
    uint2 hvA = *(const uint2*)(H + (size_t)nodeA * 64 + l * 4);
    uint2 hvB = *(const uint2*)(H + (size_t)nB * 64 + l * 4);
    float4 bv = *(const float4*)(bias + l * 4);
    float d2A = dnA * dnA, d2B = dnB * dnB;
    float bb[4] = {bv.x, bv.y, bv.z, bv.w};
    float hsA[4] = {bf_lo(hvA.x), bf_hi(hvA.x), bf_lo(hvA.y), bf_hi(hvA.y)};
    float hsB[4] = {bf_lo(hvB.x), bf_hi(hvB.x), bf_lo(hvB.y), bf_hi(hvB.y)};
    float vA[4], vB[4];
#pragma unroll
    for (int j = 0; j < 4; ++j) {
        vA[j] = sA[j] + hsA[j] * d2A + bb[j];  // layer 2: no relu
        vB[j] = sB[j] + hsB[j] * d2B + bb[j];
    }
    *(uint2*)(Z + (size_t)nodeA * 64 + l * 4) = uint2{pack2bf(vA[0], vA[1]), pack2bf(vA[2], vA[3])};
    if (hasB)
        *(uint2*)(Z + (size_t)nodeB * 64 + l * 4) =
            uint2{pack2bf(vB[0], vB[1]), pack2bf(vB[2], vB[3])};
}

// ===== decode via MFMA: 32 edges per wave (two 16-edge groups) =====
__global__ void decode_mfma(const int* __restrict__ pos, const int* __restrict__ neg,
                            const short* __restrict__ Z, float* __restrict__ out) {
    int wid = threadIdx.x >> 6;
    int lane = threadIdx.x & 63;
    int l15 = lane & 15;
    int quad = lane >> 4;
    int e0 = (blockIdx.x * 4 + wid) * 32;
    if (e0 >= N_POS + N_NEG) return;
    const int* bp = (e0 < N_POS) ? pos : (neg - N_POS);
    int eA = e0 + l15;
    int eB = e0 + 16 + l15;
    int aA = bp[eA], bA = bp[600000 + eA];
    int aB = bp[eB], bB = bp[600000 + eB];

    const short* zaA = Z + (size_t)aA * OUT_CH + quad * 8;
    const short* zbA = Z + (size_t)bA * OUT_CH + quad * 8;
    const short* zaB = Z + (size_t)aB * OUT_CH + quad * 8;
    const short* zbB = Z + (size_t)bB * OUT_CH + quad * 8;
    bf16x8 a0A = *(const bf16x8*)(zaA);
    bf16x8 a1A = *(const bf16x8*)(zaA + 32);
    bf16x8 b0A = *(const bf16x8*)(zbA);
    bf16x8 b1A = *(const bf16x8*)(zbA + 32);
    bf16x8 a0B = *(const bf16x8*)(zaB);
    bf16x8 a1B = *(const bf16x8*)(zaB + 32);
    bf16x8 b0B = *(const bf16x8*)(zbB);
    bf16x8 b1B = *(const bf16x8*)(zbB + 32);

    f32x4 accA = {}, accB = {};
    accA = __builtin_amdgcn_mfma_f32_16x16x32_bf16(a0A, b0A, accA, 0, 0, 0);
    accB = __builtin_amdgcn_mfma_f32_16x16x32_bf16(a0B, b0B, accB, 0, 0, 0);
    accA = __builtin_amdgcn_mfma_f32_16x16x32_bf16(a1A, b1A, accA, 0, 0, 0);
    accB = __builtin_amdgcn_mfma_f32_16x16x32_bf16(a1B, b1B, accB, 0, 0, 0);

    if (quad == (l15 >> 2)) {
        out[eA] = accA[l15 & 3];
        out[eB] = accB[l15 & 3];
    }
}

extern "C" void kernel_launch(void* const* d_in, const int* in_sizes, int n_in,
                              void* d_out, int out_size, void* d_ws, size_t ws_size,
                              hipStream_t stream) {
    const float* x = (const float*)d_in[0];
    const int* pos = (const int*)d_in[1];  // row0 = src, row1 = dst
    const int* neg = (const int*)d_in[2];
    const float* W1 = (const float*)d_in[3];
    const float* b1 = (const float*)d_in[4];
    const float* W2 = (const float*)d_in[5];
    const float* b2 = (const float*)d_in[6];
    float* out = (float*)d_out;

    // workspace layout (bf16 intermediates)
    ushort16* A = (ushort16*)d_ws;                      // H [N,128]; later z2 [N,64]
    ushort16* B = A + (size_t)N_NODES * 128;            // h2 [N,64]
    float* dinv = (float*)(B + (size_t)N_NODES * 128);  // [N]
    int* hist = (int*)(dinv + N_NODES);                 // [N]
    int* rowstart = hist + N_NODES;                     // [N+1]
    int2* adjw = (int2*)(rowstart + N_NODES + 1);       // [N_POS] (adj, wgt) pairs
    int* partials = (int*)(adjw + N_POS);               // [128]
    ushort16* W1t = (ushort16*)(partials + 128);        // [128*128]
    ushort16* W2t = W1t + 128 * 128;                    // [64*128]
    // rank[N_POS] overlays B: rank is dead before agg1_gemm2 writes h2 into B.
    int* rank = (int*)B;

    const int* pos_src = pos;
    const int* pos_dst = pos + N_POS;

    constexpr int NB_SCAN = (N_NODES + 1023) / 1024;  // 98

    // ---- init: zero hist + weight convert (one kernel, replaces memset) ----
    init_wt<<<NB_ZERO + 96, 256, 0, stream>>>(hist, W1, W2, W1t, W2t);

    // ---- hist+rank (atomics) || layer-1 GEMM (MFMA), role-interleaved ----
    hist_gemm<<<NB_HG, 256, 0, stream>>>(pos_dst, hist, rank, x, W1t, A, N_NODES);

    // ---- scan ----
    scan_reduce<<<NB_SCAN, 256, 0, stream>>>(hist, partials, N_NODES);
    scan_final<<<NB_SCAN, 256, 0, stream>>>(hist, partials, rowstart, dinv, N_NODES);

    // ---- csr_fill standalone (no LDS, 8 blocks/CU) ----
    csr_fill<<<NB_FILL, 256, 0, stream>>>(pos_src, pos_dst, dinv, rowstart, rank, adjw);

    // ---- fused layer-1 aggregation (batched tail) + layer-2 GEMM, 32 nodes/blk ----
    agg1_gemm2<<<(N_NODES + TN2 - 1) / TN2, 256, 0, stream>>>(rowstart, adjw, dinv, A, b1, W2t,
                                                              B, N_NODES);

    // ---- layer-2 aggregation, paired (2 nodes/group): reads h2(=B), writes z2(=A) ----
    agg_pull64<<<(N_NODES + 31) / 32, 256, 0, stream>>>(rowstart, adjw, dinv, B, b2, A, N_NODES);

    // ---- decode (32 edges/wave, 128/block) ----
    decode_mfma<<<(N_POS + N_NEG) / 128, 256, 0, stream>>>(pos, neg, (const short*)A, out);
}